// Round 10
// baseline (962.147 us; speedup 1.0000x reference)
//
#include <hip/hip_runtime.h>
#include <hip/hip_bf16.h>

#define L_SEQ 2048
#define HIDN  2048
#define NH    32
#define BATCHN 4

using bf16x8 = __attribute__((ext_vector_type(8))) short;
using f32x4  = __attribute__((ext_vector_type(4))) float;
using half2v = __attribute__((ext_vector_type(2))) _Float16;

__device__ __forceinline__ unsigned short f2bf(float f) {
  union { float f; unsigned u; } v; v.f = f;
  unsigned r = v.u + 0x7fffu + ((v.u >> 16) & 1u);
  return (unsigned short)(r >> 16);
}

__device__ __forceinline__ void gl_lds16(const void* g, void* l) {
  __builtin_amdgcn_global_load_lds(
      (const __attribute__((address_space(1))) unsigned int*)g,
      (__attribute__((address_space(3))) unsigned int*)l, 16, 0, 0);
}

__device__ __forceinline__ half2v pkrtz(float lo, float hi) {
  return __builtin_bit_cast(half2v, __builtin_amdgcn_cvt_pkrtz(lo, hi));
}

template <int CTRL>
__device__ __forceinline__ float qperm(float x) {
  int xi = __builtin_bit_cast(int, x);
  int yi = __builtin_amdgcn_update_dpp(0, xi, CTRL, 0xF, 0xF, true);
  return __builtin_bit_cast(float, yi);
}

// one scan step: pack state pair, 32 readlane -> SGPR broadcast, 32 fdot2,
// Taylor exp, fma, store. Fully inlined; two independent copies interleave.
__device__ __forceinline__ void scan_step(float& s, const half2v* aw, float dBv,
                                          float dtu, unsigned short* st_addr,
                                          int lane) {
  float sn = qperm<0xB1>(s);
  float lo = (lane & 1) ? sn : s;
  float hi = (lane & 1) ? s : sn;
  int dbits = __builtin_bit_cast(int, pkrtz(lo, hi));
  int wp[32];
#pragma unroll
  for (int p = 0; p < 32; ++p) wp[p] = __builtin_amdgcn_readlane(dbits, 2 * p);
  float a0 = 0.f, a1 = 0.f, a2 = 0.f, a3 = 0.f;
#pragma unroll
  for (int j = 0; j < 8; ++j) {
    a0 = __builtin_amdgcn_fdot2(__builtin_bit_cast(half2v, wp[j]),      aw[j],      a0, false);
    a1 = __builtin_amdgcn_fdot2(__builtin_bit_cast(half2v, wp[8 + j]),  aw[8 + j],  a1, false);
    a2 = __builtin_amdgcn_fdot2(__builtin_bit_cast(half2v, wp[16 + j]), aw[16 + j], a2, false);
    a3 = __builtin_amdgcn_fdot2(__builtin_bit_cast(half2v, wp[24 + j]), aw[24 + j], a3, false);
  }
  const float dot = (a0 + a1) + (a2 + a3);
  const float x = dot * dtu;
  const float e = __builtin_fmaf(x * x, 0.5f, 1.f + x);   // exp(x), |x| tiny
  s = e * s + dBv;
  *st_addr = f2bf(s);
}

// ---------------- f32 -> bf16 convert (grid-stride over n/4 float4s) ----------
__global__ __launch_bounds__(256) void cvt_bf16_k(const float* __restrict__ in,
                                                  unsigned short* __restrict__ out, int n4) {
  for (int i = blockIdx.x * 256 + threadIdx.x; i < n4; i += gridDim.x * 256) {
    float4 v = *(const float4*)&in[(size_t)i * 4];
    ushort4 o;
    o.x = f2bf(v.x); o.y = f2bf(v.y); o.z = f2bf(v.z); o.w = f2bf(v.w);
    *(ushort4*)&out[(size_t)i * 4] = o;
  }
}

// -------- conv weight transform: wreT[o][k*64+i] = conv_w[o][i][k] (bf16) -----
__global__ __launch_bounds__(256) void wret_k(const float* __restrict__ cw,
                                              unsigned short* __restrict__ out) {
  int idx = blockIdx.x * 256 + threadIdx.x;   // 2048*256 total
  int o = idx >> 8, q = idx & 255;
  int k = q >> 6, i = q & 63;
  out[idx] = f2bf(cw[o * 256 + i * 4 + k]);
}

// ---------------- GEMM: OUT[m][n] = sum_k X[m][k]*W[n][k], bf16 MFMA ----------
template <int SILU>
__global__ __launch_bounds__(256) void gemm_xwt_k(const unsigned short* __restrict__ X,
                                                  const unsigned short* __restrict__ W,
                                                  float* __restrict__ OUT,
                                                  int M, int N, int K) {
  __shared__ __align__(16) unsigned short As[128 * 32];
  __shared__ __align__(16) unsigned short Bs[128 * 32];
  const int tid = threadIdx.x, lane = tid & 63, wid = tid >> 6;
  const int wm = wid >> 1, wn = wid & 1;
  // XCD-aware bijective swizzle of the flattened block id (nwg % 8 == 0)
  const int lin = blockIdx.y * gridDim.x + blockIdx.x;
  const int cpx = (gridDim.x * gridDim.y) >> 3;
  const int swz = (lin & 7) * cpx + (lin >> 3);
  const int m0 = (swz % gridDim.x) * 128, n0 = (swz / gridDim.x) * 128;
  const int fr = lane & 15, kg = lane >> 4;
  const int sr = lane >> 2, sc = (lane & 3) * 8;   // staging: 4 lanes per row
  f32x4 acc[4][4] = {};
  for (int k0 = 0; k0 < K; k0 += 32) {
    const int cA0 = wid * 16, cA1 = (wid + 4) * 16;   // 16-row chunks per wave-call
    gl_lds16(&X[(size_t)(m0 + cA0 + sr) * K + k0 + sc], &As[cA0 * 32]);
    gl_lds16(&X[(size_t)(m0 + cA1 + sr) * K + k0 + sc], &As[cA1 * 32]);
    gl_lds16(&W[(size_t)(n0 + cA0 + sr) * K + k0 + sc], &Bs[cA0 * 32]);
    gl_lds16(&W[(size_t)(n0 + cA1 + sr) * K + k0 + sc], &Bs[cA1 * 32]);
    __syncthreads();
    bf16x8 af[4], bfr[4];
#pragma unroll
    for (int t = 0; t < 4; ++t) {
      af[t]  = *(const bf16x8*)&As[(wm * 64 + t * 16 + fr) * 32 + kg * 8];
      bfr[t] = *(const bf16x8*)&Bs[(wn * 64 + t * 16 + fr) * 32 + kg * 8];
    }
#pragma unroll
    for (int mt = 0; mt < 4; ++mt)
#pragma unroll
      for (int nt = 0; nt < 4; ++nt)
        acc[mt][nt] = __builtin_amdgcn_mfma_f32_16x16x32_bf16(af[mt], bfr[nt], acc[mt][nt], 0, 0, 0);
    __syncthreads();
  }
#pragma unroll
  for (int mt = 0; mt < 4; ++mt)
#pragma unroll
    for (int nt = 0; nt < 4; ++nt) {
      const int col = n0 + wn * 64 + nt * 16 + fr;
#pragma unroll
      for (int r = 0; r < 4; ++r) {
        const int row = m0 + wm * 64 + mt * 16 + kg * 4 + r;
        float v = acc[mt][nt][r];
        if (SILU) v = v / (1.f + __expf(-v));
        OUT[(size_t)row * N + col] = v;
      }
    }
}

// ------- grouped causal conv as MFMA GEMM; epilogue: (Bc+bias)*dt -> dB -------
__global__ __launch_bounds__(256) void conv_k(const unsigned short* __restrict__ xb,
                                              const unsigned short* __restrict__ wreT,
                                              const float* __restrict__ conv_b,
                                              const float* __restrict__ dt,
                                              float* __restrict__ dB) {
  __shared__ __align__(16) unsigned short x_lds[67 * 64];
  const int l0 = blockIdx.x * 64, g = blockIdx.y, b = blockIdx.z;
  const int tid = threadIdx.x, lane = tid & 63, wid = tid >> 6;
  {
    const int r = tid >> 3, ch = (tid & 7) * 8;
#pragma unroll
    for (int pass = 0; pass < 3; ++pass) {
      int rr = r + pass * 32;
      if (rr < 67) {
        int lg = l0 - 3 + rr;
        bf16x8 v = {};
        if (lg >= 0) v = *(const bf16x8*)&xb[(size_t)(b * L_SEQ + lg) * HIDN + g * 64 + ch];
        *(bf16x8*)&x_lds[rr * 64 + ch] = v;
      }
    }
  }
  __syncthreads();
  const int fr = lane & 15, kg = lane >> 4, wm = wid;
  f32x4 acc[4] = {};
#pragma unroll
  for (int ks = 0; ks < 8; ++ks) {
    bf16x8 a = *(const bf16x8*)&x_lds[(wm * 16 + fr + (ks >> 1)) * 64 + (ks & 1) * 32 + kg * 8];
#pragma unroll
    for (int nt = 0; nt < 4; ++nt) {
      bf16x8 bq = *(const bf16x8*)&wreT[(size_t)(g * 64 + nt * 16 + fr) * 256 + ks * 32 + kg * 8];
      acc[nt] = __builtin_amdgcn_mfma_f32_16x16x32_bf16(a, bq, acc[nt], 0, 0, 0);
    }
  }
#pragma unroll
  for (int nt = 0; nt < 4; ++nt) {
    const int o = nt * 16 + fr;
    const float bias = conv_b[g * 64 + o];
#pragma unroll
    for (int r = 0; r < 4; ++r) {
      const int lg = l0 + wm * 16 + kg * 4 + r;
      const float dtv = dt[b * L_SEQ + lg];
      dB[((size_t)(b * NH + g) * L_SEQ + lg) * 64 + o] = (acc[nt][r] + bias) * dtv;
    }
  }
}

// ---- FUSED: blocks 0..63 = scan, TWO chains per wave (bids 2i, 2i+1);  ------
// ---- blocks 64..1087 = gate GEMM (+silu). GEMM hides under scan latency. ----
__global__ __launch_bounds__(256) void scan_gemm_k(const float* __restrict__ dB,
                                                   const float* __restrict__ Aw,
                                                   const float* __restrict__ dt,
                                                   unsigned short* __restrict__ states,
                                                   const unsigned short* __restrict__ X,
                                                   const unsigned short* __restrict__ W,
                                                   float* __restrict__ OUT) {
  __shared__ __align__(16) unsigned short As[128 * 32];
  __shared__ __align__(16) unsigned short Bs[128 * 32];
  if (blockIdx.x >= 64) {
    // ----------------- gate GEMM tile (grid 64 x 16, swizzled) ---------------
    const int tid = threadIdx.x, lane = tid & 63, wid = tid >> 6;
    const int wm = wid >> 1, wn = wid & 1;
    const int gb = blockIdx.x - 64;               // 0..1023
    const int swz = (gb & 7) * 128 + (gb >> 3);   // XCD-bijective (1024 % 8 == 0)
    const int m0 = (swz & 63) * 128;
    const int n0 = (swz >> 6) * 128;
    const int fr = lane & 15, kg = lane >> 4;
    const int sr = lane >> 2, sc = (lane & 3) * 8;
    f32x4 acc[4][4] = {};
    for (int k0 = 0; k0 < 2048; k0 += 32) {
      const int cA0 = wid * 16, cA1 = (wid + 4) * 16;
      gl_lds16(&X[(size_t)(m0 + cA0 + sr) * 2048 + k0 + sc], &As[cA0 * 32]);
      gl_lds16(&X[(size_t)(m0 + cA1 + sr) * 2048 + k0 + sc], &As[cA1 * 32]);
      gl_lds16(&W[(size_t)(n0 + cA0 + sr) * 2048 + k0 + sc], &Bs[cA0 * 32]);
      gl_lds16(&W[(size_t)(n0 + cA1 + sr) * 2048 + k0 + sc], &Bs[cA1 * 32]);
      __syncthreads();
      bf16x8 af[4], bfr[4];
#pragma unroll
      for (int t = 0; t < 4; ++t) {
        af[t]  = *(const bf16x8*)&As[(wm * 64 + t * 16 + fr) * 32 + kg * 8];
        bfr[t] = *(const bf16x8*)&Bs[(wn * 64 + t * 16 + fr) * 32 + kg * 8];
      }
#pragma unroll
      for (int mt = 0; mt < 4; ++mt)
#pragma unroll
        for (int nt = 0; nt < 4; ++nt)
          acc[mt][nt] = __builtin_amdgcn_mfma_f32_16x16x32_bf16(af[mt], bfr[nt], acc[mt][nt], 0, 0, 0);
      __syncthreads();
    }
#pragma unroll
    for (int mt = 0; mt < 4; ++mt)
#pragma unroll
      for (int nt = 0; nt < 4; ++nt) {
        const int col = n0 + wn * 64 + nt * 16 + fr;
#pragma unroll
        for (int r = 0; r < 4; ++r) {
          const int row = m0 + wm * 64 + mt * 16 + kg * 4 + r;
          float v = acc[mt][nt][r];
          v = v / (1.f + __expf(-v));
          OUT[(size_t)row * 2048 + col] = v;
        }
      }
    return;
  }
  // ------------------- scan: 1 wave, two chains A/B ------------------------
  if (threadIdx.x >= 64) return;
  const int bidA = blockIdx.x * 2, bidB = bidA + 1;
  const int b = bidA >> 5;                       // same b for both (bit0 differs)
  const int lane = threadIdx.x;

  half2v awA[32], awB[32];
  {
    const float* ArA = Aw + (size_t)((bidA & 31) * 64 + lane) * 64;
    const float* ArB = Aw + (size_t)((bidB & 31) * 64 + lane) * 64;
#pragma unroll
    for (int j4 = 0; j4 < 16; ++j4) {
      float4 vA = *(const float4*)&ArA[j4 * 4];
      float4 vB = *(const float4*)&ArB[j4 * 4];
      awA[2 * j4]     = pkrtz(vA.x, vA.y);
      awA[2 * j4 + 1] = pkrtz(vA.z, vA.w);
      awB[2 * j4]     = pkrtz(vB.x, vB.y);
      awB[2 * j4 + 1] = pkrtz(vB.z, vB.w);
    }
  }

  const float* dBpA = dB + (size_t)bidA * L_SEQ * 64 + lane;
  const float* dBpB = dB + (size_t)bidB * L_SEQ * 64 + lane;
  unsigned short* stpA = states + (size_t)bidA * L_SEQ * 64 + lane;
  unsigned short* stpB = states + (size_t)bidB * L_SEQ * 64 + lane;
  const float* dtp = dt + b * L_SEQ;

  float rA0[4], rA1[4], rB0[4], rB1[4];
#pragma unroll
  for (int u = 0; u < 4; ++u) {
    rA0[u] = dBpA[(size_t)u * 64];
    rA1[u] = dBpA[(size_t)(4 + u) * 64];
    rB0[u] = dBpB[(size_t)u * 64];
    rB1[u] = dBpB[(size_t)(4 + u) * 64];
  }
  float4 dtc = *(const float4*)&dtp[0];
  float4 dtn = *(const float4*)&dtp[4];

  float sA = 0.f, sB = 0.f;
  for (int g = 0; g < L_SEQ / 4; ++g) {
    const int l0 = g * 4;
    const int lp = (l0 + 8 <= L_SEQ - 4) ? (l0 + 8) : (L_SEQ - 4);
    float rnA[4], rnB[4];
#pragma unroll
    for (int u = 0; u < 4; ++u) {
      rnA[u] = dBpA[(size_t)(lp + u) * 64];
      rnB[u] = dBpB[(size_t)(lp + u) * 64];
    }
    float4 dtn2 = *(const float4*)&dtp[lp];
    const float dtu[4] = { dtc.x, dtc.y, dtc.z, dtc.w };
#pragma unroll
    for (int u = 0; u < 4; ++u) {
      scan_step(sA, awA, rA0[u], dtu[u], &stpA[(size_t)(l0 + u) * 64], lane);
      scan_step(sB, awB, rB0[u], dtu[u], &stpB[(size_t)(l0 + u) * 64], lane);
    }
#pragma unroll
    for (int u = 0; u < 4; ++u) {
      rA0[u] = rA1[u]; rA1[u] = rnA[u];
      rB0[u] = rB1[u]; rB1[u] = rnB[u];
    }
    dtc = dtn; dtn = dtn2;
  }
}

// ----- C projection + x*D + silu(gate) multiply; writes hs1 (b,l,hid) f32 -----
__global__ __launch_bounds__(256) void proj_k(const unsigned short* __restrict__ st,
                                              const unsigned short* __restrict__ cwb,
                                              const float* __restrict__ xin,
                                              const float* __restrict__ Dp,
                                              const float* __restrict__ gs,
                                              float* __restrict__ hs1) {
  const int l0 = blockIdx.x * 64, h = blockIdx.y, b = blockIdx.z;
  const int tid = threadIdx.x, lane = tid & 63, wid = tid >> 6;
  const int fr = lane & 15, kg = lane >> 4, wm = wid;
  f32x4 acc[4] = {};
#pragma unroll
  for (int ks = 0; ks < 2; ++ks) {
    bf16x8 a = *(const bf16x8*)&st[((size_t)(b * NH + h) * L_SEQ + l0 + wm * 16 + fr) * 64 + ks * 32 + kg * 8];
#pragma unroll
    for (int nt = 0; nt < 4; ++nt) {
      bf16x8 bq = *(const bf16x8*)&cwb[(size_t)(h * 64 + nt * 16 + fr) * 64 + ks * 32 + kg * 8];
      acc[nt] = __builtin_amdgcn_mfma_f32_16x16x32_bf16(a, bq, acc[nt], 0, 0, 0);
    }
  }
  const float Dh = Dp[h];
#pragma unroll
  for (int nt = 0; nt < 4; ++nt) {
    const int ccol = h * 64 + nt * 16 + fr;
#pragma unroll
    for (int r = 0; r < 4; ++r) {
      const int lg = l0 + wm * 16 + kg * 4 + r;
      const size_t idx = (size_t)(b * L_SEQ + lg) * HIDN + ccol;
      float v = acc[nt][r] + xin[idx] * Dh;
      hs1[idx] = v * gs[idx];
    }
  }
}

// --------------------- gated RMSNorm -> bf16 rows -----------------------------
__global__ __launch_bounds__(256) void norm_k(const float* __restrict__ hs1,
                                              const float* __restrict__ nw,
                                              unsigned short* __restrict__ out) {
  const int row = blockIdx.x;
  const float* p = hs1 + (size_t)row * HIDN;
  const int c0 = threadIdx.x * 8;
  float4 u0 = *(const float4*)&p[c0];
  float4 u1 = *(const float4*)&p[c0 + 4];
  float ss = u0.x * u0.x + u0.y * u0.y + u0.z * u0.z + u0.w * u0.w +
             u1.x * u1.x + u1.y * u1.y + u1.z * u1.z + u1.w * u1.w;
#pragma unroll
  for (int off = 32; off; off >>= 1) ss += __shfl_xor(ss, off);
  __shared__ float pr[4];
  if ((threadIdx.x & 63) == 0) pr[threadIdx.x >> 6] = ss;
  __syncthreads();
  float tot = pr[0] + pr[1] + pr[2] + pr[3];
  float rs = rsqrtf(tot * (1.f / HIDN) + 1e-6f);
  bf16x8 res;
  res[0] = (short)f2bf(nw[c0 + 0] * u0.x * rs);
  res[1] = (short)f2bf(nw[c0 + 1] * u0.y * rs);
  res[2] = (short)f2bf(nw[c0 + 2] * u0.z * rs);
  res[3] = (short)f2bf(nw[c0 + 3] * u0.w * rs);
  res[4] = (short)f2bf(nw[c0 + 4] * u1.x * rs);
  res[5] = (short)f2bf(nw[c0 + 5] * u1.y * rs);
  res[6] = (short)f2bf(nw[c0 + 6] * u1.z * rs);
  res[7] = (short)f2bf(nw[c0 + 7] * u1.w * rs);
  *(bf16x8*)&out[(size_t)row * HIDN + c0] = res;
}

extern "C" void kernel_launch(void* const* d_in, const int* in_sizes, int n_in,
                              void* d_out, int out_size, void* d_ws, size_t ws_size,
                              hipStream_t stream) {
  const float* x  = (const float*)d_in[0];
  const float* dt = (const float*)d_in[1];
  const float* gw = (const float*)d_in[2];
  const float* Aw = (const float*)d_in[3];
  const float* cw = (const float*)d_in[4];
  const float* cb = (const float*)d_in[5];
  const float* Cw = (const float*)d_in[6];
  const float* Dp = (const float*)d_in[7];
  const float* nw = (const float*)d_in[8];
  const float* ow = (const float*)d_in[9];
  float* out = (float*)d_out;

  // workspace layout (bytes). states overlays hsb (states' last reader proj_k
  // completes before norm_k writes hsb); hs1 overlays dBf (free after scan).
  char* w = (char*)d_ws;
  unsigned short* xb   = (unsigned short*)(w);                // 32MB
  unsigned short* gwb  = (unsigned short*)(w + 33554432);     // 8MB
  unsigned short* owb  = (unsigned short*)(w + 41943040);     // 8MB
  unsigned short* wret = (unsigned short*)(w + 50331648);     // 1MB
  unsigned short* cwb  = (unsigned short*)(w + 51380224);     // 256KB
  float*          dBf  = (float*)(w + 52428800);              // 64MB
  float*          hs1  = dBf;                                 // overlay (after scan)
  unsigned short* hsb  = (unsigned short*)(w + 119537664);    // 32MB
  unsigned short* stb  = hsb;                                 // overlay (before norm)
  if (ws_size < 153092096) return;

  cvt_bf16_k<<<2048, 256, 0, stream>>>(x, xb, 16777216 / 4);
  cvt_bf16_k<<<1024, 256, 0, stream>>>(gw, gwb, 4194304 / 4);
  cvt_bf16_k<<<1024, 256, 0, stream>>>(ow, owb, 4194304 / 4);
  cvt_bf16_k<<<128, 256, 0, stream>>>(Cw, cwb, 131072 / 4);
  wret_k<<<2048, 256, 0, stream>>>(cw, wret);

  conv_k<<<dim3(32, 32, 4), 256, 0, stream>>>(xb, wret, cb, dt, dBf);
  // scan 2-chains/wave (blocks 0..63) || gate GEMM + silu (blocks 64..1087)
  scan_gemm_k<<<1088, 256, 0, stream>>>(dBf, Aw, dt, stb, xb, gwb, out);
  proj_k<<<dim3(32, 32, 4), 256, 0, stream>>>(stb, cwb, x, Dp, out, hs1);
  norm_k<<<8192, 256, 0, stream>>>(hs1, nw, hsb);
  gemm_xwt_k<0><<<dim3(64, 16), 256, 0, stream>>>(hsb, owb, out, 8192, 2048, 2048);
}

// Round 11
// 708.416 us; speedup vs baseline: 1.3582x; 1.3582x over previous
//
#include <hip/hip_runtime.h>
#include <hip/hip_bf16.h>

#define L_SEQ 2048
#define HIDN  2048
#define NH    32
#define BATCHN 4

using bf16x8 = __attribute__((ext_vector_type(8))) short;
using f32x4  = __attribute__((ext_vector_type(4))) float;
using half2v = __attribute__((ext_vector_type(2))) _Float16;

__device__ __forceinline__ unsigned short f2bf(float f) {
  union { float f; unsigned u; } v; v.f = f;
  unsigned r = v.u + 0x7fffu + ((v.u >> 16) & 1u);
  return (unsigned short)(r >> 16);
}

__device__ __forceinline__ void gl_lds16(const void* g, void* l) {
  __builtin_amdgcn_global_load_lds(
      (const __attribute__((address_space(1))) unsigned int*)g,
      (__attribute__((address_space(3))) unsigned int*)l, 16, 0, 0);
}

__device__ __forceinline__ half2v pkrtz(float lo, float hi) {
  return __builtin_bit_cast(half2v, __builtin_amdgcn_cvt_pkrtz(lo, hi));
}

template <int CTRL>
__device__ __forceinline__ float qperm(float x) {
  int xi = __builtin_bit_cast(int, x);
  int yi = __builtin_amdgcn_update_dpp(0, xi, CTRL, 0xF, 0xF, true);
  return __builtin_bit_cast(float, yi);
}

// ---------------- f32 -> bf16 convert (grid-stride over n/4 float4s) ----------
__global__ __launch_bounds__(256) void cvt_bf16_k(const float* __restrict__ in,
                                                  unsigned short* __restrict__ out, int n4) {
  for (int i = blockIdx.x * 256 + threadIdx.x; i < n4; i += gridDim.x * 256) {
    float4 v = *(const float4*)&in[(size_t)i * 4];
    ushort4 o;
    o.x = f2bf(v.x); o.y = f2bf(v.y); o.z = f2bf(v.z); o.w = f2bf(v.w);
    *(ushort4*)&out[(size_t)i * 4] = o;
  }
}

// -------- conv weight transform: wreT[o][k*64+i] = conv_w[o][i][k] (bf16) -----
__global__ __launch_bounds__(256) void wret_k(const float* __restrict__ cw,
                                              unsigned short* __restrict__ out) {
  int idx = blockIdx.x * 256 + threadIdx.x;   // 2048*256 total
  int o = idx >> 8, q = idx & 255;
  int k = q >> 6, i = q & 63;
  out[idx] = f2bf(cw[o * 256 + i * 4 + k]);
}

// ---------------- GEMM: OUT[m][n] = sum_k X[m][k]*W[n][k], bf16 MFMA ----------
template <int SILU>
__global__ __launch_bounds__(256) void gemm_xwt_k(const unsigned short* __restrict__ X,
                                                  const unsigned short* __restrict__ W,
                                                  float* __restrict__ OUT,
                                                  int M, int N, int K) {
  __shared__ __align__(16) unsigned short As[128 * 32];
  __shared__ __align__(16) unsigned short Bs[128 * 32];
  const int tid = threadIdx.x, lane = tid & 63, wid = tid >> 6;
  const int wm = wid >> 1, wn = wid & 1;
  // XCD-aware bijective swizzle of the flattened block id (nwg % 8 == 0)
  const int lin = blockIdx.y * gridDim.x + blockIdx.x;
  const int cpx = (gridDim.x * gridDim.y) >> 3;
  const int swz = (lin & 7) * cpx + (lin >> 3);
  const int m0 = (swz % gridDim.x) * 128, n0 = (swz / gridDim.x) * 128;
  const int fr = lane & 15, kg = lane >> 4;
  const int sr = lane >> 2, sc = (lane & 3) * 8;   // staging: 4 lanes per row
  f32x4 acc[4][4] = {};
  for (int k0 = 0; k0 < K; k0 += 32) {
    const int cA0 = wid * 16, cA1 = (wid + 4) * 16;   // 16-row chunks per wave-call
    gl_lds16(&X[(size_t)(m0 + cA0 + sr) * K + k0 + sc], &As[cA0 * 32]);
    gl_lds16(&X[(size_t)(m0 + cA1 + sr) * K + k0 + sc], &As[cA1 * 32]);
    gl_lds16(&W[(size_t)(n0 + cA0 + sr) * K + k0 + sc], &Bs[cA0 * 32]);
    gl_lds16(&W[(size_t)(n0 + cA1 + sr) * K + k0 + sc], &Bs[cA1 * 32]);
    __syncthreads();
    bf16x8 af[4], bfr[4];
#pragma unroll
    for (int t = 0; t < 4; ++t) {
      af[t]  = *(const bf16x8*)&As[(wm * 64 + t * 16 + fr) * 32 + kg * 8];
      bfr[t] = *(const bf16x8*)&Bs[(wn * 64 + t * 16 + fr) * 32 + kg * 8];
    }
#pragma unroll
    for (int mt = 0; mt < 4; ++mt)
#pragma unroll
      for (int nt = 0; nt < 4; ++nt)
        acc[mt][nt] = __builtin_amdgcn_mfma_f32_16x16x32_bf16(af[mt], bfr[nt], acc[mt][nt], 0, 0, 0);
    __syncthreads();
  }
#pragma unroll
  for (int mt = 0; mt < 4; ++mt)
#pragma unroll
    for (int nt = 0; nt < 4; ++nt) {
      const int col = n0 + wn * 64 + nt * 16 + fr;
#pragma unroll
      for (int r = 0; r < 4; ++r) {
        const int row = m0 + wm * 64 + mt * 16 + kg * 4 + r;
        float v = acc[mt][nt][r];
        if (SILU) v = v / (1.f + __expf(-v));
        OUT[(size_t)row * N + col] = v;
      }
    }
}

// ------- grouped causal conv as MFMA GEMM; epilogue: (Bc+bias)*dt -> dB -------
__global__ __launch_bounds__(256) void conv_k(const unsigned short* __restrict__ xb,
                                              const unsigned short* __restrict__ wreT,
                                              const float* __restrict__ conv_b,
                                              const float* __restrict__ dt,
                                              float* __restrict__ dB) {
  __shared__ __align__(16) unsigned short x_lds[67 * 64];
  const int l0 = blockIdx.x * 64, g = blockIdx.y, b = blockIdx.z;
  const int tid = threadIdx.x, lane = tid & 63, wid = tid >> 6;
  {
    const int r = tid >> 3, ch = (tid & 7) * 8;
#pragma unroll
    for (int pass = 0; pass < 3; ++pass) {
      int rr = r + pass * 32;
      if (rr < 67) {
        int lg = l0 - 3 + rr;
        bf16x8 v = {};
        if (lg >= 0) v = *(const bf16x8*)&xb[(size_t)(b * L_SEQ + lg) * HIDN + g * 64 + ch];
        *(bf16x8*)&x_lds[rr * 64 + ch] = v;
      }
    }
  }
  __syncthreads();
  const int fr = lane & 15, kg = lane >> 4, wm = wid;
  f32x4 acc[4] = {};
#pragma unroll
  for (int ks = 0; ks < 8; ++ks) {
    bf16x8 a = *(const bf16x8*)&x_lds[(wm * 16 + fr + (ks >> 1)) * 64 + (ks & 1) * 32 + kg * 8];
#pragma unroll
    for (int nt = 0; nt < 4; ++nt) {
      bf16x8 bq = *(const bf16x8*)&wreT[(size_t)(g * 64 + nt * 16 + fr) * 256 + ks * 32 + kg * 8];
      acc[nt] = __builtin_amdgcn_mfma_f32_16x16x32_bf16(a, bq, acc[nt], 0, 0, 0);
    }
  }
#pragma unroll
  for (int nt = 0; nt < 4; ++nt) {
    const int o = nt * 16 + fr;
    const float bias = conv_b[g * 64 + o];
#pragma unroll
    for (int r = 0; r < 4; ++r) {
      const int lg = l0 + wm * 16 + kg * 4 + r;
      const float dtv = dt[b * L_SEQ + lg];
      dB[((size_t)(b * NH + g) * L_SEQ + lg) * 64 + o] = (acc[nt][r] + bias) * dtv;
    }
  }
}

// ---- FUSED: blocks 0..127 = selective scan (1 wave each); blocks 128..1151 ---
// ---- = gate GEMM (8192x2048x2048 + silu). GEMM hides under scan latency. -----
// Scan v8: exchange via 32 v_readlane -> SGPR; sched_barrier(0) BATCHES the
// readlanes so the SGPR-write->VALU-read hazard is paid once, not 32x.
__global__ __launch_bounds__(256) void scan_gemm_k(const float* __restrict__ dB,
                                                   const float* __restrict__ Aw,
                                                   const float* __restrict__ dt,
                                                   unsigned short* __restrict__ states,
                                                   const unsigned short* __restrict__ X,
                                                   const unsigned short* __restrict__ W,
                                                   float* __restrict__ OUT) {
  __shared__ __align__(16) unsigned short As[128 * 32];
  __shared__ __align__(16) unsigned short Bs[128 * 32];
  if (blockIdx.x >= 128) {
    // ----------------- gate GEMM tile (grid 64 x 16, swizzled) ---------------
    const int tid = threadIdx.x, lane = tid & 63, wid = tid >> 6;
    const int wm = wid >> 1, wn = wid & 1;
    const int gb = blockIdx.x - 128;              // 0..1023
    const int swz = (gb & 7) * 128 + (gb >> 3);   // XCD-bijective (1024 % 8 == 0)
    const int m0 = (swz & 63) * 128;
    const int n0 = (swz >> 6) * 128;
    const int fr = lane & 15, kg = lane >> 4;
    const int sr = lane >> 2, sc = (lane & 3) * 8;
    f32x4 acc[4][4] = {};
    for (int k0 = 0; k0 < 2048; k0 += 32) {
      const int cA0 = wid * 16, cA1 = (wid + 4) * 16;
      gl_lds16(&X[(size_t)(m0 + cA0 + sr) * 2048 + k0 + sc], &As[cA0 * 32]);
      gl_lds16(&X[(size_t)(m0 + cA1 + sr) * 2048 + k0 + sc], &As[cA1 * 32]);
      gl_lds16(&W[(size_t)(n0 + cA0 + sr) * 2048 + k0 + sc], &Bs[cA0 * 32]);
      gl_lds16(&W[(size_t)(n0 + cA1 + sr) * 2048 + k0 + sc], &Bs[cA1 * 32]);
      __syncthreads();
      bf16x8 af[4], bfr[4];
#pragma unroll
      for (int t = 0; t < 4; ++t) {
        af[t]  = *(const bf16x8*)&As[(wm * 64 + t * 16 + fr) * 32 + kg * 8];
        bfr[t] = *(const bf16x8*)&Bs[(wn * 64 + t * 16 + fr) * 32 + kg * 8];
      }
#pragma unroll
      for (int mt = 0; mt < 4; ++mt)
#pragma unroll
        for (int nt = 0; nt < 4; ++nt)
          acc[mt][nt] = __builtin_amdgcn_mfma_f32_16x16x32_bf16(af[mt], bfr[nt], acc[mt][nt], 0, 0, 0);
      __syncthreads();
    }
#pragma unroll
    for (int mt = 0; mt < 4; ++mt)
#pragma unroll
      for (int nt = 0; nt < 4; ++nt) {
        const int col = n0 + wn * 64 + nt * 16 + fr;
#pragma unroll
        for (int r = 0; r < 4; ++r) {
          const int row = m0 + wm * 64 + mt * 16 + kg * 4 + r;
          float v = acc[mt][nt][r];
          v = v / (1.f + __expf(-v));
          OUT[(size_t)row * 2048 + col] = v;
        }
      }
    return;
  }
  // --------------------------- scan (1 wave) --------------------------------
  if (threadIdx.x >= 64) return;
  const int bid = blockIdx.x;          // b*32 + h
  const int h = bid & 31, b = bid >> 5;
  const int lane = threadIdx.x;

  half2v aw[32];
  const float* Ar = Aw + (size_t)(h * 64 + lane) * 64;
#pragma unroll
  for (int j4 = 0; j4 < 16; ++j4) {
    float4 v = *(const float4*)&Ar[j4 * 4];
    aw[2 * j4]     = pkrtz(v.x, v.y);
    aw[2 * j4 + 1] = pkrtz(v.z, v.w);
  }

  const float* dBp = dB + (size_t)bid * L_SEQ * 64 + lane;
  unsigned short* stp = states + (size_t)bid * L_SEQ * 64 + lane;
  const float* dtp = dt + b * L_SEQ;

  float r0[4], r1[4];
#pragma unroll
  for (int u = 0; u < 4; ++u) r0[u] = dBp[(size_t)u * 64];
#pragma unroll
  for (int u = 0; u < 4; ++u) r1[u] = dBp[(size_t)(4 + u) * 64];
  float4 dtc = *(const float4*)&dtp[0];
  float4 dtn = *(const float4*)&dtp[4];

  float s = 0.f;
  for (int g = 0; g < L_SEQ / 4; ++g) {
    const int l0 = g * 4;
    const int lp = (l0 + 8 <= L_SEQ - 4) ? (l0 + 8) : (L_SEQ - 4);
    float rn[4];
#pragma unroll
    for (int u = 0; u < 4; ++u) rn[u] = dBp[(size_t)(lp + u) * 64];
    float4 dtn2 = *(const float4*)&dtp[lp];
    const float dtu[4] = { dtc.x, dtc.y, dtc.z, dtc.w };
#pragma unroll
    for (int u = 0; u < 4; ++u) {
      // pair dword: lanes 2p and 2p+1 both build (s[2p], s[2p+1])
      float sn = qperm<0xB1>(s);
      float lo = (lane & 1) ? sn : s;
      float hi = (lane & 1) ? s : sn;
      int dbits = __builtin_bit_cast(int, pkrtz(lo, hi));
      // wave-uniform broadcast: 32 readlanes -> SGPRs, issued as ONE batch so
      // the SGPR-write -> VALU-read hazard is paid once (not per dot).
      int wp[32];
#pragma unroll
      for (int p = 0; p < 32; ++p)
        wp[p] = __builtin_amdgcn_readlane(dbits, 2 * p);
      __builtin_amdgcn_sched_barrier(0);   // keep all readlanes before any dot
      float a0 = 0.f, a1 = 0.f, a2 = 0.f, a3 = 0.f;
#pragma unroll
      for (int j = 0; j < 8; ++j) {
        a0 = __builtin_amdgcn_fdot2(__builtin_bit_cast(half2v, wp[j]),      aw[j],      a0, false);
        a1 = __builtin_amdgcn_fdot2(__builtin_bit_cast(half2v, wp[8 + j]),  aw[8 + j],  a1, false);
        a2 = __builtin_amdgcn_fdot2(__builtin_bit_cast(half2v, wp[16 + j]), aw[16 + j], a2, false);
        a3 = __builtin_amdgcn_fdot2(__builtin_bit_cast(half2v, wp[24 + j]), aw[24 + j], a3, false);
      }
      const float dot = (a0 + a1) + (a2 + a3);
      const float x = dot * dtu[u];
      const float e = __builtin_fmaf(x * x, 0.5f, 1.f + x);   // exp(x), |x| tiny
      s = e * s + r0[u];
      stp[(size_t)(l0 + u) * 64] = f2bf(s);
    }
#pragma unroll
    for (int u = 0; u < 4; ++u) { r0[u] = r1[u]; r1[u] = rn[u]; }
    dtc = dtn; dtn = dtn2;
  }
}

// ----- C projection + x*D + silu(gate) multiply; writes hs1 (b,l,hid) f32 -----
__global__ __launch_bounds__(256) void proj_k(const unsigned short* __restrict__ st,
                                              const unsigned short* __restrict__ cwb,
                                              const float* __restrict__ xin,
                                              const float* __restrict__ Dp,
                                              const float* __restrict__ gs,
                                              float* __restrict__ hs1) {
  const int l0 = blockIdx.x * 64, h = blockIdx.y, b = blockIdx.z;
  const int tid = threadIdx.x, lane = tid & 63, wid = tid >> 6;
  const int fr = lane & 15, kg = lane >> 4, wm = wid;
  f32x4 acc[4] = {};
#pragma unroll
  for (int ks = 0; ks < 2; ++ks) {
    bf16x8 a = *(const bf16x8*)&st[((size_t)(b * NH + h) * L_SEQ + l0 + wm * 16 + fr) * 64 + ks * 32 + kg * 8];
#pragma unroll
    for (int nt = 0; nt < 4; ++nt) {
      bf16x8 bq = *(const bf16x8*)&cwb[(size_t)(h * 64 + nt * 16 + fr) * 64 + ks * 32 + kg * 8];
      acc[nt] = __builtin_amdgcn_mfma_f32_16x16x32_bf16(a, bq, acc[nt], 0, 0, 0);
    }
  }
  const float Dh = Dp[h];
#pragma unroll
  for (int nt = 0; nt < 4; ++nt) {
    const int ccol = h * 64 + nt * 16 + fr;
#pragma unroll
    for (int r = 0; r < 4; ++r) {
      const int lg = l0 + wm * 16 + kg * 4 + r;
      const size_t idx = (size_t)(b * L_SEQ + lg) * HIDN + ccol;
      float v = acc[nt][r] + xin[idx] * Dh;
      hs1[idx] = v * gs[idx];
    }
  }
}

// --------------------- gated RMSNorm -> bf16 rows -----------------------------
__global__ __launch_bounds__(256) void norm_k(const float* __restrict__ hs1,
                                              const float* __restrict__ nw,
                                              unsigned short* __restrict__ out) {
  const int row = blockIdx.x;
  const float* p = hs1 + (size_t)row * HIDN;
  const int c0 = threadIdx.x * 8;
  float4 u0 = *(const float4*)&p[c0];
  float4 u1 = *(const float4*)&p[c0 + 4];
  float ss = u0.x * u0.x + u0.y * u0.y + u0.z * u0.z + u0.w * u0.w +
             u1.x * u1.x + u1.y * u1.y + u1.z * u1.z + u1.w * u1.w;
#pragma unroll
  for (int off = 32; off; off >>= 1) ss += __shfl_xor(ss, off);
  __shared__ float pr[4];
  if ((threadIdx.x & 63) == 0) pr[threadIdx.x >> 6] = ss;
  __syncthreads();
  float tot = pr[0] + pr[1] + pr[2] + pr[3];
  float rs = rsqrtf(tot * (1.f / HIDN) + 1e-6f);
  bf16x8 res;
  res[0] = (short)f2bf(nw[c0 + 0] * u0.x * rs);
  res[1] = (short)f2bf(nw[c0 + 1] * u0.y * rs);
  res[2] = (short)f2bf(nw[c0 + 2] * u0.z * rs);
  res[3] = (short)f2bf(nw[c0 + 3] * u0.w * rs);
  res[4] = (short)f2bf(nw[c0 + 4] * u1.x * rs);
  res[5] = (short)f2bf(nw[c0 + 5] * u1.y * rs);
  res[6] = (short)f2bf(nw[c0 + 6] * u1.z * rs);
  res[7] = (short)f2bf(nw[c0 + 7] * u1.w * rs);
  *(bf16x8*)&out[(size_t)row * HIDN + c0] = res;
}

extern "C" void kernel_launch(void* const* d_in, const int* in_sizes, int n_in,
                              void* d_out, int out_size, void* d_ws, size_t ws_size,
                              hipStream_t stream) {
  const float* x  = (const float*)d_in[0];
  const float* dt = (const float*)d_in[1];
  const float* gw = (const float*)d_in[2];
  const float* Aw = (const float*)d_in[3];
  const float* cw = (const float*)d_in[4];
  const float* cb = (const float*)d_in[5];
  const float* Cw = (const float*)d_in[6];
  const float* Dp = (const float*)d_in[7];
  const float* nw = (const float*)d_in[8];
  const float* ow = (const float*)d_in[9];
  float* out = (float*)d_out;

  // workspace layout (bytes). states overlays hsb (states' last reader proj_k
  // completes before norm_k writes hsb); hs1 overlays dBf (free after scan).
  char* w = (char*)d_ws;
  unsigned short* xb   = (unsigned short*)(w);                // 32MB
  unsigned short* gwb  = (unsigned short*)(w + 33554432);     // 8MB
  unsigned short* owb  = (unsigned short*)(w + 41943040);     // 8MB
  unsigned short* wret = (unsigned short*)(w + 50331648);     // 1MB
  unsigned short* cwb  = (unsigned short*)(w + 51380224);     // 256KB
  float*          dBf  = (float*)(w + 52428800);              // 64MB
  float*          hs1  = dBf;                                 // overlay (after scan)
  unsigned short* hsb  = (unsigned short*)(w + 119537664);    // 32MB
  unsigned short* stb  = hsb;                                 // overlay (before norm)
  if (ws_size < 153092096) return;

  cvt_bf16_k<<<2048, 256, 0, stream>>>(x, xb, 16777216 / 4);
  cvt_bf16_k<<<1024, 256, 0, stream>>>(gw, gwb, 4194304 / 4);
  cvt_bf16_k<<<1024, 256, 0, stream>>>(ow, owb, 4194304 / 4);
  cvt_bf16_k<<<128, 256, 0, stream>>>(Cw, cwb, 131072 / 4);
  wret_k<<<2048, 256, 0, stream>>>(cw, wret);

  conv_k<<<dim3(32, 32, 4), 256, 0, stream>>>(xb, wret, cb, dt, dBf);
  // scan (blocks 0..127) || gate GEMM + silu (blocks 128..1151)
  scan_gemm_k<<<1152, 256, 0, stream>>>(dBf, Aw, dt, stb, xb, gwb, out);
  proj_k<<<dim3(32, 32, 4), 256, 0, stream>>>(stb, cwb, x, Dp, out, hs1);
  norm_k<<<8192, 256, 0, stream>>>(hs1, nw, hsb);
  gemm_xwt_k<0><<<dim3(64, 16), 256, 0, stream>>>(hsb, owb, out, 8192, 2048, 2048);
}

// Round 12
// 588.641 us; speedup vs baseline: 1.6345x; 1.2035x over previous
//
#include <hip/hip_runtime.h>
#include <hip/hip_bf16.h>

#define L_SEQ 2048
#define HIDN  2048
#define NH    32
#define BATCHN 4
#define CHUNK 64
#define ITERS 3   // fixed-point correction iterations per chunk

using bf16x8 = __attribute__((ext_vector_type(8))) short;
using f32x4  = __attribute__((ext_vector_type(4))) float;

__device__ __forceinline__ unsigned short f2bf(float f) {
  union { float f; unsigned u; } v; v.f = f;
  unsigned r = v.u + 0x7fffu + ((v.u >> 16) & 1u);
  return (unsigned short)(r >> 16);
}

__device__ __forceinline__ void gl_lds16(const void* g, void* l) {
  __builtin_amdgcn_global_load_lds(
      (const __attribute__((address_space(1))) unsigned int*)g,
      (__attribute__((address_space(3))) unsigned int*)l, 16, 0, 0);
}

template <int CTRL>
__device__ __forceinline__ float qperm(float x) {
  int xi = __builtin_bit_cast(int, x);
  int yi = __builtin_amdgcn_update_dpp(0, xi, CTRL, 0xF, 0xF, true);
  return __builtin_bit_cast(float, yi);
}

// ---------------- f32 -> bf16 convert (grid-stride over n/4 float4s) ----------
__global__ __launch_bounds__(256) void cvt_bf16_k(const float* __restrict__ in,
                                                  unsigned short* __restrict__ out, int n4) {
  for (int i = blockIdx.x * 256 + threadIdx.x; i < n4; i += gridDim.x * 256) {
    float4 v = *(const float4*)&in[(size_t)i * 4];
    ushort4 o;
    o.x = f2bf(v.x); o.y = f2bf(v.y); o.z = f2bf(v.z); o.w = f2bf(v.w);
    *(ushort4*)&out[(size_t)i * 4] = o;
  }
}

// -------- conv weight transform: wreT[o][k*64+i] = conv_w[o][i][k] (bf16) -----
__global__ __launch_bounds__(256) void wret_k(const float* __restrict__ cw,
                                              unsigned short* __restrict__ out) {
  int idx = blockIdx.x * 256 + threadIdx.x;   // 2048*256 total
  int o = idx >> 8, q = idx & 255;
  int k = q >> 6, i = q & 63;
  out[idx] = f2bf(cw[o * 256 + i * 4 + k]);
}

// ---------------- GEMM: OUT[m][n] = sum_k X[m][k]*W[n][k], bf16 MFMA ----------
template <int SILU>
__global__ __launch_bounds__(256) void gemm_xwt_k(const unsigned short* __restrict__ X,
                                                  const unsigned short* __restrict__ W,
                                                  float* __restrict__ OUT,
                                                  int M, int N, int K) {
  __shared__ __align__(16) unsigned short As[128 * 32];
  __shared__ __align__(16) unsigned short Bs[128 * 32];
  const int tid = threadIdx.x, lane = tid & 63, wid = tid >> 6;
  const int wm = wid >> 1, wn = wid & 1;
  const int lin = blockIdx.y * gridDim.x + blockIdx.x;
  const int cpx = (gridDim.x * gridDim.y) >> 3;
  const int swz = (lin & 7) * cpx + (lin >> 3);
  const int m0 = (swz % gridDim.x) * 128, n0 = (swz / gridDim.x) * 128;
  const int fr = lane & 15, kg = lane >> 4;
  const int sr = lane >> 2, sc = (lane & 3) * 8;
  f32x4 acc[4][4] = {};
  for (int k0 = 0; k0 < K; k0 += 32) {
    const int cA0 = wid * 16, cA1 = (wid + 4) * 16;
    gl_lds16(&X[(size_t)(m0 + cA0 + sr) * K + k0 + sc], &As[cA0 * 32]);
    gl_lds16(&X[(size_t)(m0 + cA1 + sr) * K + k0 + sc], &As[cA1 * 32]);
    gl_lds16(&W[(size_t)(n0 + cA0 + sr) * K + k0 + sc], &Bs[cA0 * 32]);
    gl_lds16(&W[(size_t)(n0 + cA1 + sr) * K + k0 + sc], &Bs[cA1 * 32]);
    __syncthreads();
    bf16x8 af[4], bfr[4];
#pragma unroll
    for (int t = 0; t < 4; ++t) {
      af[t]  = *(const bf16x8*)&As[(wm * 64 + t * 16 + fr) * 32 + kg * 8];
      bfr[t] = *(const bf16x8*)&Bs[(wn * 64 + t * 16 + fr) * 32 + kg * 8];
    }
#pragma unroll
    for (int mt = 0; mt < 4; ++mt)
#pragma unroll
      for (int nt = 0; nt < 4; ++nt)
        acc[mt][nt] = __builtin_amdgcn_mfma_f32_16x16x32_bf16(af[mt], bfr[nt], acc[mt][nt], 0, 0, 0);
    __syncthreads();
  }
#pragma unroll
  for (int mt = 0; mt < 4; ++mt)
#pragma unroll
    for (int nt = 0; nt < 4; ++nt) {
      const int col = n0 + wn * 64 + nt * 16 + fr;
#pragma unroll
      for (int r = 0; r < 4; ++r) {
        const int row = m0 + wm * 64 + mt * 16 + kg * 4 + r;
        float v = acc[mt][nt][r];
        if (SILU) v = v / (1.f + __expf(-v));
        OUT[(size_t)row * N + col] = v;
      }
    }
}

// ------- grouped causal conv as MFMA GEMM; epilogue: (Bc+bias)*dt -> dB -------
__global__ __launch_bounds__(256) void conv_k(const unsigned short* __restrict__ xb,
                                              const unsigned short* __restrict__ wreT,
                                              const float* __restrict__ conv_b,
                                              const float* __restrict__ dt,
                                              float* __restrict__ dB) {
  __shared__ __align__(16) unsigned short x_lds[67 * 64];
  const int l0 = blockIdx.x * 64, g = blockIdx.y, b = blockIdx.z;
  const int tid = threadIdx.x, lane = tid & 63, wid = tid >> 6;
  {
    const int r = tid >> 3, ch = (tid & 7) * 8;
#pragma unroll
    for (int pass = 0; pass < 3; ++pass) {
      int rr = r + pass * 32;
      if (rr < 67) {
        int lg = l0 - 3 + rr;
        bf16x8 v = {};
        if (lg >= 0) v = *(const bf16x8*)&xb[(size_t)(b * L_SEQ + lg) * HIDN + g * 64 + ch];
        *(bf16x8*)&x_lds[rr * 64 + ch] = v;
      }
    }
  }
  __syncthreads();
  const int fr = lane & 15, kg = lane >> 4, wm = wid;
  f32x4 acc[4] = {};
#pragma unroll
  for (int ks = 0; ks < 8; ++ks) {
    bf16x8 a = *(const bf16x8*)&x_lds[(wm * 16 + fr + (ks >> 1)) * 64 + (ks & 1) * 32 + kg * 8];
#pragma unroll
    for (int nt = 0; nt < 4; ++nt) {
      bf16x8 bq = *(const bf16x8*)&wreT[(size_t)(g * 64 + nt * 16 + fr) * 256 + ks * 32 + kg * 8];
      acc[nt] = __builtin_amdgcn_mfma_f32_16x16x32_bf16(a, bq, acc[nt], 0, 0, 0);
    }
  }
#pragma unroll
  for (int nt = 0; nt < 4; ++nt) {
    const int o = nt * 16 + fr;
    const float bias = conv_b[g * 64 + o];
#pragma unroll
    for (int r = 0; r < 4; ++r) {
      const int lg = l0 + wm * 16 + kg * 4 + r;
      const float dtv = dt[b * L_SEQ + lg];
      dB[((size_t)(b * NH + g) * L_SEQ + lg) * 64 + o] = (acc[nt][r] + bias) * dtv;
    }
  }
}

// ---- FUSED: blocks 0..127 = chunked fixed-point scan (1 wave each);  --------
// ---- blocks 128..1151 = gate GEMM (+silu) hidden under the scan. ------------
// Scan v9: per 64-step chunk: [scan(e guess, lane-local fma chain, write bf16
// s-pairs to LDS) -> batched matvec X=A_w·S via 32 MFMA (v4-verified frags:
// A-op rows=m, B-op cols=time) -> ·dt -> Taylor exp -> new e] x ITERS, then
// final scan with global stores. Serial cross-lane work amortized 64x.
__global__ __launch_bounds__(256) void scan_gemm_k(const float* __restrict__ dB,
                                                   const float* __restrict__ Aw,
                                                   const float* __restrict__ dt,
                                                   unsigned short* __restrict__ states,
                                                   const unsigned short* __restrict__ X,
                                                   const unsigned short* __restrict__ W,
                                                   float* __restrict__ OUT) {
  __shared__ __align__(16) char smem[28672];
  if (blockIdx.x >= 128) {
    // ----------------- gate GEMM tile (grid 64 x 16, swizzled) ---------------
    unsigned short* As = (unsigned short*)smem;            // 8KB
    unsigned short* Bs = (unsigned short*)(smem + 8192);   // 8KB
    const int tid = threadIdx.x, lane = tid & 63, wid = tid >> 6;
    const int wm = wid >> 1, wn = wid & 1;
    const int gb = blockIdx.x - 128;              // 0..1023
    const int swz = (gb & 7) * 128 + (gb >> 3);   // XCD-bijective
    const int m0 = (swz & 63) * 128;
    const int n0 = (swz >> 6) * 128;
    const int fr = lane & 15, kg = lane >> 4;
    const int sr = lane >> 2, sc = (lane & 3) * 8;
    f32x4 acc[4][4] = {};
    for (int k0 = 0; k0 < 2048; k0 += 32) {
      const int cA0 = wid * 16, cA1 = (wid + 4) * 16;
      gl_lds16(&X[(size_t)(m0 + cA0 + sr) * 2048 + k0 + sc], &As[cA0 * 32]);
      gl_lds16(&X[(size_t)(m0 + cA1 + sr) * 2048 + k0 + sc], &As[cA1 * 32]);
      gl_lds16(&W[(size_t)(n0 + cA0 + sr) * 2048 + k0 + sc], &Bs[cA0 * 32]);
      gl_lds16(&W[(size_t)(n0 + cA1 + sr) * 2048 + k0 + sc], &Bs[cA1 * 32]);
      __syncthreads();
      bf16x8 af[4], bfr[4];
#pragma unroll
      for (int t = 0; t < 4; ++t) {
        af[t]  = *(const bf16x8*)&As[(wm * 64 + t * 16 + fr) * 32 + kg * 8];
        bfr[t] = *(const bf16x8*)&Bs[(wn * 64 + t * 16 + fr) * 32 + kg * 8];
      }
#pragma unroll
      for (int mt = 0; mt < 4; ++mt)
#pragma unroll
        for (int nt = 0; nt < 4; ++nt)
          acc[mt][nt] = __builtin_amdgcn_mfma_f32_16x16x32_bf16(af[mt], bfr[nt], acc[mt][nt], 0, 0, 0);
      __syncthreads();
    }
#pragma unroll
    for (int mt = 0; mt < 4; ++mt)
#pragma unroll
      for (int nt = 0; nt < 4; ++nt) {
        const int col = n0 + wn * 64 + nt * 16 + fr;
#pragma unroll
        for (int r = 0; r < 4; ++r) {
          const int row = m0 + wm * 64 + mt * 16 + kg * 4 + r;
          float v = acc[mt][nt][r];
          v = v / (1.f + __expf(-v));
          OUT[(size_t)row * 2048 + col] = v;
        }
      }
    return;
  }
  // --------------------------- scan (1 wave) --------------------------------
  if (threadIdx.x >= 64) return;
  const int bid = blockIdx.x;          // b*32 + h
  const int h = bid & 31, b = bid >> 5;
  const int lane = threadIdx.x;
  const int fr = lane & 15, kg = lane >> 4;

  // LDS: s-pairs [CHUNK][40 dwords] (160B stride), xT [CHUNK][72 dwords] (288B)
  char* sp = smem;                 // 10240 B
  char* xT = smem + 10240;         // 18432 B

  // A_w fragments (v4-verified): lane(fr,kg) holds A[h][mb*16+fr][kt*32+kg*8+j]
  bf16x8 afr[4][2];
  {
    const float* Ah = Aw + (size_t)h * 64 * 64;
#pragma unroll
    for (int mb = 0; mb < 4; ++mb)
#pragma unroll
      for (int kt = 0; kt < 2; ++kt) {
        const float* p = &Ah[(size_t)(mb * 16 + fr) * 64 + kt * 32 + kg * 8];
        float4 v0 = *(const float4*)p;
        float4 v1 = *(const float4*)(p + 4);
        bf16x8 f;
        f[0] = (short)f2bf(v0.x); f[1] = (short)f2bf(v0.y);
        f[2] = (short)f2bf(v0.z); f[3] = (short)f2bf(v0.w);
        f[4] = (short)f2bf(v1.x); f[5] = (short)f2bf(v1.y);
        f[6] = (short)f2bf(v1.z); f[7] = (short)f2bf(v1.w);
        afr[mb][kt] = f;
      }
  }

  const float* dBp = dB + (size_t)bid * L_SEQ * 64 + lane;
  unsigned short* stp = states + (size_t)bid * L_SEQ * 64 + lane;
  const float* dtp = dt + b * L_SEQ;
  const int spw = (lane >> 1) * 4;             // s-pair dword byte offset

  float scs = 0.f;                             // carried exact state
  for (int c = 0; c < L_SEQ / CHUNK; ++c) {
    const int l0 = c * CHUNK;
    float Dv[CHUNK], E[CHUNK];
#pragma unroll
    for (int l = 0; l < CHUNK; ++l) Dv[l] = dBp[(size_t)(l0 + l) * 64];
#pragma unroll
    for (int l = 0; l < CHUNK; ++l) E[l] = 1.0f;
    float dtq[4];
#pragma unroll
    for (int tb = 0; tb < 4; ++tb) dtq[tb] = dtp[l0 + tb * 16 + fr];

    for (int it = 0; it < ITERS; ++it) {
      // ---- scan with LDS pair writes (s_l BEFORE update at step l) ----
      float s = scs;
#pragma unroll
      for (int l = 0; l < CHUNK; ++l) {
        float sn = qperm<0xB1>(s);
        float lo = (lane & 1) ? sn : s;
        float hi = (lane & 1) ? s : sn;
        unsigned pw;
        asm("v_cvt_pk_bf16_f32 %0, %1, %2" : "=v"(pw) : "v"(lo), "v"(hi));
        *(unsigned*)(sp + l * 160 + spw) = pw;
        s = __builtin_fmaf(E[l], s, Dv[l]);
      }
      asm volatile("" ::: "memory");
      // ---- batched matvec: X[m][t] = A_w · S ----
      bf16x8 bf[4][2];
#pragma unroll
      for (int tb = 0; tb < 4; ++tb)
#pragma unroll
        for (int kt = 0; kt < 2; ++kt)
          bf[tb][kt] = *(const bf16x8*)(sp + (tb * 16 + fr) * 160 + (kt * 16 + kg * 4) * 4);
      f32x4 acc[4][4];
#pragma unroll
      for (int mb = 0; mb < 4; ++mb)
#pragma unroll
        for (int tb = 0; tb < 4; ++tb) {
          f32x4 z = {0.f, 0.f, 0.f, 0.f};
          f32x4 t0 = __builtin_amdgcn_mfma_f32_16x16x32_bf16(afr[mb][0], bf[tb][0], z, 0, 0, 0);
          acc[mb][tb] = __builtin_amdgcn_mfma_f32_16x16x32_bf16(afr[mb][1], bf[tb][1], t0, 0, 0, 0);
        }
      // scale by dt (t = tb*16+fr per lane) and write xT[t][m]
#pragma unroll
      for (int mb = 0; mb < 4; ++mb)
#pragma unroll
        for (int tb = 0; tb < 4; ++tb) {
          f32x4 v = acc[mb][tb];
          v[0] *= dtq[tb]; v[1] *= dtq[tb]; v[2] *= dtq[tb]; v[3] *= dtq[tb];
          *(f32x4*)(xT + (tb * 16 + fr) * 288 + (mb * 16 + kg * 4) * 4) = v;
        }
      asm volatile("" ::: "memory");
      // ---- readback own-m time series, Taylor exp -> E ----
#pragma unroll
      for (int l = 0; l < CHUNK; ++l) {
        float x = *(const float*)(xT + l * 288 + lane * 4);
        E[l] = __builtin_fmaf(x * x, 0.5f, 1.0f + x);
      }
    }
    // ---- final scan with converged E: store states ----
    {
      float s = scs;
#pragma unroll
      for (int l = 0; l < CHUNK; ++l) {
        s = __builtin_fmaf(E[l], s, Dv[l]);
        stp[(size_t)(l0 + l) * 64] = f2bf(s);
      }
      scs = s;
    }
  }
}

// ----- C projection + x*D + silu(gate) multiply; writes hs1 (b,l,hid) f32 -----
__global__ __launch_bounds__(256) void proj_k(const unsigned short* __restrict__ st,
                                              const unsigned short* __restrict__ cwb,
                                              const float* __restrict__ xin,
                                              const float* __restrict__ Dp,
                                              const float* __restrict__ gs,
                                              float* __restrict__ hs1) {
  const int l0 = blockIdx.x * 64, h = blockIdx.y, b = blockIdx.z;
  const int tid = threadIdx.x, lane = tid & 63, wid = tid >> 6;
  const int fr = lane & 15, kg = lane >> 4, wm = wid;
  f32x4 acc[4] = {};
#pragma unroll
  for (int ks = 0; ks < 2; ++ks) {
    bf16x8 a = *(const bf16x8*)&st[((size_t)(b * NH + h) * L_SEQ + l0 + wm * 16 + fr) * 64 + ks * 32 + kg * 8];
#pragma unroll
    for (int nt = 0; nt < 4; ++nt) {
      bf16x8 bq = *(const bf16x8*)&cwb[(size_t)(h * 64 + nt * 16 + fr) * 64 + ks * 32 + kg * 8];
      acc[nt] = __builtin_amdgcn_mfma_f32_16x16x32_bf16(a, bq, acc[nt], 0, 0, 0);
    }
  }
  const float Dh = Dp[h];
#pragma unroll
  for (int nt = 0; nt < 4; ++nt) {
    const int ccol = h * 64 + nt * 16 + fr;
#pragma unroll
    for (int r = 0; r < 4; ++r) {
      const int lg = l0 + wm * 16 + kg * 4 + r;
      const size_t idx = (size_t)(b * L_SEQ + lg) * HIDN + ccol;
      float v = acc[nt][r] + xin[idx] * Dh;
      hs1[idx] = v * gs[idx];
    }
  }
}

// --------------------- gated RMSNorm -> bf16 rows -----------------------------
__global__ __launch_bounds__(256) void norm_k(const float* __restrict__ hs1,
                                              const float* __restrict__ nw,
                                              unsigned short* __restrict__ out) {
  const int row = blockIdx.x;
  const float* p = hs1 + (size_t)row * HIDN;
  const int c0 = threadIdx.x * 8;
  float4 u0 = *(const float4*)&p[c0];
  float4 u1 = *(const float4*)&p[c0 + 4];
  float ss = u0.x * u0.x + u0.y * u0.y + u0.z * u0.z + u0.w * u0.w +
             u1.x * u1.x + u1.y * u1.y + u1.z * u1.z + u1.w * u1.w;
#pragma unroll
  for (int off = 32; off; off >>= 1) ss += __shfl_xor(ss, off);
  __shared__ float pr[4];
  if ((threadIdx.x & 63) == 0) pr[threadIdx.x >> 6] = ss;
  __syncthreads();
  float tot = pr[0] + pr[1] + pr[2] + pr[3];
  float rs = rsqrtf(tot * (1.f / HIDN) + 1e-6f);
  bf16x8 res;
  res[0] = (short)f2bf(nw[c0 + 0] * u0.x * rs);
  res[1] = (short)f2bf(nw[c0 + 1] * u0.y * rs);
  res[2] = (short)f2bf(nw[c0 + 2] * u0.z * rs);
  res[3] = (short)f2bf(nw[c0 + 3] * u0.w * rs);
  res[4] = (short)f2bf(nw[c0 + 4] * u1.x * rs);
  res[5] = (short)f2bf(nw[c0 + 5] * u1.y * rs);
  res[6] = (short)f2bf(nw[c0 + 6] * u1.z * rs);
  res[7] = (short)f2bf(nw[c0 + 7] * u1.w * rs);
  *(bf16x8*)&out[(size_t)row * HIDN + c0] = res;
}

extern "C" void kernel_launch(void* const* d_in, const int* in_sizes, int n_in,
                              void* d_out, int out_size, void* d_ws, size_t ws_size,
                              hipStream_t stream) {
  const float* x  = (const float*)d_in[0];
  const float* dt = (const float*)d_in[1];
  const float* gw = (const float*)d_in[2];
  const float* Aw = (const float*)d_in[3];
  const float* cw = (const float*)d_in[4];
  const float* cb = (const float*)d_in[5];
  const float* Cw = (const float*)d_in[6];
  const float* Dp = (const float*)d_in[7];
  const float* nw = (const float*)d_in[8];
  const float* ow = (const float*)d_in[9];
  float* out = (float*)d_out;

  // workspace layout (bytes). states overlays hsb (states' last reader proj_k
  // completes before norm_k writes hsb); hs1 overlays dBf (free after scan).
  char* w = (char*)d_ws;
  unsigned short* xb   = (unsigned short*)(w);                // 32MB
  unsigned short* gwb  = (unsigned short*)(w + 33554432);     // 8MB
  unsigned short* owb  = (unsigned short*)(w + 41943040);     // 8MB
  unsigned short* wret = (unsigned short*)(w + 50331648);     // 1MB
  unsigned short* cwb  = (unsigned short*)(w + 51380224);     // 256KB
  float*          dBf  = (float*)(w + 52428800);              // 64MB
  float*          hs1  = dBf;                                 // overlay (after scan)
  unsigned short* hsb  = (unsigned short*)(w + 119537664);    // 32MB
  unsigned short* stb  = hsb;                                 // overlay (before norm)
  if (ws_size < 153092096) return;

  cvt_bf16_k<<<2048, 256, 0, stream>>>(x, xb, 16777216 / 4);
  cvt_bf16_k<<<1024, 256, 0, stream>>>(gw, gwb, 4194304 / 4);
  cvt_bf16_k<<<1024, 256, 0, stream>>>(ow, owb, 4194304 / 4);
  cvt_bf16_k<<<128, 256, 0, stream>>>(Cw, cwb, 131072 / 4);
  wret_k<<<2048, 256, 0, stream>>>(cw, wret);

  conv_k<<<dim3(32, 32, 4), 256, 0, stream>>>(xb, wret, cb, dt, dBf);
  // chunked fixed-point scan (blocks 0..127) || gate GEMM (blocks 128..1151)
  scan_gemm_k<<<1152, 256, 0, stream>>>(dBf, Aw, dt, stb, xb, gwb, out);
  proj_k<<<dim3(32, 32, 4), 256, 0, stream>>>(stb, cwb, x, Dp, out, hs1);
  norm_k<<<8192, 256, 0, stream>>>(hs1, nw, hsb);
  gemm_xwt_k<0><<<dim3(64, 16), 256, 0, stream>>>(hsb, owb, out, 8192, 2048, 2048);
}

// Round 13
// 552.378 us; speedup vs baseline: 1.7418x; 1.0656x over previous
//
#include <hip/hip_runtime.h>
#include <hip/hip_bf16.h>

#define L_SEQ 2048
#define HIDN  2048
#define NH    32
#define BATCHN 4
#define CHUNK 64
#define ITERS 2   // fixed-point correction iterations per chunk

using bf16x8 = __attribute__((ext_vector_type(8))) short;
using f32x4  = __attribute__((ext_vector_type(4))) float;

__device__ __forceinline__ unsigned short f2bf(float f) {
  union { float f; unsigned u; } v; v.f = f;
  unsigned r = v.u + 0x7fffu + ((v.u >> 16) & 1u);
  return (unsigned short)(r >> 16);
}

__device__ __forceinline__ void gl_lds16(const void* g, void* l) {
  __builtin_amdgcn_global_load_lds(
      (const __attribute__((address_space(1))) unsigned int*)g,
      (__attribute__((address_space(3))) unsigned int*)l, 16, 0, 0);
}

template <int CTRL>
__device__ __forceinline__ float qperm(float x) {
  int xi = __builtin_bit_cast(int, x);
  int yi = __builtin_amdgcn_update_dpp(0, xi, CTRL, 0xF, 0xF, true);
  return __builtin_bit_cast(float, yi);
}

// ---------------- f32 -> bf16 convert (grid-stride over n/4 float4s) ----------
__global__ __launch_bounds__(256) void cvt_bf16_k(const float* __restrict__ in,
                                                  unsigned short* __restrict__ out, int n4) {
  for (int i = blockIdx.x * 256 + threadIdx.x; i < n4; i += gridDim.x * 256) {
    float4 v = *(const float4*)&in[(size_t)i * 4];
    ushort4 o;
    o.x = f2bf(v.x); o.y = f2bf(v.y); o.z = f2bf(v.z); o.w = f2bf(v.w);
    *(ushort4*)&out[(size_t)i * 4] = o;
  }
}

// -------- conv weight transform: wreT[o][k*64+i] = conv_w[o][i][k] (bf16) -----
__global__ __launch_bounds__(256) void wret_k(const float* __restrict__ cw,
                                              unsigned short* __restrict__ out) {
  int idx = blockIdx.x * 256 + threadIdx.x;   // 2048*256 total
  int o = idx >> 8, q = idx & 255;
  int k = q >> 6, i = q & 63;
  out[idx] = f2bf(cw[o * 256 + i * 4 + k]);
}

// ---------------- GEMM: OUT[m][n] = sum_k X[m][k]*W[n][k], bf16 MFMA ----------
template <int SILU>
__global__ __launch_bounds__(256) void gemm_xwt_k(const unsigned short* __restrict__ X,
                                                  const unsigned short* __restrict__ W,
                                                  float* __restrict__ OUT,
                                                  int M, int N, int K) {
  __shared__ __align__(16) unsigned short As[128 * 32];
  __shared__ __align__(16) unsigned short Bs[128 * 32];
  const int tid = threadIdx.x, lane = tid & 63, wid = tid >> 6;
  const int wm = wid >> 1, wn = wid & 1;
  const int lin = blockIdx.y * gridDim.x + blockIdx.x;
  const int cpx = (gridDim.x * gridDim.y) >> 3;
  const int swz = (lin & 7) * cpx + (lin >> 3);
  const int m0 = (swz % gridDim.x) * 128, n0 = (swz / gridDim.x) * 128;
  const int fr = lane & 15, kg = lane >> 4;
  const int sr = lane >> 2, sc = (lane & 3) * 8;
  f32x4 acc[4][4] = {};
  for (int k0 = 0; k0 < K; k0 += 32) {
    const int cA0 = wid * 16, cA1 = (wid + 4) * 16;
    gl_lds16(&X[(size_t)(m0 + cA0 + sr) * K + k0 + sc], &As[cA0 * 32]);
    gl_lds16(&X[(size_t)(m0 + cA1 + sr) * K + k0 + sc], &As[cA1 * 32]);
    gl_lds16(&W[(size_t)(n0 + cA0 + sr) * K + k0 + sc], &Bs[cA0 * 32]);
    gl_lds16(&W[(size_t)(n0 + cA1 + sr) * K + k0 + sc], &Bs[cA1 * 32]);
    __syncthreads();
    bf16x8 af[4], bfr[4];
#pragma unroll
    for (int t = 0; t < 4; ++t) {
      af[t]  = *(const bf16x8*)&As[(wm * 64 + t * 16 + fr) * 32 + kg * 8];
      bfr[t] = *(const bf16x8*)&Bs[(wn * 64 + t * 16 + fr) * 32 + kg * 8];
    }
#pragma unroll
    for (int mt = 0; mt < 4; ++mt)
#pragma unroll
      for (int nt = 0; nt < 4; ++nt)
        acc[mt][nt] = __builtin_amdgcn_mfma_f32_16x16x32_bf16(af[mt], bfr[nt], acc[mt][nt], 0, 0, 0);
    __syncthreads();
  }
#pragma unroll
  for (int mt = 0; mt < 4; ++mt)
#pragma unroll
    for (int nt = 0; nt < 4; ++nt) {
      const int col = n0 + wn * 64 + nt * 16 + fr;
#pragma unroll
      for (int r = 0; r < 4; ++r) {
        const int row = m0 + wm * 64 + mt * 16 + kg * 4 + r;
        float v = acc[mt][nt][r];
        if (SILU) v = v / (1.f + __expf(-v));
        OUT[(size_t)row * N + col] = v;
      }
    }
}

// --- grouped causal conv as MFMA GEMM; epilogue: (Bc+bias)*dt -> dBt[row][l] --
// dBt layout TRANSPOSED: row = (b*NH+g)*64 + o, col = l  (float4 stores).
__global__ __launch_bounds__(256) void conv_k(const unsigned short* __restrict__ xb,
                                              const unsigned short* __restrict__ wreT,
                                              const float* __restrict__ conv_b,
                                              const float* __restrict__ dt,
                                              float* __restrict__ dBt) {
  __shared__ __align__(16) unsigned short x_lds[67 * 64];
  const int l0 = blockIdx.x * 64, g = blockIdx.y, b = blockIdx.z;
  const int tid = threadIdx.x, lane = tid & 63, wid = tid >> 6;
  {
    const int r = tid >> 3, ch = (tid & 7) * 8;
#pragma unroll
    for (int pass = 0; pass < 3; ++pass) {
      int rr = r + pass * 32;
      if (rr < 67) {
        int lg = l0 - 3 + rr;
        bf16x8 v = {};
        if (lg >= 0) v = *(const bf16x8*)&xb[(size_t)(b * L_SEQ + lg) * HIDN + g * 64 + ch];
        *(bf16x8*)&x_lds[rr * 64 + ch] = v;
      }
    }
  }
  __syncthreads();
  const int fr = lane & 15, kg = lane >> 4, wm = wid;
  f32x4 acc[4] = {};
#pragma unroll
  for (int ks = 0; ks < 8; ++ks) {
    bf16x8 a = *(const bf16x8*)&x_lds[(wm * 16 + fr + (ks >> 1)) * 64 + (ks & 1) * 32 + kg * 8];
#pragma unroll
    for (int nt = 0; nt < 4; ++nt) {
      bf16x8 bq = *(const bf16x8*)&wreT[(size_t)(g * 64 + nt * 16 + fr) * 256 + ks * 32 + kg * 8];
      acc[nt] = __builtin_amdgcn_mfma_f32_16x16x32_bf16(a, bq, acc[nt], 0, 0, 0);
    }
  }
  const int lgb = l0 + wm * 16 + kg * 4;
  const float4 dt4 = *(const float4*)&dt[b * L_SEQ + lgb];
#pragma unroll
  for (int nt = 0; nt < 4; ++nt) {
    const int o = nt * 16 + fr;
    const float bias = conv_b[g * 64 + o];
    float4 vv;
    vv.x = (acc[nt][0] + bias) * dt4.x;
    vv.y = (acc[nt][1] + bias) * dt4.y;
    vv.z = (acc[nt][2] + bias) * dt4.z;
    vv.w = (acc[nt][3] + bias) * dt4.w;
    *(float4*)&dBt[((size_t)(b * NH + g) * 64 + o) * L_SEQ + lgb] = vv;
  }
}

// ---- FUSED: blocks 0..127 = chunked fixed-point scan (1 wave each);  --------
// ---- blocks 128..1151 = gate GEMM (+silu) hidden under the scan. ------------
__global__ __launch_bounds__(256) void scan_gemm_k(const float* __restrict__ dBt,
                                                   const float* __restrict__ Aw,
                                                   const float* __restrict__ dt,
                                                   unsigned short* __restrict__ states,
                                                   const unsigned short* __restrict__ X,
                                                   const unsigned short* __restrict__ W,
                                                   float* __restrict__ OUT) {
  __shared__ __align__(16) char smem[30720];
  if (blockIdx.x >= 128) {
    // ----------------- gate GEMM tile (grid 64 x 16, swizzled) ---------------
    unsigned short* As = (unsigned short*)smem;            // 8KB
    unsigned short* Bs = (unsigned short*)(smem + 8192);   // 8KB
    const int tid = threadIdx.x, lane = tid & 63, wid = tid >> 6;
    const int wm = wid >> 1, wn = wid & 1;
    const int gb = blockIdx.x - 128;              // 0..1023
    const int swz = (gb & 7) * 128 + (gb >> 3);   // XCD-bijective
    const int m0 = (swz & 63) * 128;
    const int n0 = (swz >> 6) * 128;
    const int fr = lane & 15, kg = lane >> 4;
    const int sr = lane >> 2, sc = (lane & 3) * 8;
    f32x4 acc[4][4] = {};
    for (int k0 = 0; k0 < 2048; k0 += 32) {
      const int cA0 = wid * 16, cA1 = (wid + 4) * 16;
      gl_lds16(&X[(size_t)(m0 + cA0 + sr) * 2048 + k0 + sc], &As[cA0 * 32]);
      gl_lds16(&X[(size_t)(m0 + cA1 + sr) * 2048 + k0 + sc], &As[cA1 * 32]);
      gl_lds16(&W[(size_t)(n0 + cA0 + sr) * 2048 + k0 + sc], &Bs[cA0 * 32]);
      gl_lds16(&W[(size_t)(n0 + cA1 + sr) * 2048 + k0 + sc], &Bs[cA1 * 32]);
      __syncthreads();
      bf16x8 af[4], bfr[4];
#pragma unroll
      for (int t = 0; t < 4; ++t) {
        af[t]  = *(const bf16x8*)&As[(wm * 64 + t * 16 + fr) * 32 + kg * 8];
        bfr[t] = *(const bf16x8*)&Bs[(wn * 64 + t * 16 + fr) * 32 + kg * 8];
      }
#pragma unroll
      for (int mt = 0; mt < 4; ++mt)
#pragma unroll
        for (int nt = 0; nt < 4; ++nt)
          acc[mt][nt] = __builtin_amdgcn_mfma_f32_16x16x32_bf16(af[mt], bfr[nt], acc[mt][nt], 0, 0, 0);
      __syncthreads();
    }
#pragma unroll
    for (int mt = 0; mt < 4; ++mt)
#pragma unroll
      for (int nt = 0; nt < 4; ++nt) {
        const int col = n0 + wn * 64 + nt * 16 + fr;
#pragma unroll
        for (int r = 0; r < 4; ++r) {
          const int row = m0 + wm * 64 + mt * 16 + kg * 4 + r;
          float v = acc[mt][nt][r];
          v = v / (1.f + __expf(-v));
          OUT[(size_t)row * 2048 + col] = v;
        }
      }
    return;
  }
  // --------------------------- scan (1 wave) --------------------------------
  if (threadIdx.x >= 64) return;
  const int bid = blockIdx.x;          // b*32 + h
  const int h = bid & 31, b = bid >> 5;
  const int lane = threadIdx.x;
  const int fr = lane & 15, kg = lane >> 4;

  // LDS: s-pairs [CHUNK] stride 176B; xT [CHUNK] stride 304B (2-way banks=free)
  char* sp = smem;                 // 11264 B
  char* xT = smem + 11264;         // 19456 B

  // A_w fragments (v4-verified): lane(fr,kg) holds A[h][mb*16+fr][kt*32+kg*8+j]
  bf16x8 afr[4][2];
  {
    const float* Ah = Aw + (size_t)h * 64 * 64;
#pragma unroll
    for (int mb = 0; mb < 4; ++mb)
#pragma unroll
      for (int kt = 0; kt < 2; ++kt) {
        const float* p = &Ah[(size_t)(mb * 16 + fr) * 64 + kt * 32 + kg * 8];
        float4 v0 = *(const float4*)p;
        float4 v1 = *(const float4*)(p + 4);
        bf16x8 f;
        f[0] = (short)f2bf(v0.x); f[1] = (short)f2bf(v0.y);
        f[2] = (short)f2bf(v0.z); f[3] = (short)f2bf(v0.w);
        f[4] = (short)f2bf(v1.x); f[5] = (short)f2bf(v1.y);
        f[6] = (short)f2bf(v1.z); f[7] = (short)f2bf(v1.w);
        afr[mb][kt] = f;
      }
  }

  const float* dBp = dBt + (size_t)(bid * 64 + lane) * L_SEQ;   // own row
  unsigned short* stp = states + (size_t)bid * L_SEQ * 64 + lane;
  const float* dtp = dt + b * L_SEQ;
  const int spw = (lane >> 1) * 4;             // s-pair dword byte offset

  float scs = 0.f;                             // carried exact state
  for (int c = 0; c < L_SEQ / CHUNK; ++c) {
    const int l0 = c * CHUNK;
    float Dv[CHUNK], E[CHUNK];
#pragma unroll
    for (int t = 0; t < CHUNK / 4; ++t) {
      float4 q = *(const float4*)&dBp[l0 + t * 4];
      Dv[4 * t] = q.x; Dv[4 * t + 1] = q.y; Dv[4 * t + 2] = q.z; Dv[4 * t + 3] = q.w;
    }
#pragma unroll
    for (int l = 0; l < CHUNK; ++l) E[l] = 1.0f;
    float dtq[4];
#pragma unroll
    for (int tb = 0; tb < 4; ++tb) dtq[tb] = dtp[l0 + tb * 16 + fr];

    for (int it = 0; it < ITERS; ++it) {
      // ---- scan with LDS pair writes (s_l BEFORE update at step l) ----
      float s = scs;
#pragma unroll
      for (int l = 0; l < CHUNK; ++l) {
        float sn = qperm<0xB1>(s);
        float lo = (lane & 1) ? sn : s;
        float hi = (lane & 1) ? s : sn;
        unsigned pw;
        asm("v_cvt_pk_bf16_f32 %0, %1, %2" : "=v"(pw) : "v"(lo), "v"(hi));
        *(unsigned*)(sp + l * 176 + spw) = pw;
        s = __builtin_fmaf(E[l], s, Dv[l]);
      }
      asm volatile("" ::: "memory");
      // ---- batched matvec: X[m][t] = A_w · S ----
      bf16x8 bf[4][2];
#pragma unroll
      for (int tb = 0; tb < 4; ++tb)
#pragma unroll
        for (int kt = 0; kt < 2; ++kt)
          bf[tb][kt] = *(const bf16x8*)(sp + (tb * 16 + fr) * 176 + (kt * 16 + kg * 4) * 4);
      f32x4 acc[4][4];
#pragma unroll
      for (int mb = 0; mb < 4; ++mb)
#pragma unroll
        for (int tb = 0; tb < 4; ++tb) {
          f32x4 z = {0.f, 0.f, 0.f, 0.f};
          f32x4 t0 = __builtin_amdgcn_mfma_f32_16x16x32_bf16(afr[mb][0], bf[tb][0], z, 0, 0, 0);
          acc[mb][tb] = __builtin_amdgcn_mfma_f32_16x16x32_bf16(afr[mb][1], bf[tb][1], t0, 0, 0, 0);
        }
      // scale by dt (t = tb*16+fr per lane) and write xT[t][m]
#pragma unroll
      for (int mb = 0; mb < 4; ++mb)
#pragma unroll
        for (int tb = 0; tb < 4; ++tb) {
          f32x4 v = acc[mb][tb];
          v[0] *= dtq[tb]; v[1] *= dtq[tb]; v[2] *= dtq[tb]; v[3] *= dtq[tb];
          *(f32x4*)(xT + (tb * 16 + fr) * 304 + (mb * 16 + kg * 4) * 4) = v;
        }
      asm volatile("" ::: "memory");
      // ---- readback own-m time series, Taylor exp -> E ----
#pragma unroll
      for (int l = 0; l < CHUNK; ++l) {
        float x = *(const float*)(xT + l * 304 + lane * 4);
        E[l] = __builtin_fmaf(x * x, 0.5f, 1.0f + x);
      }
    }
    // ---- final scan with converged E: store states ----
    {
      float s = scs;
#pragma unroll
      for (int l = 0; l < CHUNK; ++l) {
        s = __builtin_fmaf(E[l], s, Dv[l]);
        stp[(size_t)(l0 + l) * 64] = f2bf(s);
      }
      scs = s;
    }
  }
}

// ----- C projection + x*D + silu(gate) multiply; writes hs1 (b,l,hid) f32 -----
__global__ __launch_bounds__(256) void proj_k(const unsigned short* __restrict__ st,
                                              const unsigned short* __restrict__ cwb,
                                              const float* __restrict__ xin,
                                              const float* __restrict__ Dp,
                                              const float* __restrict__ gs,
                                              float* __restrict__ hs1) {
  const int l0 = blockIdx.x * 64, h = blockIdx.y, b = blockIdx.z;
  const int tid = threadIdx.x, lane = tid & 63, wid = tid >> 6;
  const int fr = lane & 15, kg = lane >> 4, wm = wid;
  f32x4 acc[4] = {};
#pragma unroll
  for (int ks = 0; ks < 2; ++ks) {
    bf16x8 a = *(const bf16x8*)&st[((size_t)(b * NH + h) * L_SEQ + l0 + wm * 16 + fr) * 64 + ks * 32 + kg * 8];
#pragma unroll
    for (int nt = 0; nt < 4; ++nt) {
      bf16x8 bq = *(const bf16x8*)&cwb[(size_t)(h * 64 + nt * 16 + fr) * 64 + ks * 32 + kg * 8];
      acc[nt] = __builtin_amdgcn_mfma_f32_16x16x32_bf16(a, bq, acc[nt], 0, 0, 0);
    }
  }
  const float Dh = Dp[h];
#pragma unroll
  for (int nt = 0; nt < 4; ++nt) {
    const int ccol = h * 64 + nt * 16 + fr;
#pragma unroll
    for (int r = 0; r < 4; ++r) {
      const int lg = l0 + wm * 16 + kg * 4 + r;
      const size_t idx = (size_t)(b * L_SEQ + lg) * HIDN + ccol;
      float v = acc[nt][r] + xin[idx] * Dh;
      hs1[idx] = v * gs[idx];
    }
  }
}

// --------------------- gated RMSNorm -> bf16 rows -----------------------------
__global__ __launch_bounds__(256) void norm_k(const float* __restrict__ hs1,
                                              const float* __restrict__ nw,
                                              unsigned short* __restrict__ out) {
  const int row = blockIdx.x;
  const float* p = hs1 + (size_t)row * HIDN;
  const int c0 = threadIdx.x * 8;
  float4 u0 = *(const float4*)&p[c0];
  float4 u1 = *(const float4*)&p[c0 + 4];
  float ss = u0.x * u0.x + u0.y * u0.y + u0.z * u0.z + u0.w * u0.w +
             u1.x * u1.x + u1.y * u1.y + u1.z * u1.z + u1.w * u1.w;
#pragma unroll
  for (int off = 32; off; off >>= 1) ss += __shfl_xor(ss, off);
  __shared__ float pr[4];
  if ((threadIdx.x & 63) == 0) pr[threadIdx.x >> 6] = ss;
  __syncthreads();
  float tot = pr[0] + pr[1] + pr[2] + pr[3];
  float rs = rsqrtf(tot * (1.f / HIDN) + 1e-6f);
  bf16x8 res;
  res[0] = (short)f2bf(nw[c0 + 0] * u0.x * rs);
  res[1] = (short)f2bf(nw[c0 + 1] * u0.y * rs);
  res[2] = (short)f2bf(nw[c0 + 2] * u0.z * rs);
  res[3] = (short)f2bf(nw[c0 + 3] * u0.w * rs);
  res[4] = (short)f2bf(nw[c0 + 4] * u1.x * rs);
  res[5] = (short)f2bf(nw[c0 + 5] * u1.y * rs);
  res[6] = (short)f2bf(nw[c0 + 6] * u1.z * rs);
  res[7] = (short)f2bf(nw[c0 + 7] * u1.w * rs);
  *(bf16x8*)&out[(size_t)row * HIDN + c0] = res;
}

extern "C" void kernel_launch(void* const* d_in, const int* in_sizes, int n_in,
                              void* d_out, int out_size, void* d_ws, size_t ws_size,
                              hipStream_t stream) {
  const float* x  = (const float*)d_in[0];
  const float* dt = (const float*)d_in[1];
  const float* gw = (const float*)d_in[2];
  const float* Aw = (const float*)d_in[3];
  const float* cw = (const float*)d_in[4];
  const float* cb = (const float*)d_in[5];
  const float* Cw = (const float*)d_in[6];
  const float* Dp = (const float*)d_in[7];
  const float* nw = (const float*)d_in[8];
  const float* ow = (const float*)d_in[9];
  float* out = (float*)d_out;

  // workspace layout (bytes). states overlays hsb; hs1 overlays dBt.
  char* w = (char*)d_ws;
  unsigned short* xb   = (unsigned short*)(w);                // 32MB
  unsigned short* gwb  = (unsigned short*)(w + 33554432);     // 8MB
  unsigned short* owb  = (unsigned short*)(w + 41943040);     // 8MB
  unsigned short* wret = (unsigned short*)(w + 50331648);     // 1MB
  unsigned short* cwb  = (unsigned short*)(w + 51380224);     // 256KB
  float*          dBt  = (float*)(w + 52428800);              // 64MB
  float*          hs1  = dBt;                                 // overlay (after scan)
  unsigned short* hsb  = (unsigned short*)(w + 119537664);    // 32MB
  unsigned short* stb  = hsb;                                 // overlay (before norm)
  if (ws_size < 153092096) return;

  cvt_bf16_k<<<2048, 256, 0, stream>>>(x, xb, 16777216 / 4);
  cvt_bf16_k<<<1024, 256, 0, stream>>>(gw, gwb, 4194304 / 4);
  cvt_bf16_k<<<1024, 256, 0, stream>>>(ow, owb, 4194304 / 4);
  cvt_bf16_k<<<128, 256, 0, stream>>>(Cw, cwb, 131072 / 4);
  wret_k<<<2048, 256, 0, stream>>>(cw, wret);

  conv_k<<<dim3(32, 32, 4), 256, 0, stream>>>(xb, wret, cb, dt, dBt);
  // chunked fixed-point scan (blocks 0..127) || gate GEMM (blocks 128..1151)
  scan_gemm_k<<<1152, 256, 0, stream>>>(dBt, Aw, dt, stb, xb, gwb, out);
  proj_k<<<dim3(32, 32, 4), 256, 0, stream>>>(stb, cwb, x, Dp, out, hs1);
  norm_k<<<8192, 256, 0, stream>>>(hs1, nw, hsb);
  gemm_xwt_k<0><<<dim3(64, 16), 256, 0, stream>>>(hsb, owb, out, 8192, 2048, 2048);
}

// Round 14
// 529.383 us; speedup vs baseline: 1.8175x; 1.0434x over previous
//
#include <hip/hip_runtime.h>
#include <hip/hip_bf16.h>

#define L_SEQ 2048
#define HIDN  2048
#define NH    32
#define BATCHN 4
#define CHUNK 64
#define ITERS 1   // fixed-point correction iterations per chunk

using bf16x8 = __attribute__((ext_vector_type(8))) short;
using f32x4  = __attribute__((ext_vector_type(4))) float;

__device__ __forceinline__ unsigned short f2bf(float f) {
  union { float f; unsigned u; } v; v.f = f;
  unsigned r = v.u + 0x7fffu + ((v.u >> 16) & 1u);
  return (unsigned short)(r >> 16);
}

__device__ __forceinline__ float bf2f(unsigned short u) {
  unsigned v = ((unsigned)u) << 16;
  return __builtin_bit_cast(float, v);
}

__device__ __forceinline__ void gl_lds16(const void* g, void* l) {
  __builtin_amdgcn_global_load_lds(
      (const __attribute__((address_space(1))) unsigned int*)g,
      (__attribute__((address_space(3))) unsigned int*)l, 16, 0, 0);
}

template <int CTRL>
__device__ __forceinline__ float qperm(float x) {
  int xi = __builtin_bit_cast(int, x);
  int yi = __builtin_amdgcn_update_dpp(0, xi, CTRL, 0xF, 0xF, true);
  return __builtin_bit_cast(float, yi);
}

// ---------------- f32 -> bf16 convert (grid-stride over n/4 float4s) ----------
__global__ __launch_bounds__(256) void cvt_bf16_k(const float* __restrict__ in,
                                                  unsigned short* __restrict__ out, int n4) {
  for (int i = blockIdx.x * 256 + threadIdx.x; i < n4; i += gridDim.x * 256) {
    float4 v = *(const float4*)&in[(size_t)i * 4];
    ushort4 o;
    o.x = f2bf(v.x); o.y = f2bf(v.y); o.z = f2bf(v.z); o.w = f2bf(v.w);
    *(ushort4*)&out[(size_t)i * 4] = o;
  }
}

// -------- conv weight transform: wreT[o][k*64+i] = conv_w[o][i][k] (bf16) -----
__global__ __launch_bounds__(256) void wret_k(const float* __restrict__ cw,
                                              unsigned short* __restrict__ out) {
  int idx = blockIdx.x * 256 + threadIdx.x;   // 2048*256 total
  int o = idx >> 8, q = idx & 255;
  int k = q >> 6, i = q & 63;
  out[idx] = f2bf(cw[o * 256 + i * 4 + k]);
}

// ---------------- GEMM: OUT[m][n] = sum_k X[m][k]*W[n][k], bf16 MFMA ----------
template <int SILU>
__global__ __launch_bounds__(256) void gemm_xwt_k(const unsigned short* __restrict__ X,
                                                  const unsigned short* __restrict__ W,
                                                  float* __restrict__ OUT,
                                                  int M, int N, int K) {
  __shared__ __align__(16) unsigned short As[128 * 32];
  __shared__ __align__(16) unsigned short Bs[128 * 32];
  const int tid = threadIdx.x, lane = tid & 63, wid = tid >> 6;
  const int wm = wid >> 1, wn = wid & 1;
  const int lin = blockIdx.y * gridDim.x + blockIdx.x;
  const int cpx = (gridDim.x * gridDim.y) >> 3;
  const int swz = (lin & 7) * cpx + (lin >> 3);
  const int m0 = (swz % gridDim.x) * 128, n0 = (swz / gridDim.x) * 128;
  const int fr = lane & 15, kg = lane >> 4;
  const int sr = lane >> 2, sc = (lane & 3) * 8;
  f32x4 acc[4][4] = {};
  for (int k0 = 0; k0 < K; k0 += 32) {
    const int cA0 = wid * 16, cA1 = (wid + 4) * 16;
    gl_lds16(&X[(size_t)(m0 + cA0 + sr) * K + k0 + sc], &As[cA0 * 32]);
    gl_lds16(&X[(size_t)(m0 + cA1 + sr) * K + k0 + sc], &As[cA1 * 32]);
    gl_lds16(&W[(size_t)(n0 + cA0 + sr) * K + k0 + sc], &Bs[cA0 * 32]);
    gl_lds16(&W[(size_t)(n0 + cA1 + sr) * K + k0 + sc], &Bs[cA1 * 32]);
    __syncthreads();
    bf16x8 af[4], bfr[4];
#pragma unroll
    for (int t = 0; t < 4; ++t) {
      af[t]  = *(const bf16x8*)&As[(wm * 64 + t * 16 + fr) * 32 + kg * 8];
      bfr[t] = *(const bf16x8*)&Bs[(wn * 64 + t * 16 + fr) * 32 + kg * 8];
    }
#pragma unroll
    for (int mt = 0; mt < 4; ++mt)
#pragma unroll
      for (int nt = 0; nt < 4; ++nt)
        acc[mt][nt] = __builtin_amdgcn_mfma_f32_16x16x32_bf16(af[mt], bfr[nt], acc[mt][nt], 0, 0, 0);
    __syncthreads();
  }
#pragma unroll
  for (int mt = 0; mt < 4; ++mt)
#pragma unroll
    for (int nt = 0; nt < 4; ++nt) {
      const int col = n0 + wn * 64 + nt * 16 + fr;
#pragma unroll
      for (int r = 0; r < 4; ++r) {
        const int row = m0 + wm * 64 + mt * 16 + kg * 4 + r;
        float v = acc[mt][nt][r];
        if (SILU) v = v / (1.f + __expf(-v));
        OUT[(size_t)row * N + col] = v;
      }
    }
}

// --- grouped causal conv as MFMA GEMM; epilogue: (Bc+bias)*dt -> dBt[row][l] --
__global__ __launch_bounds__(256) void conv_k(const unsigned short* __restrict__ xb,
                                              const unsigned short* __restrict__ wreT,
                                              const float* __restrict__ conv_b,
                                              const float* __restrict__ dt,
                                              float* __restrict__ dBt) {
  __shared__ __align__(16) unsigned short x_lds[67 * 64];
  const int l0 = blockIdx.x * 64, g = blockIdx.y, b = blockIdx.z;
  const int tid = threadIdx.x, lane = tid & 63, wid = tid >> 6;
  {
    const int r = tid >> 3, ch = (tid & 7) * 8;
#pragma unroll
    for (int pass = 0; pass < 3; ++pass) {
      int rr = r + pass * 32;
      if (rr < 67) {
        int lg = l0 - 3 + rr;
        bf16x8 v = {};
        if (lg >= 0) v = *(const bf16x8*)&xb[(size_t)(b * L_SEQ + lg) * HIDN + g * 64 + ch];
        *(bf16x8*)&x_lds[rr * 64 + ch] = v;
      }
    }
  }
  __syncthreads();
  const int fr = lane & 15, kg = lane >> 4, wm = wid;
  f32x4 acc[4] = {};
#pragma unroll
  for (int ks = 0; ks < 8; ++ks) {
    bf16x8 a = *(const bf16x8*)&x_lds[(wm * 16 + fr + (ks >> 1)) * 64 + (ks & 1) * 32 + kg * 8];
#pragma unroll
    for (int nt = 0; nt < 4; ++nt) {
      bf16x8 bq = *(const bf16x8*)&wreT[(size_t)(g * 64 + nt * 16 + fr) * 256 + ks * 32 + kg * 8];
      acc[nt] = __builtin_amdgcn_mfma_f32_16x16x32_bf16(a, bq, acc[nt], 0, 0, 0);
    }
  }
  const int lgb = l0 + wm * 16 + kg * 4;
  const float4 dt4 = *(const float4*)&dt[b * L_SEQ + lgb];
#pragma unroll
  for (int nt = 0; nt < 4; ++nt) {
    const int o = nt * 16 + fr;
    const float bias = conv_b[g * 64 + o];
    float4 vv;
    vv.x = (acc[nt][0] + bias) * dt4.x;
    vv.y = (acc[nt][1] + bias) * dt4.y;
    vv.z = (acc[nt][2] + bias) * dt4.z;
    vv.w = (acc[nt][3] + bias) * dt4.w;
    *(float4*)&dBt[((size_t)(b * NH + g) * 64 + o) * L_SEQ + lgb] = vv;
  }
}

// ---- FUSED: blocks 0..127 = chunked fixed-point scan (1 wave each);  --------
// ---- blocks 128..1151 = gate GEMM, silu -> bf16 (hidden under the scan). ----
__global__ __launch_bounds__(256) void scan_gemm_k(const float* __restrict__ dBt,
                                                   const float* __restrict__ Aw,
                                                   const float* __restrict__ dt,
                                                   unsigned short* __restrict__ states,
                                                   const unsigned short* __restrict__ X,
                                                   const unsigned short* __restrict__ W,
                                                   unsigned short* __restrict__ GOUT) {
  __shared__ __align__(16) char smem[30720];
  if (blockIdx.x >= 128) {
    // ----------------- gate GEMM tile (grid 64 x 16, swizzled) ---------------
    unsigned short* As = (unsigned short*)smem;            // 8KB
    unsigned short* Bs = (unsigned short*)(smem + 8192);   // 8KB
    const int tid = threadIdx.x, lane = tid & 63, wid = tid >> 6;
    const int wm = wid >> 1, wn = wid & 1;
    const int gb = blockIdx.x - 128;              // 0..1023
    const int swz = (gb & 7) * 128 + (gb >> 3);   // XCD-bijective
    const int m0 = (swz & 63) * 128;
    const int n0 = (swz >> 6) * 128;
    const int fr = lane & 15, kg = lane >> 4;
    const int sr = lane >> 2, sc = (lane & 3) * 8;
    f32x4 acc[4][4] = {};
    for (int k0 = 0; k0 < 2048; k0 += 32) {
      const int cA0 = wid * 16, cA1 = (wid + 4) * 16;
      gl_lds16(&X[(size_t)(m0 + cA0 + sr) * 2048 + k0 + sc], &As[cA0 * 32]);
      gl_lds16(&X[(size_t)(m0 + cA1 + sr) * 2048 + k0 + sc], &As[cA1 * 32]);
      gl_lds16(&W[(size_t)(n0 + cA0 + sr) * 2048 + k0 + sc], &Bs[cA0 * 32]);
      gl_lds16(&W[(size_t)(n0 + cA1 + sr) * 2048 + k0 + sc], &Bs[cA1 * 32]);
      __syncthreads();
      bf16x8 af[4], bfr[4];
#pragma unroll
      for (int t = 0; t < 4; ++t) {
        af[t]  = *(const bf16x8*)&As[(wm * 64 + t * 16 + fr) * 32 + kg * 8];
        bfr[t] = *(const bf16x8*)&Bs[(wn * 64 + t * 16 + fr) * 32 + kg * 8];
      }
#pragma unroll
      for (int mt = 0; mt < 4; ++mt)
#pragma unroll
        for (int nt = 0; nt < 4; ++nt)
          acc[mt][nt] = __builtin_amdgcn_mfma_f32_16x16x32_bf16(af[mt], bfr[nt], acc[mt][nt], 0, 0, 0);
      __syncthreads();
    }
#pragma unroll
    for (int mt = 0; mt < 4; ++mt)
#pragma unroll
      for (int nt = 0; nt < 4; ++nt) {
        const int col = n0 + wn * 64 + nt * 16 + fr;
#pragma unroll
        for (int r = 0; r < 4; ++r) {
          const int row = m0 + wm * 64 + mt * 16 + kg * 4 + r;
          float v = acc[mt][nt][r];
          v = v / (1.f + __expf(-v));
          GOUT[(size_t)row * 2048 + col] = f2bf(v);
        }
      }
    return;
  }
  // --------------------------- scan (1 wave) --------------------------------
  if (threadIdx.x >= 64) return;
  const int bid = blockIdx.x;          // b*32 + h
  const int h = bid & 31, b = bid >> 5;
  const int lane = threadIdx.x;
  const int fr = lane & 15, kg = lane >> 4;

  // LDS: s-pairs [CHUNK] stride 176B; xT [CHUNK] stride 304B (2-way banks=free)
  char* sp = smem;                 // 11264 B
  char* xT = smem + 11264;         // 19456 B

  // A_w fragments (v4-verified): lane(fr,kg) holds A[h][mb*16+fr][kt*32+kg*8+j]
  bf16x8 afr[4][2];
  {
    const float* Ah = Aw + (size_t)h * 64 * 64;
#pragma unroll
    for (int mb = 0; mb < 4; ++mb)
#pragma unroll
      for (int kt = 0; kt < 2; ++kt) {
        const float* p = &Ah[(size_t)(mb * 16 + fr) * 64 + kt * 32 + kg * 8];
        float4 v0 = *(const float4*)p;
        float4 v1 = *(const float4*)(p + 4);
        bf16x8 f;
        f[0] = (short)f2bf(v0.x); f[1] = (short)f2bf(v0.y);
        f[2] = (short)f2bf(v0.z); f[3] = (short)f2bf(v0.w);
        f[4] = (short)f2bf(v1.x); f[5] = (short)f2bf(v1.y);
        f[6] = (short)f2bf(v1.z); f[7] = (short)f2bf(v1.w);
        afr[mb][kt] = f;
      }
  }

  const float* dBp = dBt + (size_t)(bid * 64 + lane) * L_SEQ;   // own row
  unsigned short* stp = states + (size_t)bid * L_SEQ * 64 + lane;
  const float* dtp = dt + b * L_SEQ;
  const int spw = (lane >> 1) * 4;             // s-pair dword byte offset

  float scs = 0.f;                             // carried exact state
  for (int c = 0; c < L_SEQ / CHUNK; ++c) {
    const int l0 = c * CHUNK;
    float Dv[CHUNK], E[CHUNK];
#pragma unroll
    for (int t = 0; t < CHUNK / 4; ++t) {
      float4 q = *(const float4*)&dBp[l0 + t * 4];
      Dv[4 * t] = q.x; Dv[4 * t + 1] = q.y; Dv[4 * t + 2] = q.z; Dv[4 * t + 3] = q.w;
    }
#pragma unroll
    for (int l = 0; l < CHUNK; ++l) E[l] = 1.0f;
    float dtq[4];
#pragma unroll
    for (int tb = 0; tb < 4; ++tb) dtq[tb] = dtp[l0 + tb * 16 + fr];

    for (int it = 0; it < ITERS; ++it) {
      // ---- scan with LDS pair writes (s_l BEFORE update at step l) ----
      float s = scs;
#pragma unroll
      for (int l = 0; l < CHUNK; ++l) {
        float sn = qperm<0xB1>(s);
        float lo = (lane & 1) ? sn : s;
        float hi = (lane & 1) ? s : sn;
        unsigned pw;
        asm("v_cvt_pk_bf16_f32 %0, %1, %2" : "=v"(pw) : "v"(lo), "v"(hi));
        *(unsigned*)(sp + l * 176 + spw) = pw;
        s = __builtin_fmaf(E[l], s, Dv[l]);
      }
      asm volatile("" ::: "memory");
      // ---- batched matvec: X[m][t] = A_w · S ----
      bf16x8 bf[4][2];
#pragma unroll
      for (int tb = 0; tb < 4; ++tb)
#pragma unroll
        for (int kt = 0; kt < 2; ++kt)
          bf[tb][kt] = *(const bf16x8*)(sp + (tb * 16 + fr) * 176 + (kt * 16 + kg * 4) * 4);
      f32x4 acc[4][4];
#pragma unroll
      for (int mb = 0; mb < 4; ++mb)
#pragma unroll
        for (int tb = 0; tb < 4; ++tb) {
          f32x4 z = {0.f, 0.f, 0.f, 0.f};
          f32x4 t0 = __builtin_amdgcn_mfma_f32_16x16x32_bf16(afr[mb][0], bf[tb][0], z, 0, 0, 0);
          acc[mb][tb] = __builtin_amdgcn_mfma_f32_16x16x32_bf16(afr[mb][1], bf[tb][1], t0, 0, 0, 0);
        }
      // scale by dt (t = tb*16+fr per lane) and write xT[t][m]
#pragma unroll
      for (int mb = 0; mb < 4; ++mb)
#pragma unroll
        for (int tb = 0; tb < 4; ++tb) {
          f32x4 v = acc[mb][tb];
          v[0] *= dtq[tb]; v[1] *= dtq[tb]; v[2] *= dtq[tb]; v[3] *= dtq[tb];
          *(f32x4*)(xT + (tb * 16 + fr) * 304 + (mb * 16 + kg * 4) * 4) = v;
        }
      asm volatile("" ::: "memory");
      // ---- readback own-m time series, Taylor exp -> E ----
#pragma unroll
      for (int l = 0; l < CHUNK; ++l) {
        float x = *(const float*)(xT + l * 304 + lane * 4);
        E[l] = __builtin_fmaf(x * x, 0.5f, 1.0f + x);
      }
    }
    // ---- final scan with converged E: store states ----
    {
      float s = scs;
#pragma unroll
      for (int l = 0; l < CHUNK; ++l) {
        s = __builtin_fmaf(E[l], s, Dv[l]);
        stp[(size_t)(l0 + l) * 64] = f2bf(s);
      }
      scs = s;
    }
  }
}

// -- C projection + x*D + silu(gate) multiply; writes hsb (b,l,hid) bf16 -------
__global__ __launch_bounds__(256) void proj_k(const unsigned short* __restrict__ st,
                                              const unsigned short* __restrict__ cwb,
                                              const unsigned short* __restrict__ xbp,
                                              const float* __restrict__ Dp,
                                              const unsigned short* __restrict__ gsb,
                                              unsigned short* __restrict__ hsb) {
  const int l0 = blockIdx.x * 64, h = blockIdx.y, b = blockIdx.z;
  const int tid = threadIdx.x, lane = tid & 63, wid = tid >> 6;
  const int fr = lane & 15, kg = lane >> 4, wm = wid;
  f32x4 acc[4] = {};
#pragma unroll
  for (int ks = 0; ks < 2; ++ks) {
    bf16x8 a = *(const bf16x8*)&st[((size_t)(b * NH + h) * L_SEQ + l0 + wm * 16 + fr) * 64 + ks * 32 + kg * 8];
#pragma unroll
    for (int nt = 0; nt < 4; ++nt) {
      bf16x8 bq = *(const bf16x8*)&cwb[(size_t)(h * 64 + nt * 16 + fr) * 64 + ks * 32 + kg * 8];
      acc[nt] = __builtin_amdgcn_mfma_f32_16x16x32_bf16(a, bq, acc[nt], 0, 0, 0);
    }
  }
  const float Dh = Dp[h];
#pragma unroll
  for (int nt = 0; nt < 4; ++nt) {
    const int ccol = h * 64 + nt * 16 + fr;
#pragma unroll
    for (int r = 0; r < 4; ++r) {
      const int lg = l0 + wm * 16 + kg * 4 + r;
      const size_t idx = (size_t)(b * L_SEQ + lg) * HIDN + ccol;
      float v = acc[nt][r] + bf2f(xbp[idx]) * Dh;
      hsb[idx] = f2bf(v * bf2f(gsb[idx]));
    }
  }
}

// ------------ gated RMSNorm, bf16 in / bf16 out (in-place) --------------------
__global__ __launch_bounds__(256) void norm_k(unsigned short* __restrict__ hsb,
                                              const float* __restrict__ nw) {
  const int row = blockIdx.x;
  unsigned short* p = hsb + (size_t)row * HIDN;
  const int c0 = threadIdx.x * 8;
  bf16x8 u = *(const bf16x8*)&p[c0];
  float f[8];
#pragma unroll
  for (int i = 0; i < 8; ++i) f[i] = bf2f((unsigned short)u[i]);
  float ss = f[0] * f[0] + f[1] * f[1] + f[2] * f[2] + f[3] * f[3] +
             f[4] * f[4] + f[5] * f[5] + f[6] * f[6] + f[7] * f[7];
#pragma unroll
  for (int off = 32; off; off >>= 1) ss += __shfl_xor(ss, off);
  __shared__ float pr[4];
  if ((threadIdx.x & 63) == 0) pr[threadIdx.x >> 6] = ss;
  __syncthreads();
  float tot = pr[0] + pr[1] + pr[2] + pr[3];
  float rs = rsqrtf(tot * (1.f / HIDN) + 1e-6f);
  bf16x8 res;
#pragma unroll
  for (int i = 0; i < 8; ++i) res[i] = (short)f2bf(nw[c0 + i] * f[i] * rs);
  *(bf16x8*)&p[c0] = res;
}

extern "C" void kernel_launch(void* const* d_in, const int* in_sizes, int n_in,
                              void* d_out, int out_size, void* d_ws, size_t ws_size,
                              hipStream_t stream) {
  const float* x  = (const float*)d_in[0];
  const float* dt = (const float*)d_in[1];
  const float* gw = (const float*)d_in[2];
  const float* Aw = (const float*)d_in[3];
  const float* cw = (const float*)d_in[4];
  const float* cb = (const float*)d_in[5];
  const float* Cw = (const float*)d_in[6];
  const float* Dp = (const float*)d_in[7];
  const float* nw = (const float*)d_in[8];
  const float* ow = (const float*)d_in[9];
  float* out = (float*)d_out;

  // workspace (bytes): hsb overlays dBt (dead after scan); stb has own slot.
  // gate bf16 lives in d_out's first 32MB (dead before out-GEMM writes).
  char* w = (char*)d_ws;
  unsigned short* xb   = (unsigned short*)(w);                // 32MB
  unsigned short* gwb  = (unsigned short*)(w + 33554432);     // 8MB
  unsigned short* owb  = (unsigned short*)(w + 41943040);     // 8MB
  unsigned short* wret = (unsigned short*)(w + 50331648);     // 1MB
  unsigned short* cwb  = (unsigned short*)(w + 51380224);     // 256KB
  float*          dBt  = (float*)(w + 52428800);              // 64MB
  unsigned short* hsb  = (unsigned short*)(w + 52428800);     // overlay (after scan)
  unsigned short* stb  = (unsigned short*)(w + 119537664);    // 32MB
  unsigned short* gsb  = (unsigned short*)d_out;              // gate bf16, 32MB
  if (ws_size < 153092096) return;

  cvt_bf16_k<<<2048, 256, 0, stream>>>(x, xb, 16777216 / 4);
  cvt_bf16_k<<<1024, 256, 0, stream>>>(gw, gwb, 4194304 / 4);
  cvt_bf16_k<<<1024, 256, 0, stream>>>(ow, owb, 4194304 / 4);
  cvt_bf16_k<<<128, 256, 0, stream>>>(Cw, cwb, 131072 / 4);
  wret_k<<<2048, 256, 0, stream>>>(cw, wret);

  conv_k<<<dim3(32, 32, 4), 256, 0, stream>>>(xb, wret, cb, dt, dBt);
  // chunked fixed-point scan (blocks 0..127) || gate GEMM (blocks 128..1151)
  scan_gemm_k<<<1152, 256, 0, stream>>>(dBt, Aw, dt, stb, xb, gwb, gsb);
  proj_k<<<dim3(32, 32, 4), 256, 0, stream>>>(stb, cwb, xb, Dp, gsb, hsb);
  norm_k<<<8192, 256, 0, stream>>>(hsb, nw);
  gemm_xwt_k<0><<<dim3(64, 16), 256, 0, stream>>>(hsb, owb, out, 8192, 2048, 2048);
}

// Round 15
// 522.114 us; speedup vs baseline: 1.8428x; 1.0139x over previous
//
#include <hip/hip_runtime.h>
#include <hip/hip_bf16.h>

#define L_SEQ 2048
#define HIDN  2048
#define NH    32
#define BATCHN 4
#define CHUNK 64
#define ITERS 1   // fixed-point correction iterations per chunk

using bf16x8 = __attribute__((ext_vector_type(8))) short;
using f32x4  = __attribute__((ext_vector_type(4))) float;

__device__ __forceinline__ unsigned short f2bf(float f) {
  union { float f; unsigned u; } v; v.f = f;
  unsigned r = v.u + 0x7fffu + ((v.u >> 16) & 1u);
  return (unsigned short)(r >> 16);
}

__device__ __forceinline__ float bf2f(unsigned short u) {
  unsigned v = ((unsigned)u) << 16;
  return __builtin_bit_cast(float, v);
}

__device__ __forceinline__ void gl_lds16(const void* g, void* l) {
  __builtin_amdgcn_global_load_lds(
      (const __attribute__((address_space(1))) unsigned int*)g,
      (__attribute__((address_space(3))) unsigned int*)l, 16, 0, 0);
}

template <int CTRL>
__device__ __forceinline__ float qperm(float x) {
  int xi = __builtin_bit_cast(int, x);
  int yi = __builtin_amdgcn_update_dpp(0, xi, CTRL, 0xF, 0xF, true);
  return __builtin_bit_cast(float, yi);
}

// ---------------- f32 -> bf16 convert (grid-stride over n/4 float4s) ----------
__global__ __launch_bounds__(256) void cvt_bf16_k(const float* __restrict__ in,
                                                  unsigned short* __restrict__ out, int n4) {
  for (int i = blockIdx.x * 256 + threadIdx.x; i < n4; i += gridDim.x * 256) {
    float4 v = *(const float4*)&in[(size_t)i * 4];
    ushort4 o;
    o.x = f2bf(v.x); o.y = f2bf(v.y); o.z = f2bf(v.z); o.w = f2bf(v.w);
    *(ushort4*)&out[(size_t)i * 4] = o;
  }
}

// ---- out-weight prep: owb[n][k] = bf16(ow[n][k] * nw[k])  (norm-weight fold) -
__global__ __launch_bounds__(256) void ownw_k(const float* __restrict__ ow,
                                              const float* __restrict__ nw,
                                              unsigned short* __restrict__ out) {
  int i = blockIdx.x * 256 + threadIdx.x;    // over 4194304/4 float4s
  float4 v = *(const float4*)&ow[(size_t)i * 4];
  int k0 = (i * 4) & 2047;
  ushort4 o;
  o.x = f2bf(v.x * nw[k0 + 0]); o.y = f2bf(v.y * nw[k0 + 1]);
  o.z = f2bf(v.z * nw[k0 + 2]); o.w = f2bf(v.w * nw[k0 + 3]);
  *(ushort4*)&out[(size_t)i * 4] = o;
}

// -------- conv weight transform: wreT[o][k*64+i] = conv_w[o][i][k] (bf16) -----
__global__ __launch_bounds__(256) void wret_k(const float* __restrict__ cw,
                                              unsigned short* __restrict__ out) {
  int idx = blockIdx.x * 256 + threadIdx.x;   // 2048*256 total
  int o = idx >> 8, q = idx & 255;
  int k = q >> 6, i = q & 63;
  out[idx] = f2bf(cw[o * 256 + i * 4 + k]);
}

// --------- out GEMM: OUT[m][n] = rs[m] * sum_k X[m][k]*W[n][k] ----------------
__global__ __launch_bounds__(256) void gemm_out_k(const unsigned short* __restrict__ X,
                                                  const unsigned short* __restrict__ W,
                                                  const float* __restrict__ rs,
                                                  float* __restrict__ OUT,
                                                  int M, int N, int K) {
  __shared__ __align__(16) unsigned short As[128 * 32];
  __shared__ __align__(16) unsigned short Bs[128 * 32];
  const int tid = threadIdx.x, lane = tid & 63, wid = tid >> 6;
  const int wm = wid >> 1, wn = wid & 1;
  const int lin = blockIdx.y * gridDim.x + blockIdx.x;
  const int cpx = (gridDim.x * gridDim.y) >> 3;
  const int swz = (lin & 7) * cpx + (lin >> 3);
  const int m0 = (swz % gridDim.x) * 128, n0 = (swz / gridDim.x) * 128;
  const int fr = lane & 15, kg = lane >> 4;
  const int sr = lane >> 2, sc = (lane & 3) * 8;
  f32x4 acc[4][4] = {};
  for (int k0 = 0; k0 < K; k0 += 32) {
    const int cA0 = wid * 16, cA1 = (wid + 4) * 16;
    gl_lds16(&X[(size_t)(m0 + cA0 + sr) * K + k0 + sc], &As[cA0 * 32]);
    gl_lds16(&X[(size_t)(m0 + cA1 + sr) * K + k0 + sc], &As[cA1 * 32]);
    gl_lds16(&W[(size_t)(n0 + cA0 + sr) * K + k0 + sc], &Bs[cA0 * 32]);
    gl_lds16(&W[(size_t)(n0 + cA1 + sr) * K + k0 + sc], &Bs[cA1 * 32]);
    __syncthreads();
    bf16x8 af[4], bfr[4];
#pragma unroll
    for (int t = 0; t < 4; ++t) {
      af[t]  = *(const bf16x8*)&As[(wm * 64 + t * 16 + fr) * 32 + kg * 8];
      bfr[t] = *(const bf16x8*)&Bs[(wn * 64 + t * 16 + fr) * 32 + kg * 8];
    }
#pragma unroll
    for (int mt = 0; mt < 4; ++mt)
#pragma unroll
      for (int nt = 0; nt < 4; ++nt)
        acc[mt][nt] = __builtin_amdgcn_mfma_f32_16x16x32_bf16(af[mt], bfr[nt], acc[mt][nt], 0, 0, 0);
    __syncthreads();
  }
#pragma unroll
  for (int mt = 0; mt < 4; ++mt)
#pragma unroll
    for (int nt = 0; nt < 4; ++nt) {
      const int col = n0 + wn * 64 + nt * 16 + fr;
#pragma unroll
      for (int r = 0; r < 4; ++r) {
        const int row = m0 + wm * 64 + mt * 16 + kg * 4 + r;
        OUT[(size_t)row * N + col] = acc[mt][nt][r] * rs[row];
      }
    }
}

// --- grouped causal conv as MFMA GEMM; epilogue: (Bc+bias)*dt -> dBt[row][l] --
__global__ __launch_bounds__(256) void conv_k(const unsigned short* __restrict__ xb,
                                              const unsigned short* __restrict__ wreT,
                                              const float* __restrict__ conv_b,
                                              const float* __restrict__ dt,
                                              float* __restrict__ dBt) {
  __shared__ __align__(16) unsigned short x_lds[67 * 64];
  const int l0 = blockIdx.x * 64, g = blockIdx.y, b = blockIdx.z;
  const int tid = threadIdx.x, lane = tid & 63, wid = tid >> 6;
  {
    const int r = tid >> 3, ch = (tid & 7) * 8;
#pragma unroll
    for (int pass = 0; pass < 3; ++pass) {
      int rr = r + pass * 32;
      if (rr < 67) {
        int lg = l0 - 3 + rr;
        bf16x8 v = {};
        if (lg >= 0) v = *(const bf16x8*)&xb[(size_t)(b * L_SEQ + lg) * HIDN + g * 64 + ch];
        *(bf16x8*)&x_lds[rr * 64 + ch] = v;
      }
    }
  }
  __syncthreads();
  const int fr = lane & 15, kg = lane >> 4, wm = wid;
  f32x4 acc[4] = {};
#pragma unroll
  for (int ks = 0; ks < 8; ++ks) {
    bf16x8 a = *(const bf16x8*)&x_lds[(wm * 16 + fr + (ks >> 1)) * 64 + (ks & 1) * 32 + kg * 8];
#pragma unroll
    for (int nt = 0; nt < 4; ++nt) {
      bf16x8 bq = *(const bf16x8*)&wreT[(size_t)(g * 64 + nt * 16 + fr) * 256 + ks * 32 + kg * 8];
      acc[nt] = __builtin_amdgcn_mfma_f32_16x16x32_bf16(a, bq, acc[nt], 0, 0, 0);
    }
  }
  const int lgb = l0 + wm * 16 + kg * 4;
  const float4 dt4 = *(const float4*)&dt[b * L_SEQ + lgb];
#pragma unroll
  for (int nt = 0; nt < 4; ++nt) {
    const int o = nt * 16 + fr;
    const float bias = conv_b[g * 64 + o];
    float4 vv;
    vv.x = (acc[nt][0] + bias) * dt4.x;
    vv.y = (acc[nt][1] + bias) * dt4.y;
    vv.z = (acc[nt][2] + bias) * dt4.z;
    vv.w = (acc[nt][3] + bias) * dt4.w;
    *(float4*)&dBt[((size_t)(b * NH + g) * 64 + o) * L_SEQ + lgb] = vv;
  }
}

// ---- FUSED: blocks 0..127 = chunked fixed-point scan (1 wave, setprio(1)); --
// ---- blocks 128..1151 = gate GEMM, silu -> bf16 (hidden under the scan). ----
__global__ __launch_bounds__(256) void scan_gemm_k(const float* __restrict__ dBt,
                                                   const float* __restrict__ Aw,
                                                   const float* __restrict__ dt,
                                                   unsigned short* __restrict__ states,
                                                   const unsigned short* __restrict__ X,
                                                   const unsigned short* __restrict__ W,
                                                   unsigned short* __restrict__ GOUT) {
  __shared__ __align__(16) char smem[30720];
  if (blockIdx.x >= 128) {
    // ----------------- gate GEMM tile (grid 64 x 16, swizzled) ---------------
    unsigned short* As = (unsigned short*)smem;            // 8KB
    unsigned short* Bs = (unsigned short*)(smem + 8192);   // 8KB
    const int tid = threadIdx.x, lane = tid & 63, wid = tid >> 6;
    const int wm = wid >> 1, wn = wid & 1;
    const int gb = blockIdx.x - 128;              // 0..1023
    const int swz = (gb & 7) * 128 + (gb >> 3);   // XCD-bijective
    const int m0 = (swz & 63) * 128;
    const int n0 = (swz >> 6) * 128;
    const int fr = lane & 15, kg = lane >> 4;
    const int sr = lane >> 2, sc = (lane & 3) * 8;
    f32x4 acc[4][4] = {};
    for (int k0 = 0; k0 < 2048; k0 += 32) {
      const int cA0 = wid * 16, cA1 = (wid + 4) * 16;
      gl_lds16(&X[(size_t)(m0 + cA0 + sr) * 2048 + k0 + sc], &As[cA0 * 32]);
      gl_lds16(&X[(size_t)(m0 + cA1 + sr) * 2048 + k0 + sc], &As[cA1 * 32]);
      gl_lds16(&W[(size_t)(n0 + cA0 + sr) * 2048 + k0 + sc], &Bs[cA0 * 32]);
      gl_lds16(&W[(size_t)(n0 + cA1 + sr) * 2048 + k0 + sc], &Bs[cA1 * 32]);
      __syncthreads();
      bf16x8 af[4], bfr[4];
#pragma unroll
      for (int t = 0; t < 4; ++t) {
        af[t]  = *(const bf16x8*)&As[(wm * 64 + t * 16 + fr) * 32 + kg * 8];
        bfr[t] = *(const bf16x8*)&Bs[(wn * 64 + t * 16 + fr) * 32 + kg * 8];
      }
#pragma unroll
      for (int mt = 0; mt < 4; ++mt)
#pragma unroll
        for (int nt = 0; nt < 4; ++nt)
          acc[mt][nt] = __builtin_amdgcn_mfma_f32_16x16x32_bf16(af[mt], bfr[nt], acc[mt][nt], 0, 0, 0);
      __syncthreads();
    }
#pragma unroll
    for (int mt = 0; mt < 4; ++mt)
#pragma unroll
      for (int nt = 0; nt < 4; ++nt) {
        const int col = n0 + wn * 64 + nt * 16 + fr;
#pragma unroll
        for (int r = 0; r < 4; ++r) {
          const int row = m0 + wm * 64 + mt * 16 + kg * 4 + r;
          float v = acc[mt][nt][r];
          v = v / (1.f + __expf(-v));
          GOUT[(size_t)row * 2048 + col] = f2bf(v);
        }
      }
    return;
  }
  // --------------------------- scan (1 wave) --------------------------------
  if (threadIdx.x >= 64) return;
  __builtin_amdgcn_s_setprio(1);   // latency-critical chain wins CU arbitration
  const int bid = blockIdx.x;          // b*32 + h
  const int h = bid & 31, b = bid >> 5;
  const int lane = threadIdx.x;
  const int fr = lane & 15, kg = lane >> 4;

  // LDS: s-pairs [CHUNK] stride 176B; xT [CHUNK] stride 304B (2-way banks=free)
  char* sp = smem;                 // 11264 B
  char* xT = smem + 11264;         // 19456 B

  // A_w fragments (v4-verified): lane(fr,kg) holds A[h][mb*16+fr][kt*32+kg*8+j]
  bf16x8 afr[4][2];
  {
    const float* Ah = Aw + (size_t)h * 64 * 64;
#pragma unroll
    for (int mb = 0; mb < 4; ++mb)
#pragma unroll
      for (int kt = 0; kt < 2; ++kt) {
        const float* p = &Ah[(size_t)(mb * 16 + fr) * 64 + kt * 32 + kg * 8];
        float4 v0 = *(const float4*)p;
        float4 v1 = *(const float4*)(p + 4);
        bf16x8 f;
        f[0] = (short)f2bf(v0.x); f[1] = (short)f2bf(v0.y);
        f[2] = (short)f2bf(v0.z); f[3] = (short)f2bf(v0.w);
        f[4] = (short)f2bf(v1.x); f[5] = (short)f2bf(v1.y);
        f[6] = (short)f2bf(v1.z); f[7] = (short)f2bf(v1.w);
        afr[mb][kt] = f;
      }
  }

  const float* dBp = dBt + (size_t)(bid * 64 + lane) * L_SEQ;   // own row
  unsigned short* stp = states + (size_t)bid * L_SEQ * 64 + lane;
  const float* dtp = dt + b * L_SEQ;
  const int spw = (lane >> 1) * 4;             // s-pair dword byte offset

  float scs = 0.f;                             // carried exact state
  for (int c = 0; c < L_SEQ / CHUNK; ++c) {
    const int l0 = c * CHUNK;
    float Dv[CHUNK], E[CHUNK];
#pragma unroll
    for (int t = 0; t < CHUNK / 4; ++t) {
      float4 q = *(const float4*)&dBp[l0 + t * 4];
      Dv[4 * t] = q.x; Dv[4 * t + 1] = q.y; Dv[4 * t + 2] = q.z; Dv[4 * t + 3] = q.w;
    }
#pragma unroll
    for (int l = 0; l < CHUNK; ++l) E[l] = 1.0f;
    float dtq[4];
#pragma unroll
    for (int tb = 0; tb < 4; ++tb) dtq[tb] = dtp[l0 + tb * 16 + fr];

    for (int it = 0; it < ITERS; ++it) {
      // ---- scan with LDS pair writes (s_l BEFORE update at step l) ----
      float s = scs;
#pragma unroll
      for (int l = 0; l < CHUNK; ++l) {
        float sn = qperm<0xB1>(s);
        float lo = (lane & 1) ? sn : s;
        float hi = (lane & 1) ? s : sn;
        unsigned pw;
        asm("v_cvt_pk_bf16_f32 %0, %1, %2" : "=v"(pw) : "v"(lo), "v"(hi));
        *(unsigned*)(sp + l * 176 + spw) = pw;
        s = __builtin_fmaf(E[l], s, Dv[l]);
      }
      asm volatile("" ::: "memory");
      // ---- batched matvec: X[m][t] = A_w · S ----
      bf16x8 bf[4][2];
#pragma unroll
      for (int tb = 0; tb < 4; ++tb)
#pragma unroll
        for (int kt = 0; kt < 2; ++kt)
          bf[tb][kt] = *(const bf16x8*)(sp + (tb * 16 + fr) * 176 + (kt * 16 + kg * 4) * 4);
      f32x4 acc[4][4];
#pragma unroll
      for (int mb = 0; mb < 4; ++mb)
#pragma unroll
        for (int tb = 0; tb < 4; ++tb) {
          f32x4 z = {0.f, 0.f, 0.f, 0.f};
          f32x4 t0 = __builtin_amdgcn_mfma_f32_16x16x32_bf16(afr[mb][0], bf[tb][0], z, 0, 0, 0);
          acc[mb][tb] = __builtin_amdgcn_mfma_f32_16x16x32_bf16(afr[mb][1], bf[tb][1], t0, 0, 0, 0);
        }
      // scale by dt (t = tb*16+fr per lane) and write xT[t][m]
#pragma unroll
      for (int mb = 0; mb < 4; ++mb)
#pragma unroll
        for (int tb = 0; tb < 4; ++tb) {
          f32x4 v = acc[mb][tb];
          v[0] *= dtq[tb]; v[1] *= dtq[tb]; v[2] *= dtq[tb]; v[3] *= dtq[tb];
          *(f32x4*)(xT + (tb * 16 + fr) * 304 + (mb * 16 + kg * 4) * 4) = v;
        }
      asm volatile("" ::: "memory");
      // ---- readback own-m time series, Taylor exp -> E ----
#pragma unroll
      for (int l = 0; l < CHUNK; ++l) {
        float x = *(const float*)(xT + l * 304 + lane * 4);
        E[l] = __builtin_fmaf(x * x, 0.5f, 1.0f + x);
      }
    }
    // ---- final scan with converged E: store states ----
    {
      float s = scs;
#pragma unroll
      for (int l = 0; l < CHUNK; ++l) {
        s = __builtin_fmaf(E[l], s, Dv[l]);
        stp[(size_t)(l0 + l) * 64] = f2bf(s);
      }
      scs = s;
    }
  }
}

// -- C projection + x*D + silu(gate) multiply; writes hsb (b,l,hid) bf16 -------
__global__ __launch_bounds__(256) void proj_k(const unsigned short* __restrict__ st,
                                              const unsigned short* __restrict__ cwb,
                                              const unsigned short* __restrict__ xbp,
                                              const float* __restrict__ Dp,
                                              const unsigned short* __restrict__ gsb,
                                              unsigned short* __restrict__ hsb) {
  const int l0 = blockIdx.x * 64, h = blockIdx.y, b = blockIdx.z;
  const int tid = threadIdx.x, lane = tid & 63, wid = tid >> 6;
  const int fr = lane & 15, kg = lane >> 4, wm = wid;
  f32x4 acc[4] = {};
#pragma unroll
  for (int ks = 0; ks < 2; ++ks) {
    bf16x8 a = *(const bf16x8*)&st[((size_t)(b * NH + h) * L_SEQ + l0 + wm * 16 + fr) * 64 + ks * 32 + kg * 8];
#pragma unroll
    for (int nt = 0; nt < 4; ++nt) {
      bf16x8 bq = *(const bf16x8*)&cwb[(size_t)(h * 64 + nt * 16 + fr) * 64 + ks * 32 + kg * 8];
      acc[nt] = __builtin_amdgcn_mfma_f32_16x16x32_bf16(a, bq, acc[nt], 0, 0, 0);
    }
  }
  const float Dh = Dp[h];
#pragma unroll
  for (int nt = 0; nt < 4; ++nt) {
    const int ccol = h * 64 + nt * 16 + fr;
#pragma unroll
    for (int r = 0; r < 4; ++r) {
      const int lg = l0 + wm * 16 + kg * 4 + r;
      const size_t idx = (size_t)(b * L_SEQ + lg) * HIDN + ccol;
      float v = acc[nt][r] + bf2f(xbp[idx]) * Dh;
      hsb[idx] = f2bf(v * bf2f(gsb[idx]));
    }
  }
}

// ---------- per-row rsqrt(mean(hs^2)+eps) from bf16 hs (norm fold) ------------
__global__ __launch_bounds__(256) void rs_k(const unsigned short* __restrict__ hsb,
                                            float* __restrict__ rs) {
  const int row = blockIdx.x;
  const unsigned short* p = hsb + (size_t)row * HIDN;
  const int c0 = threadIdx.x * 8;
  bf16x8 u = *(const bf16x8*)&p[c0];
  float ss = 0.f;
#pragma unroll
  for (int i = 0; i < 8; ++i) { float f = bf2f((unsigned short)u[i]); ss += f * f; }
#pragma unroll
  for (int off = 32; off; off >>= 1) ss += __shfl_xor(ss, off);
  __shared__ float pr[4];
  if ((threadIdx.x & 63) == 0) pr[threadIdx.x >> 6] = ss;
  __syncthreads();
  if (threadIdx.x == 0) {
    float tot = pr[0] + pr[1] + pr[2] + pr[3];
    rs[row] = rsqrtf(tot * (1.f / HIDN) + 1e-6f);
  }
}

extern "C" void kernel_launch(void* const* d_in, const int* in_sizes, int n_in,
                              void* d_out, int out_size, void* d_ws, size_t ws_size,
                              hipStream_t stream) {
  const float* x  = (const float*)d_in[0];
  const float* dt = (const float*)d_in[1];
  const float* gw = (const float*)d_in[2];
  const float* Aw = (const float*)d_in[3];
  const float* cw = (const float*)d_in[4];
  const float* cb = (const float*)d_in[5];
  const float* Cw = (const float*)d_in[6];
  const float* Dp = (const float*)d_in[7];
  const float* nw = (const float*)d_in[8];
  const float* ow = (const float*)d_in[9];
  float* out = (float*)d_out;

  // workspace (bytes): hsb overlays dBt (dead after scan); stb has own slot.
  // gate bf16 lives in d_out's first 32MB (dead before out-GEMM writes).
  char* w = (char*)d_ws;
  unsigned short* xb   = (unsigned short*)(w);                // 32MB
  unsigned short* gwb  = (unsigned short*)(w + 33554432);     // 8MB
  unsigned short* owb  = (unsigned short*)(w + 41943040);     // 8MB (ow*nw)
  unsigned short* wret = (unsigned short*)(w + 50331648);     // 1MB
  unsigned short* cwb  = (unsigned short*)(w + 51380224);     // 256KB
  float*          rsb  = (float*)(w + 51642368);              // 32KB
  float*          dBt  = (float*)(w + 52428800);              // 64MB
  unsigned short* hsb  = (unsigned short*)(w + 52428800);     // overlay (after scan)
  unsigned short* stb  = (unsigned short*)(w + 119537664);    // 32MB
  unsigned short* gsb  = (unsigned short*)d_out;              // gate bf16, 32MB
  if (ws_size < 153092096) return;

  cvt_bf16_k<<<2048, 256, 0, stream>>>(x, xb, 16777216 / 4);
  cvt_bf16_k<<<1024, 256, 0, stream>>>(gw, gwb, 4194304 / 4);
  ownw_k<<<4096, 256, 0, stream>>>(ow, nw, owb);
  cvt_bf16_k<<<128, 256, 0, stream>>>(Cw, cwb, 131072 / 4);
  wret_k<<<2048, 256, 0, stream>>>(cw, wret);

  conv_k<<<dim3(32, 32, 4), 256, 0, stream>>>(xb, wret, cb, dt, dBt);
  // chunked fixed-point scan (blocks 0..127) || gate GEMM (blocks 128..1151)
  scan_gemm_k<<<1152, 256, 0, stream>>>(dBt, Aw, dt, stb, xb, gwb, gsb);
  proj_k<<<dim3(32, 32, 4), 256, 0, stream>>>(stb, cwb, xb, Dp, gsb, hsb);
  rs_k<<<8192, 256, 0, stream>>>(hsb, rsb);
  gemm_out_k<<<dim3(64, 16), 256, 0, stream>>>(hsb, owb, rsb, out, 8192, 2048, 2048);
}

// Round 16
// 416.975 us; speedup vs baseline: 2.3074x; 1.2521x over previous
//
#include <hip/hip_runtime.h>
#include <hip/hip_bf16.h>

#define L_SEQ 2048
#define HIDN  2048
#define NH    32
#define BATCHN 4
#define CHUNK 64
#define ITERS 1   // fixed-point correction iterations per chunk

using bf16x8 = __attribute__((ext_vector_type(8))) short;
using f32x4  = __attribute__((ext_vector_type(4))) float;

__device__ __forceinline__ unsigned short f2bf(float f) {
  union { float f; unsigned u; } v; v.f = f;
  unsigned r = v.u + 0x7fffu + ((v.u >> 16) & 1u);
  return (unsigned short)(r >> 16);
}

__device__ __forceinline__ float bf2f(unsigned short u) {
  unsigned v = ((unsigned)u) << 16;
  return __builtin_bit_cast(float, v);
}

__device__ __forceinline__ void gl_lds16(const void* g, void* l) {
  __builtin_amdgcn_global_load_lds(
      (const __attribute__((address_space(1))) unsigned int*)g,
      (__attribute__((address_space(3))) unsigned int*)l, 16, 0, 0);
}

template <int CTRL>
__device__ __forceinline__ float qperm(float x) {
  int xi = __builtin_bit_cast(int, x);
  int yi = __builtin_amdgcn_update_dpp(0, xi, CTRL, 0xF, 0xF, true);
  return __builtin_bit_cast(float, yi);
}

#define BARRIER() do { asm volatile("" ::: "memory"); \
  __builtin_amdgcn_s_barrier(); asm volatile("" ::: "memory"); } while (0)

// ---------------- f32 -> bf16 convert (grid-stride over n/4 float4s) ----------
__global__ __launch_bounds__(256) void cvt_bf16_k(const float* __restrict__ in,
                                                  unsigned short* __restrict__ out, int n4) {
  for (int i = blockIdx.x * 256 + threadIdx.x; i < n4; i += gridDim.x * 256) {
    float4 v = *(const float4*)&in[(size_t)i * 4];
    ushort4 o;
    o.x = f2bf(v.x); o.y = f2bf(v.y); o.z = f2bf(v.z); o.w = f2bf(v.w);
    *(ushort4*)&out[(size_t)i * 4] = o;
  }
}

// ---- out-weight prep: owb[n][k] = bf16(ow[n][k] * nw[k])  (norm-weight fold) -
__global__ __launch_bounds__(256) void ownw_k(const float* __restrict__ ow,
                                              const float* __restrict__ nw,
                                              unsigned short* __restrict__ out) {
  int i = blockIdx.x * 256 + threadIdx.x;    // over 4194304/4 float4s
  float4 v = *(const float4*)&ow[(size_t)i * 4];
  int k0 = (i * 4) & 2047;
  ushort4 o;
  o.x = f2bf(v.x * nw[k0 + 0]); o.y = f2bf(v.y * nw[k0 + 1]);
  o.z = f2bf(v.z * nw[k0 + 2]); o.w = f2bf(v.w * nw[k0 + 3]);
  *(ushort4*)&out[(size_t)i * 4] = o;
}

// -------- conv weight transform: wreT[o][k*64+i] = conv_w[o][i][k] (bf16) -----
__global__ __launch_bounds__(256) void wret_k(const float* __restrict__ cw,
                                              unsigned short* __restrict__ out) {
  int idx = blockIdx.x * 256 + threadIdx.x;   // 2048*256 total
  int o = idx >> 8, q = idx & 255;
  int k = q >> 6, i = q & 63;
  out[idx] = f2bf(cw[o * 256 + i * 4 + k]);
}

// ===== 256x256 tile, BK=64, 8-wave, double-buffered 4-phase pipelined GEMM ====
// OUT[m][n] = sum_k X[m][k]*W[n][k].  MODE 0: f32 out * rs[m].  MODE 1: silu->bf16.
// LDS 128KB: buf b: A at b*65536 (256 rows x 128B), B at +32768.
// T2 swizzle: phys colbyte = logical ^ ((row&7)<<4); staged via pre-swizzled
// global source (gl_lds writes linearly), read with the same XOR.
template <int MODE>
__global__ __launch_bounds__(512, 2) void gemm256_k(const unsigned short* __restrict__ X,
                                                    const unsigned short* __restrict__ W,
                                                    const float* __restrict__ rs,
                                                    void* __restrict__ OUTp,
                                                    int M, int N, int K) {
  __shared__ __align__(16) char smem[131072];
  const int tid = threadIdx.x, lane = tid & 63, w = tid >> 6;
  const int wm = w >> 2, wn = w & 3, fr = lane & 15, kg = lane >> 4;
  const int nbx = M >> 8, nby = N >> 8;
  const int nwg = nbx * nby, cpx = nwg >> 3;
  const int lin = blockIdx.x;
  const int swz = (lin & 7) * cpx + (lin >> 3);     // XCD-bijective (nwg%8==0)
  const int m0 = (swz % nbx) * 256, n0 = (swz / nbx) * 256;
  const int twistL = (fr & 7) << 4;

  // stage one 16KB half-tile (2 x gl_lds16/thread), pre-swizzled source
  auto stageA = [&](int buf, int half, int kq) {
#pragma unroll
    for (int q = 0; q < 2; ++q) {
      int s = q * 8192 + tid * 16;
      int r = s >> 7, cb = s & 127;
      const void* src = &X[(size_t)(m0 + half * 128 + r) * K + kq + ((cb ^ ((r & 7) << 4)) >> 1)];
      void* dst = smem + buf * 65536 + half * 16384 + q * 8192 + w * 1024;
      gl_lds16(src, dst);
    }
  };
  auto stageB = [&](int buf, int half, int kq) {
#pragma unroll
    for (int q = 0; q < 2; ++q) {
      int s = q * 8192 + tid * 16;
      int r = s >> 7, cb = s & 127;
      const void* src = &W[(size_t)(n0 + half * 128 + r) * K + kq + ((cb ^ ((r & 7) << 4)) >> 1)];
      void* dst = smem + buf * 65536 + 32768 + half * 16384 + q * 8192 + w * 1024;
      gl_lds16(src, dst);
    }
  };

  // prologue: stage tile 0 into buf 0
  stageA(0, 0, 0); stageA(0, 1, 0); stageB(0, 0, 0); stageB(0, 1, 0);

  f32x4 acc[8][4] = {};
  int cur = 0;
  const int NT = K >> 6;
  for (int kt = 0; kt < NT; ++kt) {
    const char* Ab = smem + cur * 65536;
    const char* Bb = smem + cur * 65536 + 32768;
#pragma unroll
    for (int p = 0; p < 4; ++p) {
      const int mg = p & 1, ks = p >> 1;
      if (p == 0) { asm volatile("s_waitcnt vmcnt(0)" ::: "memory"); }
      BARRIER();
      if (kt + 1 < NT) {           // prefetch next tile (phases 0..2)
        if (p == 0)      { stageA(cur ^ 1, 0, (kt + 1) << 6); stageA(cur ^ 1, 1, (kt + 1) << 6); }
        else if (p == 1) { stageB(cur ^ 1, 0, (kt + 1) << 6); }
        else if (p == 2) { stageB(cur ^ 1, 1, (kt + 1) << 6); }
      }
      bf16x8 af[4], bfr[4];
#pragma unroll
      for (int t = 0; t < 4; ++t) {
        const int Ra = wm * 128 + mg * 64 + t * 16 + fr;
        af[t] = *(const bf16x8*)(Ab + Ra * 128 + ((ks * 64 + kg * 16) ^ twistL));
        const int Rb = wn * 64 + t * 16 + fr;
        bfr[t] = *(const bf16x8*)(Bb + Rb * 128 + ((ks * 64 + kg * 16) ^ twistL));
      }
      asm volatile("s_waitcnt lgkmcnt(0)" ::: "memory");
      __builtin_amdgcn_sched_barrier(0);
      __builtin_amdgcn_s_setprio(1);
#pragma unroll
      for (int t = 0; t < 4; ++t)
#pragma unroll
        for (int nf = 0; nf < 4; ++nf)
          acc[mg * 4 + t][nf] = __builtin_amdgcn_mfma_f32_16x16x32_bf16(af[t], bfr[nf], acc[mg * 4 + t][nf], 0, 0, 0);
      __builtin_amdgcn_s_setprio(0);
    }
    cur ^= 1;
  }

#pragma unroll
  for (int mf = 0; mf < 8; ++mf)
#pragma unroll
    for (int nf = 0; nf < 4; ++nf) {
      const int col = n0 + wn * 64 + nf * 16 + fr;
#pragma unroll
      for (int r = 0; r < 4; ++r) {
        const int row = m0 + wm * 128 + mf * 16 + kg * 4 + r;
        float v = acc[mf][nf][r];
        if (MODE == 0) {
          ((float*)OUTp)[(size_t)row * N + col] = v * rs[row];
        } else {
          v = v / (1.f + __expf(-v));
          ((unsigned short*)OUTp)[(size_t)row * N + col] = f2bf(v);
        }
      }
    }
}

// --- grouped causal conv as MFMA GEMM; epilogue: (Bc+bias)*dt -> dBt[row][l] --
__global__ __launch_bounds__(256) void conv_k(const unsigned short* __restrict__ xb,
                                              const unsigned short* __restrict__ wreT,
                                              const float* __restrict__ conv_b,
                                              const float* __restrict__ dt,
                                              float* __restrict__ dBt) {
  __shared__ __align__(16) unsigned short x_lds[67 * 64];
  const int l0 = blockIdx.x * 64, g = blockIdx.y, b = blockIdx.z;
  const int tid = threadIdx.x, lane = tid & 63, wid = tid >> 6;
  {
    const int r = tid >> 3, ch = (tid & 7) * 8;
#pragma unroll
    for (int pass = 0; pass < 3; ++pass) {
      int rr = r + pass * 32;
      if (rr < 67) {
        int lg = l0 - 3 + rr;
        bf16x8 v = {};
        if (lg >= 0) v = *(const bf16x8*)&xb[(size_t)(b * L_SEQ + lg) * HIDN + g * 64 + ch];
        *(bf16x8*)&x_lds[rr * 64 + ch] = v;
      }
    }
  }
  __syncthreads();
  const int fr = lane & 15, kg = lane >> 4, wm = wid;
  f32x4 acc[4] = {};
#pragma unroll
  for (int ks = 0; ks < 8; ++ks) {
    bf16x8 a = *(const bf16x8*)&x_lds[(wm * 16 + fr + (ks >> 1)) * 64 + (ks & 1) * 32 + kg * 8];
#pragma unroll
    for (int nt = 0; nt < 4; ++nt) {
      bf16x8 bq = *(const bf16x8*)&wreT[(size_t)(g * 64 + nt * 16 + fr) * 256 + ks * 32 + kg * 8];
      acc[nt] = __builtin_amdgcn_mfma_f32_16x16x32_bf16(a, bq, acc[nt], 0, 0, 0);
    }
  }
  const int lgb = l0 + wm * 16 + kg * 4;
  const float4 dt4 = *(const float4*)&dt[b * L_SEQ + lgb];
#pragma unroll
  for (int nt = 0; nt < 4; ++nt) {
    const int o = nt * 16 + fr;
    const float bias = conv_b[g * 64 + o];
    float4 vv;
    vv.x = (acc[nt][0] + bias) * dt4.x;
    vv.y = (acc[nt][1] + bias) * dt4.y;
    vv.z = (acc[nt][2] + bias) * dt4.z;
    vv.w = (acc[nt][3] + bias) * dt4.w;
    *(float4*)&dBt[((size_t)(b * NH + g) * 64 + o) * L_SEQ + lgb] = vv;
  }
}

// --------- chunked fixed-point scan, standalone (1 wave per (b,h)) ------------
__global__ __launch_bounds__(64) void scan_k(const float* __restrict__ dBt,
                                             const float* __restrict__ Aw,
                                             const float* __restrict__ dt,
                                             unsigned short* __restrict__ states) {
  __shared__ __align__(16) char smem[30720];
  const int bid = blockIdx.x;          // b*32 + h
  const int h = bid & 31, b = bid >> 5;
  const int lane = threadIdx.x;
  const int fr = lane & 15, kg = lane >> 4;

  char* sp = smem;                 // s-pairs [CHUNK] stride 176B
  char* xT = smem + 11264;         // xT [CHUNK] stride 304B

  bf16x8 afr[4][2];
  {
    const float* Ah = Aw + (size_t)h * 64 * 64;
#pragma unroll
    for (int mb = 0; mb < 4; ++mb)
#pragma unroll
      for (int kt = 0; kt < 2; ++kt) {
        const float* p = &Ah[(size_t)(mb * 16 + fr) * 64 + kt * 32 + kg * 8];
        float4 v0 = *(const float4*)p;
        float4 v1 = *(const float4*)(p + 4);
        bf16x8 f;
        f[0] = (short)f2bf(v0.x); f[1] = (short)f2bf(v0.y);
        f[2] = (short)f2bf(v0.z); f[3] = (short)f2bf(v0.w);
        f[4] = (short)f2bf(v1.x); f[5] = (short)f2bf(v1.y);
        f[6] = (short)f2bf(v1.z); f[7] = (short)f2bf(v1.w);
        afr[mb][kt] = f;
      }
  }

  const float* dBp = dBt + (size_t)(bid * 64 + lane) * L_SEQ;   // own row
  unsigned short* stp = states + (size_t)bid * L_SEQ * 64 + lane;
  const float* dtp = dt + b * L_SEQ;
  const int spw = (lane >> 1) * 4;

  float scs = 0.f;
  for (int c = 0; c < L_SEQ / CHUNK; ++c) {
    const int l0 = c * CHUNK;
    float Dv[CHUNK], E[CHUNK];
#pragma unroll
    for (int t = 0; t < CHUNK / 4; ++t) {
      float4 q = *(const float4*)&dBp[l0 + t * 4];
      Dv[4 * t] = q.x; Dv[4 * t + 1] = q.y; Dv[4 * t + 2] = q.z; Dv[4 * t + 3] = q.w;
    }
#pragma unroll
    for (int l = 0; l < CHUNK; ++l) E[l] = 1.0f;
    float dtq[4];
#pragma unroll
    for (int tb = 0; tb < 4; ++tb) dtq[tb] = dtp[l0 + tb * 16 + fr];

    for (int it = 0; it < ITERS; ++it) {
      float s = scs;
#pragma unroll
      for (int l = 0; l < CHUNK; ++l) {
        float sn = qperm<0xB1>(s);
        float lo = (lane & 1) ? sn : s;
        float hi = (lane & 1) ? s : sn;
        unsigned pw;
        asm("v_cvt_pk_bf16_f32 %0, %1, %2" : "=v"(pw) : "v"(lo), "v"(hi));
        *(unsigned*)(sp + l * 176 + spw) = pw;
        s = __builtin_fmaf(E[l], s, Dv[l]);
      }
      asm volatile("" ::: "memory");
      bf16x8 bf[4][2];
#pragma unroll
      for (int tb = 0; tb < 4; ++tb)
#pragma unroll
        for (int kt = 0; kt < 2; ++kt)
          bf[tb][kt] = *(const bf16x8*)(sp + (tb * 16 + fr) * 176 + (kt * 16 + kg * 4) * 4);
      f32x4 acc[4][4];
#pragma unroll
      for (int mb = 0; mb < 4; ++mb)
#pragma unroll
        for (int tb = 0; tb < 4; ++tb) {
          f32x4 z = {0.f, 0.f, 0.f, 0.f};
          f32x4 t0 = __builtin_amdgcn_mfma_f32_16x16x32_bf16(afr[mb][0], bf[tb][0], z, 0, 0, 0);
          acc[mb][tb] = __builtin_amdgcn_mfma_f32_16x16x32_bf16(afr[mb][1], bf[tb][1], t0, 0, 0, 0);
        }
#pragma unroll
      for (int mb = 0; mb < 4; ++mb)
#pragma unroll
        for (int tb = 0; tb < 4; ++tb) {
          f32x4 v = acc[mb][tb];
          v[0] *= dtq[tb]; v[1] *= dtq[tb]; v[2] *= dtq[tb]; v[3] *= dtq[tb];
          *(f32x4*)(xT + (tb * 16 + fr) * 304 + (mb * 16 + kg * 4) * 4) = v;
        }
      asm volatile("" ::: "memory");
#pragma unroll
      for (int l = 0; l < CHUNK; ++l) {
        float x = *(const float*)(xT + l * 304 + lane * 4);
        E[l] = __builtin_fmaf(x * x, 0.5f, 1.0f + x);
      }
    }
    {
      float s = scs;
#pragma unroll
      for (int l = 0; l < CHUNK; ++l) {
        s = __builtin_fmaf(E[l], s, Dv[l]);
        stp[(size_t)(l0 + l) * 64] = f2bf(s);
      }
      scs = s;
    }
  }
}

// -- C projection + x*D + silu(gate) multiply; writes hsb (b,l,hid) bf16 -------
__global__ __launch_bounds__(256) void proj_k(const unsigned short* __restrict__ st,
                                              const unsigned short* __restrict__ cwb,
                                              const unsigned short* __restrict__ xbp,
                                              const float* __restrict__ Dp,
                                              const unsigned short* __restrict__ gsb,
                                              unsigned short* __restrict__ hsb) {
  const int l0 = blockIdx.x * 64, h = blockIdx.y, b = blockIdx.z;
  const int tid = threadIdx.x, lane = tid & 63, wid = tid >> 6;
  const int fr = lane & 15, kg = lane >> 4, wm = wid;
  f32x4 acc[4] = {};
#pragma unroll
  for (int ks = 0; ks < 2; ++ks) {
    bf16x8 a = *(const bf16x8*)&st[((size_t)(b * NH + h) * L_SEQ + l0 + wm * 16 + fr) * 64 + ks * 32 + kg * 8];
#pragma unroll
    for (int nt = 0; nt < 4; ++nt) {
      bf16x8 bq = *(const bf16x8*)&cwb[(size_t)(h * 64 + nt * 16 + fr) * 64 + ks * 32 + kg * 8];
      acc[nt] = __builtin_amdgcn_mfma_f32_16x16x32_bf16(a, bq, acc[nt], 0, 0, 0);
    }
  }
  const float Dh = Dp[h];
#pragma unroll
  for (int nt = 0; nt < 4; ++nt) {
    const int ccol = h * 64 + nt * 16 + fr;
#pragma unroll
    for (int r = 0; r < 4; ++r) {
      const int lg = l0 + wm * 16 + kg * 4 + r;
      const size_t idx = (size_t)(b * L_SEQ + lg) * HIDN + ccol;
      float v = acc[nt][r] + bf2f(xbp[idx]) * Dh;
      hsb[idx] = f2bf(v * bf2f(gsb[idx]));
    }
  }
}

// ---------- per-row rsqrt(mean(hs^2)+eps) from bf16 hs (norm fold) ------------
__global__ __launch_bounds__(256) void rs_k(const unsigned short* __restrict__ hsb,
                                            float* __restrict__ rs) {
  const int row = blockIdx.x;
  const unsigned short* p = hsb + (size_t)row * HIDN;
  const int c0 = threadIdx.x * 8;
  bf16x8 u = *(const bf16x8*)&p[c0];
  float ss = 0.f;
#pragma unroll
  for (int i = 0; i < 8; ++i) { float f = bf2f((unsigned short)u[i]); ss += f * f; }
#pragma unroll
  for (int off = 32; off; off >>= 1) ss += __shfl_xor(ss, off);
  __shared__ float pr[4];
  if ((threadIdx.x & 63) == 0) pr[threadIdx.x >> 6] = ss;
  __syncthreads();
  if (threadIdx.x == 0) {
    float tot = pr[0] + pr[1] + pr[2] + pr[3];
    rs[row] = rsqrtf(tot * (1.f / HIDN) + 1e-6f);
  }
}

extern "C" void kernel_launch(void* const* d_in, const int* in_sizes, int n_in,
                              void* d_out, int out_size, void* d_ws, size_t ws_size,
                              hipStream_t stream) {
  const float* x  = (const float*)d_in[0];
  const float* dt = (const float*)d_in[1];
  const float* gw = (const float*)d_in[2];
  const float* Aw = (const float*)d_in[3];
  const float* cw = (const float*)d_in[4];
  const float* cb = (const float*)d_in[5];
  const float* Cw = (const float*)d_in[6];
  const float* Dp = (const float*)d_in[7];
  const float* nw = (const float*)d_in[8];
  const float* ow = (const float*)d_in[9];
  float* out = (float*)d_out;

  // workspace (bytes): hsb overlays dBt (dead after scan); stb has own slot.
  // gate bf16 lives in d_out's first 32MB (dead before out-GEMM writes).
  char* w = (char*)d_ws;
  unsigned short* xb   = (unsigned short*)(w);                // 32MB
  unsigned short* gwb  = (unsigned short*)(w + 33554432);     // 8MB
  unsigned short* owb  = (unsigned short*)(w + 41943040);     // 8MB (ow*nw)
  unsigned short* wret = (unsigned short*)(w + 50331648);     // 1MB
  unsigned short* cwb  = (unsigned short*)(w + 51380224);     // 256KB
  float*          rsb  = (float*)(w + 51642368);              // 32KB
  float*          dBt  = (float*)(w + 52428800);              // 64MB
  unsigned short* hsb  = (unsigned short*)(w + 52428800);     // overlay (after scan)
  unsigned short* stb  = (unsigned short*)(w + 119537664);    // 32MB
  unsigned short* gsb  = (unsigned short*)d_out;              // gate bf16, 32MB
  if (ws_size < 153092096) return;

  cvt_bf16_k<<<2048, 256, 0, stream>>>(x, xb, 16777216 / 4);
  cvt_bf16_k<<<1024, 256, 0, stream>>>(gw, gwb, 4194304 / 4);
  ownw_k<<<4096, 256, 0, stream>>>(ow, nw, owb);
  cvt_bf16_k<<<128, 256, 0, stream>>>(Cw, cwb, 131072 / 4);
  wret_k<<<2048, 256, 0, stream>>>(cw, wret);

  // gate GEMM (256^2 4-phase pipelined), silu -> bf16 gsb
  gemm256_k<1><<<256, 512, 0, stream>>>(xb, gwb, nullptr, gsb, 8192, 2048, 2048);
  conv_k<<<dim3(32, 32, 4), 256, 0, stream>>>(xb, wret, cb, dt, dBt);
  scan_k<<<128, 64, 0, stream>>>(dBt, Aw, dt, stb);
  proj_k<<<dim3(32, 32, 4), 256, 0, stream>>>(stb, cwb, xb, Dp, gsb, hsb);
  rs_k<<<8192, 256, 0, stream>>>(hsb, rsb);
  // out GEMM (256^2 4-phase pipelined), rs-scaled f32
  gemm256_k<0><<<256, 512, 0, stream>>>(hsb, owb, rsb, out, 8192, 2048, 2048);
}

// Round 17
// 416.528 us; speedup vs baseline: 2.3099x; 1.0011x over previous
//
#include <hip/hip_runtime.h>
#include <hip/hip_bf16.h>

#define L_SEQ 2048
#define HIDN  2048
#define NH    32
#define BATCHN 4
#define CHUNK 64

using bf16x8 = __attribute__((ext_vector_type(8))) short;
using f32x4  = __attribute__((ext_vector_type(4))) float;

__device__ __forceinline__ unsigned short f2bf(float f) {
  union { float f; unsigned u; } v; v.f = f;
  unsigned r = v.u + 0x7fffu + ((v.u >> 16) & 1u);
  return (unsigned short)(r >> 16);
}

__device__ __forceinline__ float bf2f(unsigned short u) {
  unsigned v = ((unsigned)u) << 16;
  return __builtin_bit_cast(float, v);
}

__device__ __forceinline__ void gl_lds16(const void* g, void* l) {
  __builtin_amdgcn_global_load_lds(
      (const __attribute__((address_space(1))) unsigned int*)g,
      (__attribute__((address_space(3))) unsigned int*)l, 16, 0, 0);
}

template <int CTRL>
__device__ __forceinline__ float qperm(float x) {
  int xi = __builtin_bit_cast(int, x);
  int yi = __builtin_amdgcn_update_dpp(0, xi, CTRL, 0xF, 0xF, true);
  return __builtin_bit_cast(float, yi);
}

#define BARRIER() do { asm volatile("" ::: "memory"); \
  __builtin_amdgcn_s_barrier(); asm volatile("" ::: "memory"); } while (0)

// ---------------- f32 -> bf16 convert (grid-stride over n/4 float4s) ----------
__global__ __launch_bounds__(256) void cvt_bf16_k(const float* __restrict__ in,
                                                  unsigned short* __restrict__ out, int n4) {
  for (int i = blockIdx.x * 256 + threadIdx.x; i < n4; i += gridDim.x * 256) {
    float4 v = *(const float4*)&in[(size_t)i * 4];
    ushort4 o;
    o.x = f2bf(v.x); o.y = f2bf(v.y); o.z = f2bf(v.z); o.w = f2bf(v.w);
    *(ushort4*)&out[(size_t)i * 4] = o;
  }
}

// ---- out-weight prep: owb[n][k] = bf16(ow[n][k] * nw[k])  (norm-weight fold) -
__global__ __launch_bounds__(256) void ownw_k(const float* __restrict__ ow,
                                              const float* __restrict__ nw,
                                              unsigned short* __restrict__ out) {
  int i = blockIdx.x * 256 + threadIdx.x;    // over 4194304/4 float4s
  float4 v = *(const float4*)&ow[(size_t)i * 4];
  int k0 = (i * 4) & 2047;
  ushort4 o;
  o.x = f2bf(v.x * nw[k0 + 0]); o.y = f2bf(v.y * nw[k0 + 1]);
  o.z = f2bf(v.z * nw[k0 + 2]); o.w = f2bf(v.w * nw[k0 + 3]);
  *(ushort4*)&out[(size_t)i * 4] = o;
}

// -------- conv weight transform: wreT[o][k*64+i] = conv_w[o][i][k] (bf16) -----
__global__ __launch_bounds__(256) void wret_k(const float* __restrict__ cw,
                                              unsigned short* __restrict__ out) {
  int idx = blockIdx.x * 256 + threadIdx.x;   // 2048*256 total
  int o = idx >> 8, q = idx & 255;
  int k = q >> 6, i = q & 63;
  out[idx] = f2bf(cw[o * 256 + i * 4 + k]);
}

// ===== 256x256 tile, BK=64, 8-wave, double-buffered 4-phase pipelined GEMM ====
template <int MODE>
__global__ __launch_bounds__(512, 2) void gemm256_k(const unsigned short* __restrict__ X,
                                                    const unsigned short* __restrict__ W,
                                                    const float* __restrict__ rs,
                                                    void* __restrict__ OUTp,
                                                    int M, int N, int K) {
  __shared__ __align__(16) char smem[131072];
  const int tid = threadIdx.x, lane = tid & 63, w = tid >> 6;
  const int wm = w >> 2, wn = w & 3, fr = lane & 15, kg = lane >> 4;
  const int nbx = M >> 8, nby = N >> 8;
  const int nwg = nbx * nby, cpx = nwg >> 3;
  const int lin = blockIdx.x;
  const int swz = (lin & 7) * cpx + (lin >> 3);     // XCD-bijective (nwg%8==0)
  const int m0 = (swz % nbx) * 256, n0 = (swz / nbx) * 256;
  const int twistL = (fr & 7) << 4;

  auto stageA = [&](int buf, int half, int kq) {
#pragma unroll
    for (int q = 0; q < 2; ++q) {
      int s = q * 8192 + tid * 16;
      int r = s >> 7, cb = s & 127;
      const void* src = &X[(size_t)(m0 + half * 128 + r) * K + kq + ((cb ^ ((r & 7) << 4)) >> 1)];
      void* dst = smem + buf * 65536 + half * 16384 + q * 8192 + w * 1024;
      gl_lds16(src, dst);
    }
  };
  auto stageB = [&](int buf, int half, int kq) {
#pragma unroll
    for (int q = 0; q < 2; ++q) {
      int s = q * 8192 + tid * 16;
      int r = s >> 7, cb = s & 127;
      const void* src = &W[(size_t)(n0 + half * 128 + r) * K + kq + ((cb ^ ((r & 7) << 4)) >> 1)];
      void* dst = smem + buf * 65536 + 32768 + half * 16384 + q * 8192 + w * 1024;
      gl_lds16(src, dst);
    }
  };

  stageA(0, 0, 0); stageA(0, 1, 0); stageB(0, 0, 0); stageB(0, 1, 0);

  f32x4 acc[8][4] = {};
  int cur = 0;
  const int NT = K >> 6;
  for (int kt = 0; kt < NT; ++kt) {
    const char* Ab = smem + cur * 65536;
    const char* Bb = smem + cur * 65536 + 32768;
#pragma unroll
    for (int p = 0; p < 4; ++p) {
      const int mg = p & 1, ks = p >> 1;
      if (p == 0) { asm volatile("s_waitcnt vmcnt(0)" ::: "memory"); }
      BARRIER();
      if (kt + 1 < NT) {
        if (p == 0)      { stageA(cur ^ 1, 0, (kt + 1) << 6); stageA(cur ^ 1, 1, (kt + 1) << 6); }
        else if (p == 1) { stageB(cur ^ 1, 0, (kt + 1) << 6); }
        else if (p == 2) { stageB(cur ^ 1, 1, (kt + 1) << 6); }
      }
      bf16x8 af[4], bfr[4];
#pragma unroll
      for (int t = 0; t < 4; ++t) {
        const int Ra = wm * 128 + mg * 64 + t * 16 + fr;
        af[t] = *(const bf16x8*)(Ab + Ra * 128 + ((ks * 64 + kg * 16) ^ twistL));
        const int Rb = wn * 64 + t * 16 + fr;
        bfr[t] = *(const bf16x8*)(Bb + Rb * 128 + ((ks * 64 + kg * 16) ^ twistL));
      }
      asm volatile("s_waitcnt lgkmcnt(0)" ::: "memory");
      __builtin_amdgcn_sched_barrier(0);
      __builtin_amdgcn_s_setprio(1);
#pragma unroll
      for (int t = 0; t < 4; ++t)
#pragma unroll
        for (int nf = 0; nf < 4; ++nf)
          acc[mg * 4 + t][nf] = __builtin_amdgcn_mfma_f32_16x16x32_bf16(af[t], bfr[nf], acc[mg * 4 + t][nf], 0, 0, 0);
      __builtin_amdgcn_s_setprio(0);
    }
    cur ^= 1;
  }

#pragma unroll
  for (int mf = 0; mf < 8; ++mf)
#pragma unroll
    for (int nf = 0; nf < 4; ++nf) {
      const int col = n0 + wn * 64 + nf * 16 + fr;
#pragma unroll
      for (int r = 0; r < 4; ++r) {
        const int row = m0 + wm * 128 + mf * 16 + kg * 4 + r;
        float v = acc[mf][nf][r];
        if (MODE == 0) {
          ((float*)OUTp)[(size_t)row * N + col] = v * rs[row];
        } else {
          v = v / (1.f + __expf(-v));
          ((unsigned short*)OUTp)[(size_t)row * N + col] = f2bf(v);
        }
      }
    }
}

// --- grouped causal conv as MFMA GEMM; epilogue: (Bc+bias)*dt -> dBt[row][l] --
__global__ __launch_bounds__(256) void conv_k(const unsigned short* __restrict__ xb,
                                              const unsigned short* __restrict__ wreT,
                                              const float* __restrict__ conv_b,
                                              const float* __restrict__ dt,
                                              float* __restrict__ dBt) {
  __shared__ __align__(16) unsigned short x_lds[67 * 64];
  const int l0 = blockIdx.x * 64, g = blockIdx.y, b = blockIdx.z;
  const int tid = threadIdx.x, lane = tid & 63, wid = tid >> 6;
  {
    const int r = tid >> 3, ch = (tid & 7) * 8;
#pragma unroll
    for (int pass = 0; pass < 3; ++pass) {
      int rr = r + pass * 32;
      if (rr < 67) {
        int lg = l0 - 3 + rr;
        bf16x8 v = {};
        if (lg >= 0) v = *(const bf16x8*)&xb[(size_t)(b * L_SEQ + lg) * HIDN + g * 64 + ch];
        *(bf16x8*)&x_lds[rr * 64 + ch] = v;
      }
    }
  }
  __syncthreads();
  const int fr = lane & 15, kg = lane >> 4, wm = wid;
  f32x4 acc[4] = {};
#pragma unroll
  for (int ks = 0; ks < 8; ++ks) {
    bf16x8 a = *(const bf16x8*)&x_lds[(wm * 16 + fr + (ks >> 1)) * 64 + (ks & 1) * 32 + kg * 8];
#pragma unroll
    for (int nt = 0; nt < 4; ++nt) {
      bf16x8 bq = *(const bf16x8*)&wreT[(size_t)(g * 64 + nt * 16 + fr) * 256 + ks * 32 + kg * 8];
      acc[nt] = __builtin_amdgcn_mfma_f32_16x16x32_bf16(a, bq, acc[nt], 0, 0, 0);
    }
  }
  const int lgb = l0 + wm * 16 + kg * 4;
  const float4 dt4 = *(const float4*)&dt[b * L_SEQ + lgb];
#pragma unroll
  for (int nt = 0; nt < 4; ++nt) {
    const int o = nt * 16 + fr;
    const float bias = conv_b[g * 64 + o];
    float4 vv;
    vv.x = (acc[nt][0] + bias) * dt4.x;
    vv.y = (acc[nt][1] + bias) * dt4.y;
    vv.z = (acc[nt][2] + bias) * dt4.z;
    vv.w = (acc[nt][3] + bias) * dt4.w;
    *(float4*)&dBt[((size_t)(b * NH + g) * 64 + o) * L_SEQ + lgb] = vv;
  }
}

// --------- chunked fixed-point scan v10 (1 wave per (b,h)) --------------------
// ITERS=1 specialized: pass1 is pure add-chain (E=1); E computed inline in the
// final pass from xT LDS. Dv prefetched one chunk ahead via global_load_lds
// double-buffer (per-lane global source = own dBt row; wave-uniform LDS dest).
__global__ __launch_bounds__(64) void scan_k(const float* __restrict__ dBt,
                                             const float* __restrict__ Aw,
                                             const float* __restrict__ dt,
                                             unsigned short* __restrict__ states) {
  __shared__ __align__(16) char smem[63488];
  const int bid = blockIdx.x;          // b*32 + h
  const int h = bid & 31, b = bid >> 5;
  const int lane = threadIdx.x;
  const int fr = lane & 15, kg = lane >> 4;

  char* sp = smem;                 // s-pairs [CHUNK] stride 176B   (11264 B)
  char* xT = smem + 11264;         // xT [CHUNK] stride 304B        (19456 B)
  char* db = smem + 30720;         // Dv staging: 2 bufs x 16KB

  bf16x8 afr[4][2];
  {
    const float* Ah = Aw + (size_t)h * 64 * 64;
#pragma unroll
    for (int mb = 0; mb < 4; ++mb)
#pragma unroll
      for (int kt = 0; kt < 2; ++kt) {
        const float* p = &Ah[(size_t)(mb * 16 + fr) * 64 + kt * 32 + kg * 8];
        float4 v0 = *(const float4*)p;
        float4 v1 = *(const float4*)(p + 4);
        bf16x8 f;
        f[0] = (short)f2bf(v0.x); f[1] = (short)f2bf(v0.y);
        f[2] = (short)f2bf(v0.z); f[3] = (short)f2bf(v0.w);
        f[4] = (short)f2bf(v1.x); f[5] = (short)f2bf(v1.y);
        f[6] = (short)f2bf(v1.z); f[7] = (short)f2bf(v1.w);
        afr[mb][kt] = f;
      }
  }

  const float* dBp = dBt + (size_t)(bid * 64 + lane) * L_SEQ;   // own row
  unsigned short* stp = states + (size_t)bid * L_SEQ * 64 + lane;
  const float* dtp = dt + b * L_SEQ;
  const int spw = (lane >> 1) * 4;

  auto pfDv = [&](int buf, int c) {
#pragma unroll
    for (int q = 0; q < 16; ++q)
      gl_lds16(&dBp[c * CHUNK + q * 4], db + buf * 16384 + q * 1024);
  };
  pfDv(0, 0);   // prefetch chunk 0

  float scs = 0.f;
  for (int c = 0; c < L_SEQ / CHUNK; ++c) {
    const int l0 = c * CHUNK;
    const int buf = c & 1;
    float Dv[CHUNK];
    asm volatile("s_waitcnt vmcnt(0)" ::: "memory");
#pragma unroll
    for (int q = 0; q < 16; ++q) {
      f32x4 v = *(const f32x4*)(db + buf * 16384 + q * 1024 + lane * 16);
      Dv[q * 4] = v[0]; Dv[q * 4 + 1] = v[1]; Dv[q * 4 + 2] = v[2]; Dv[q * 4 + 3] = v[3];
    }
    if (c + 1 < L_SEQ / CHUNK) pfDv(buf ^ 1, c + 1);   // prefetch next chunk
    float dtq[4];
#pragma unroll
    for (int tb = 0; tb < 4; ++tb) dtq[tb] = dtp[l0 + tb * 16 + fr];

    // ---- pass 1 (E=1): write s-pair (state BEFORE step l), then s += Dv ----
    {
      float s = scs;
#pragma unroll
      for (int l = 0; l < CHUNK; ++l) {
        float sn = qperm<0xB1>(s);
        float lo = (lane & 1) ? sn : s;
        float hi = (lane & 1) ? s : sn;
        unsigned pw;
        asm("v_cvt_pk_bf16_f32 %0, %1, %2" : "=v"(pw) : "v"(lo), "v"(hi));
        *(unsigned*)(sp + l * 176 + spw) = pw;
        s = s + Dv[l];
      }
    }
    asm volatile("" ::: "memory");
    // ---- batched matvec: X[m][t] = A_w · S, scaled by dt ----
    {
      bf16x8 bf[4][2];
#pragma unroll
      for (int tb = 0; tb < 4; ++tb)
#pragma unroll
        for (int kt = 0; kt < 2; ++kt)
          bf[tb][kt] = *(const bf16x8*)(sp + (tb * 16 + fr) * 176 + (kt * 16 + kg * 4) * 4);
      f32x4 acc[4][4];
#pragma unroll
      for (int mb = 0; mb < 4; ++mb)
#pragma unroll
        for (int tb = 0; tb < 4; ++tb) {
          f32x4 z = {0.f, 0.f, 0.f, 0.f};
          f32x4 t0 = __builtin_amdgcn_mfma_f32_16x16x32_bf16(afr[mb][0], bf[tb][0], z, 0, 0, 0);
          acc[mb][tb] = __builtin_amdgcn_mfma_f32_16x16x32_bf16(afr[mb][1], bf[tb][1], t0, 0, 0, 0);
        }
#pragma unroll
      for (int mb = 0; mb < 4; ++mb)
#pragma unroll
        for (int tb = 0; tb < 4; ++tb) {
          f32x4 v = acc[mb][tb];
          v[0] *= dtq[tb]; v[1] *= dtq[tb]; v[2] *= dtq[tb]; v[3] *= dtq[tb];
          *(f32x4*)(xT + (tb * 16 + fr) * 304 + (mb * 16 + kg * 4) * 4) = v;
        }
    }
    asm volatile("" ::: "memory");
    // ---- final pass: E inline from xT; s = E*s + Dv; store bf16 states ----
    {
      float s = scs;
#pragma unroll
      for (int l = 0; l < CHUNK; ++l) {
        float x = *(const float*)(xT + l * 304 + lane * 4);
        float E = __builtin_fmaf(x * x, 0.5f, 1.0f + x);
        s = __builtin_fmaf(E, s, Dv[l]);
        stp[(size_t)(l0 + l) * 64] = f2bf(s);
      }
      scs = s;
    }
  }
}

// -- C projection + x*D + silu(gate) multiply; writes hsb (b,l,hid) bf16 -------
__global__ __launch_bounds__(256) void proj_k(const unsigned short* __restrict__ st,
                                              const unsigned short* __restrict__ cwb,
                                              const unsigned short* __restrict__ xbp,
                                              const float* __restrict__ Dp,
                                              const unsigned short* __restrict__ gsb,
                                              unsigned short* __restrict__ hsb) {
  const int l0 = blockIdx.x * 64, h = blockIdx.y, b = blockIdx.z;
  const int tid = threadIdx.x, lane = tid & 63, wid = tid >> 6;
  const int fr = lane & 15, kg = lane >> 4, wm = wid;
  f32x4 acc[4] = {};
#pragma unroll
  for (int ks = 0; ks < 2; ++ks) {
    bf16x8 a = *(const bf16x8*)&st[((size_t)(b * NH + h) * L_SEQ + l0 + wm * 16 + fr) * 64 + ks * 32 + kg * 8];
#pragma unroll
    for (int nt = 0; nt < 4; ++nt) {
      bf16x8 bq = *(const bf16x8*)&cwb[(size_t)(h * 64 + nt * 16 + fr) * 64 + ks * 32 + kg * 8];
      acc[nt] = __builtin_amdgcn_mfma_f32_16x16x32_bf16(a, bq, acc[nt], 0, 0, 0);
    }
  }
  const float Dh = Dp[h];
#pragma unroll
  for (int nt = 0; nt < 4; ++nt) {
    const int ccol = h * 64 + nt * 16 + fr;
#pragma unroll
    for (int r = 0; r < 4; ++r) {
      const int lg = l0 + wm * 16 + kg * 4 + r;
      const size_t idx = (size_t)(b * L_SEQ + lg) * HIDN + ccol;
      float v = acc[nt][r] + bf2f(xbp[idx]) * Dh;
      hsb[idx] = f2bf(v * bf2f(gsb[idx]));
    }
  }
}

// ---------- per-row rsqrt(mean(hs^2)+eps) from bf16 hs (norm fold) ------------
__global__ __launch_bounds__(256) void rs_k(const unsigned short* __restrict__ hsb,
                                            float* __restrict__ rs) {
  const int row = blockIdx.x;
  const unsigned short* p = hsb + (size_t)row * HIDN;
  const int c0 = threadIdx.x * 8;
  bf16x8 u = *(const bf16x8*)&p[c0];
  float ss = 0.f;
#pragma unroll
  for (int i = 0; i < 8; ++i) { float f = bf2f((unsigned short)u[i]); ss += f * f; }
#pragma unroll
  for (int off = 32; off; off >>= 1) ss += __shfl_xor(ss, off);
  __shared__ float pr[4];
  if ((threadIdx.x & 63) == 0) pr[threadIdx.x >> 6] = ss;
  __syncthreads();
  if (threadIdx.x == 0) {
    float tot = pr[0] + pr[1] + pr[2] + pr[3];
    rs[row] = rsqrtf(tot * (1.f / HIDN) + 1e-6f);
  }
}

extern "C" void kernel_launch(void* const* d_in, const int* in_sizes, int n_in,
                              void* d_out, int out_size, void* d_ws, size_t ws_size,
                              hipStream_t stream) {
  const float* x  = (const float*)d_in[0];
  const float* dt = (const float*)d_in[1];
  const float* gw = (const float*)d_in[2];
  const float* Aw = (const float*)d_in[3];
  const float* cw = (const float*)d_in[4];
  const float* cb = (const float*)d_in[5];
  const float* Cw = (const float*)d_in[6];
  const float* Dp = (const float*)d_in[7];
  const float* nw = (const float*)d_in[8];
  const float* ow = (const float*)d_in[9];
  float* out = (float*)d_out;

  // workspace (bytes): hsb overlays dBt (dead after scan); stb has own slot.
  // gate bf16 lives in d_out's first 32MB (dead before out-GEMM writes).
  char* w = (char*)d_ws;
  unsigned short* xb   = (unsigned short*)(w);                // 32MB
  unsigned short* gwb  = (unsigned short*)(w + 33554432);     // 8MB
  unsigned short* owb  = (unsigned short*)(w + 41943040);     // 8MB (ow*nw)
  unsigned short* wret = (unsigned short*)(w + 50331648);     // 1MB
  unsigned short* cwb  = (unsigned short*)(w + 51380224);     // 256KB
  float*          rsb  = (float*)(w + 51642368);              // 32KB
  float*          dBt  = (float*)(w + 52428800);              // 64MB
  unsigned short* hsb  = (unsigned short*)(w + 52428800);     // overlay (after scan)
  unsigned short* stb  = (unsigned short*)(w + 119537664);    // 32MB
  unsigned short* gsb  = (unsigned short*)d_out;              // gate bf16, 32MB
  if (ws_size < 153092096) return;

  cvt_bf16_k<<<2048, 256, 0, stream>>>(x, xb, 16777216 / 4);
  cvt_bf16_k<<<1024, 256, 0, stream>>>(gw, gwb, 4194304 / 4);
  ownw_k<<<4096, 256, 0, stream>>>(ow, nw, owb);
  cvt_bf16_k<<<128, 256, 0, stream>>>(Cw, cwb, 131072 / 4);
  wret_k<<<2048, 256, 0, stream>>>(cw, wret);

  // gate GEMM (256^2 4-phase pipelined), silu -> bf16 gsb
  gemm256_k<1><<<256, 512, 0, stream>>>(xb, gwb, nullptr, gsb, 8192, 2048, 2048);
  conv_k<<<dim3(32, 32, 4), 256, 0, stream>>>(xb, wret, cb, dt, dBt);
  scan_k<<<128, 64, 0, stream>>>(dBt, Aw, dt, stb);
  proj_k<<<dim3(32, 32, 4), 256, 0, stream>>>(stb, cwb, xb, Dp, gsb, hsb);
  rs_k<<<8192, 256, 0, stream>>>(hsb, rsb);
  // out GEMM (256^2 4-phase pipelined), rs-scaled f32
  gemm256_k<0><<<256, 512, 0, stream>>>(hsb, owb, rsb, out, 8192, 2048, 2048);
}

// Round 18
// 352.256 us; speedup vs baseline: 2.7314x; 1.1825x over previous
//
#include <hip/hip_runtime.h>
#include <hip/hip_bf16.h>

#define L_SEQ 2048
#define HIDN  2048
#define NH    32
#define BATCHN 4
#define CHUNK 64

using bf16x8 = __attribute__((ext_vector_type(8))) short;
using f32x4  = __attribute__((ext_vector_type(4))) float;

__device__ __forceinline__ unsigned short f2bf(float f) {
  union { float f; unsigned u; } v; v.f = f;
  unsigned r = v.u + 0x7fffu + ((v.u >> 16) & 1u);
  return (unsigned short)(r >> 16);
}

__device__ __forceinline__ float bf2f(unsigned short u) {
  unsigned v = ((unsigned)u) << 16;
  return __builtin_bit_cast(float, v);
}

__device__ __forceinline__ void gl_lds16(const void* g, void* l) {
  __builtin_amdgcn_global_load_lds(
      (const __attribute__((address_space(1))) unsigned int*)g,
      (__attribute__((address_space(3))) unsigned int*)l, 16, 0, 0);
}

template <int CTRL>
__device__ __forceinline__ float qperm(float x) {
  int xi = __builtin_bit_cast(int, x);
  int yi = __builtin_amdgcn_update_dpp(0, xi, CTRL, 0xF, 0xF, true);
  return __builtin_bit_cast(float, yi);
}

#define BARRIER() do { asm volatile("" ::: "memory"); \
  __builtin_amdgcn_s_barrier(); asm volatile("" ::: "memory"); } while (0)

// ---------------- f32 -> bf16 convert (grid-stride over n/4 float4s) ----------
__global__ __launch_bounds__(256) void cvt_bf16_k(const float* __restrict__ in,
                                                  unsigned short* __restrict__ out, int n4) {
  for (int i = blockIdx.x * 256 + threadIdx.x; i < n4; i += gridDim.x * 256) {
    float4 v = *(const float4*)&in[(size_t)i * 4];
    ushort4 o;
    o.x = f2bf(v.x); o.y = f2bf(v.y); o.z = f2bf(v.z); o.w = f2bf(v.w);
    *(ushort4*)&out[(size_t)i * 4] = o;
  }
}

// ---- out-weight prep: owb[n][k] = bf16(ow[n][k] * nw[k])  (norm-weight fold) -
__global__ __launch_bounds__(256) void ownw_k(const float* __restrict__ ow,
                                              const float* __restrict__ nw,
                                              unsigned short* __restrict__ out) {
  int i = blockIdx.x * 256 + threadIdx.x;    // over 4194304/4 float4s
  float4 v = *(const float4*)&ow[(size_t)i * 4];
  int k0 = (i * 4) & 2047;
  ushort4 o;
  o.x = f2bf(v.x * nw[k0 + 0]); o.y = f2bf(v.y * nw[k0 + 1]);
  o.z = f2bf(v.z * nw[k0 + 2]); o.w = f2bf(v.w * nw[k0 + 3]);
  *(ushort4*)&out[(size_t)i * 4] = o;
}

// -------- conv weight transform: wreT[o][k*64+i] = conv_w[o][i][k] (bf16) -----
__global__ __launch_bounds__(256) void wret_k(const float* __restrict__ cw,
                                              unsigned short* __restrict__ out) {
  int idx = blockIdx.x * 256 + threadIdx.x;   // 2048*256 total
  int o = idx >> 8, q = idx & 255;
  int k = q >> 6, i = q & 63;
  out[idx] = f2bf(cw[o * 256 + i * 4 + k]);
}

// ===== 256x256 tile, BK=64, 8-wave, double-buffered 4-phase pipelined GEMM ====
// (standalone; used for the out-projection with rs[m] scaling)
__global__ __launch_bounds__(512, 2) void gemm256_out_k(const unsigned short* __restrict__ X,
                                                        const unsigned short* __restrict__ W,
                                                        const float* __restrict__ rs,
                                                        float* __restrict__ OUT,
                                                        int M, int N, int K) {
  __shared__ __align__(16) char smem[131072];
  const int tid = threadIdx.x, lane = tid & 63, w = tid >> 6;
  const int wm = w >> 2, wn = w & 3, fr = lane & 15, kg = lane >> 4;
  const int nbx = M >> 8, nby = N >> 8;
  const int nwg = nbx * nby, cpx = nwg >> 3;
  const int lin = blockIdx.x;
  const int swz = (lin & 7) * cpx + (lin >> 3);     // XCD-bijective (nwg%8==0)
  const int m0 = (swz % nbx) * 256, n0 = (swz / nbx) * 256;
  const int twistL = (fr & 7) << 4;

  auto stageA = [&](int buf, int half, int kq) {
#pragma unroll
    for (int q = 0; q < 2; ++q) {
      int s = q * 8192 + tid * 16;
      int r = s >> 7, cb = s & 127;
      const void* src = &X[(size_t)(m0 + half * 128 + r) * K + kq + ((cb ^ ((r & 7) << 4)) >> 1)];
      void* dst = smem + buf * 65536 + half * 16384 + q * 8192 + w * 1024;
      gl_lds16(src, dst);
    }
  };
  auto stageB = [&](int buf, int half, int kq) {
#pragma unroll
    for (int q = 0; q < 2; ++q) {
      int s = q * 8192 + tid * 16;
      int r = s >> 7, cb = s & 127;
      const void* src = &W[(size_t)(n0 + half * 128 + r) * K + kq + ((cb ^ ((r & 7) << 4)) >> 1)];
      void* dst = smem + buf * 65536 + 32768 + half * 16384 + q * 8192 + w * 1024;
      gl_lds16(src, dst);
    }
  };

  stageA(0, 0, 0); stageA(0, 1, 0); stageB(0, 0, 0); stageB(0, 1, 0);

  f32x4 acc[8][4] = {};
  int cur = 0;
  const int NT = K >> 6;
  for (int kt = 0; kt < NT; ++kt) {
    const char* Ab = smem + cur * 65536;
    const char* Bb = smem + cur * 65536 + 32768;
#pragma unroll
    for (int p = 0; p < 4; ++p) {
      const int mg = p & 1, ks = p >> 1;
      if (p == 0) { asm volatile("s_waitcnt vmcnt(0)" ::: "memory"); }
      BARRIER();
      if (kt + 1 < NT) {
        if (p == 0)      { stageA(cur ^ 1, 0, (kt + 1) << 6); stageA(cur ^ 1, 1, (kt + 1) << 6); }
        else if (p == 1) { stageB(cur ^ 1, 0, (kt + 1) << 6); }
        else if (p == 2) { stageB(cur ^ 1, 1, (kt + 1) << 6); }
      }
      bf16x8 af[4], bfr[4];
#pragma unroll
      for (int t = 0; t < 4; ++t) {
        const int Ra = wm * 128 + mg * 64 + t * 16 + fr;
        af[t] = *(const bf16x8*)(Ab + Ra * 128 + ((ks * 64 + kg * 16) ^ twistL));
        const int Rb = wn * 64 + t * 16 + fr;
        bfr[t] = *(const bf16x8*)(Bb + Rb * 128 + ((ks * 64 + kg * 16) ^ twistL));
      }
      asm volatile("s_waitcnt lgkmcnt(0)" ::: "memory");
      __builtin_amdgcn_sched_barrier(0);
      __builtin_amdgcn_s_setprio(1);
#pragma unroll
      for (int t = 0; t < 4; ++t)
#pragma unroll
        for (int nf = 0; nf < 4; ++nf)
          acc[mg * 4 + t][nf] = __builtin_amdgcn_mfma_f32_16x16x32_bf16(af[t], bfr[nf], acc[mg * 4 + t][nf], 0, 0, 0);
      __builtin_amdgcn_s_setprio(0);
    }
    cur ^= 1;
  }

#pragma unroll
  for (int mf = 0; mf < 8; ++mf)
#pragma unroll
    for (int nf = 0; nf < 4; ++nf) {
      const int col = n0 + wn * 64 + nf * 16 + fr;
#pragma unroll
      for (int r = 0; r < 4; ++r) {
        const int row = m0 + wm * 128 + mf * 16 + kg * 4 + r;
        OUT[(size_t)row * N + col] = acc[mf][nf][r] * rs[row];
      }
    }
}

// --- grouped causal conv as MFMA GEMM; epilogue: (Bc+bias)*dt -> dBt[row][l] --
__global__ __launch_bounds__(256) void conv_k(const unsigned short* __restrict__ xb,
                                              const unsigned short* __restrict__ wreT,
                                              const float* __restrict__ conv_b,
                                              const float* __restrict__ dt,
                                              float* __restrict__ dBt) {
  __shared__ __align__(16) unsigned short x_lds[67 * 64];
  const int l0 = blockIdx.x * 64, g = blockIdx.y, b = blockIdx.z;
  const int tid = threadIdx.x, lane = tid & 63, wid = tid >> 6;
  {
    const int r = tid >> 3, ch = (tid & 7) * 8;
#pragma unroll
    for (int pass = 0; pass < 3; ++pass) {
      int rr = r + pass * 32;
      if (rr < 67) {
        int lg = l0 - 3 + rr;
        bf16x8 v = {};
        if (lg >= 0) v = *(const bf16x8*)&xb[(size_t)(b * L_SEQ + lg) * HIDN + g * 64 + ch];
        *(bf16x8*)&x_lds[rr * 64 + ch] = v;
      }
    }
  }
  __syncthreads();
  const int fr = lane & 15, kg = lane >> 4, wm = wid;
  f32x4 acc[4] = {};
#pragma unroll
  for (int ks = 0; ks < 8; ++ks) {
    bf16x8 a = *(const bf16x8*)&x_lds[(wm * 16 + fr + (ks >> 1)) * 64 + (ks & 1) * 32 + kg * 8];
#pragma unroll
    for (int nt = 0; nt < 4; ++nt) {
      bf16x8 bq = *(const bf16x8*)&wreT[(size_t)(g * 64 + nt * 16 + fr) * 256 + ks * 32 + kg * 8];
      acc[nt] = __builtin_amdgcn_mfma_f32_16x16x32_bf16(a, bq, acc[nt], 0, 0, 0);
    }
  }
  const int lgb = l0 + wm * 16 + kg * 4;
  const float4 dt4 = *(const float4*)&dt[b * L_SEQ + lgb];
#pragma unroll
  for (int nt = 0; nt < 4; ++nt) {
    const int o = nt * 16 + fr;
    const float bias = conv_b[g * 64 + o];
    float4 vv;
    vv.x = (acc[nt][0] + bias) * dt4.x;
    vv.y = (acc[nt][1] + bias) * dt4.y;
    vv.z = (acc[nt][2] + bias) * dt4.z;
    vv.w = (acc[nt][3] + bias) * dt4.w;
    *(float4*)&dBt[((size_t)(b * NH + g) * 64 + o) * L_SEQ + lgb] = vv;
  }
}

// ==== FUSED: blocks 0..127 = chunked scan (1 wave; 128KB LDS -> CU-exclusive,
// ==== no GEMM contention); blocks 128..383 = gate GEMM 256^2 (silu -> bf16).
__global__ __launch_bounds__(512, 1) void scan_gate_k(const float* __restrict__ dBt,
                                                      const float* __restrict__ Aw,
                                                      const float* __restrict__ dt,
                                                      unsigned short* __restrict__ states,
                                                      const unsigned short* __restrict__ X,
                                                      const unsigned short* __restrict__ W,
                                                      unsigned short* __restrict__ GOUT) {
  __shared__ __align__(16) char smem[131072];
  if (blockIdx.x >= 128) {
    // ------------------ gate GEMM (M=8192,N=2048,K=2048) ---------------------
    const int tid = threadIdx.x, lane = tid & 63, w = tid >> 6;
    const int wm = w >> 2, wn = w & 3, fr = lane & 15, kg = lane >> 4;
    const int gb = blockIdx.x - 128;            // 0..255
    const int swz = (gb & 7) * 32 + (gb >> 3);  // XCD-bijective (256 blocks)
    const int m0 = (swz & 31) * 256, n0 = (swz >> 5) * 256;
    const int twistL = (fr & 7) << 4;
    auto stageA = [&](int buf, int half, int kq) {
#pragma unroll
      for (int q = 0; q < 2; ++q) {
        int s = q * 8192 + tid * 16;
        int r = s >> 7, cb = s & 127;
        const void* src = &X[(size_t)(m0 + half * 128 + r) * 2048 + kq + ((cb ^ ((r & 7) << 4)) >> 1)];
        void* dst = smem + buf * 65536 + half * 16384 + q * 8192 + w * 1024;
        gl_lds16(src, dst);
      }
    };
    auto stageB = [&](int buf, int half, int kq) {
#pragma unroll
      for (int q = 0; q < 2; ++q) {
        int s = q * 8192 + tid * 16;
        int r = s >> 7, cb = s & 127;
        const void* src = &W[(size_t)(n0 + half * 128 + r) * 2048 + kq + ((cb ^ ((r & 7) << 4)) >> 1)];
        void* dst = smem + buf * 65536 + 32768 + half * 16384 + q * 8192 + w * 1024;
        gl_lds16(src, dst);
      }
    };
    stageA(0, 0, 0); stageA(0, 1, 0); stageB(0, 0, 0); stageB(0, 1, 0);
    f32x4 acc[8][4] = {};
    int cur = 0;
    for (int kt = 0; kt < 32; ++kt) {
      const char* Ab = smem + cur * 65536;
      const char* Bb = smem + cur * 65536 + 32768;
#pragma unroll
      for (int p = 0; p < 4; ++p) {
        const int mg = p & 1, ks = p >> 1;
        if (p == 0) { asm volatile("s_waitcnt vmcnt(0)" ::: "memory"); }
        BARRIER();
        if (kt + 1 < 32) {
          if (p == 0)      { stageA(cur ^ 1, 0, (kt + 1) << 6); stageA(cur ^ 1, 1, (kt + 1) << 6); }
          else if (p == 1) { stageB(cur ^ 1, 0, (kt + 1) << 6); }
          else if (p == 2) { stageB(cur ^ 1, 1, (kt + 1) << 6); }
        }
        bf16x8 af[4], bfr[4];
#pragma unroll
        for (int t = 0; t < 4; ++t) {
          const int Ra = wm * 128 + mg * 64 + t * 16 + fr;
          af[t] = *(const bf16x8*)(Ab + Ra * 128 + ((ks * 64 + kg * 16) ^ twistL));
          const int Rb = wn * 64 + t * 16 + fr;
          bfr[t] = *(const bf16x8*)(Bb + Rb * 128 + ((ks * 64 + kg * 16) ^ twistL));
        }
        asm volatile("s_waitcnt lgkmcnt(0)" ::: "memory");
        __builtin_amdgcn_sched_barrier(0);
        __builtin_amdgcn_s_setprio(1);
#pragma unroll
        for (int t = 0; t < 4; ++t)
#pragma unroll
          for (int nf = 0; nf < 4; ++nf)
            acc[mg * 4 + t][nf] = __builtin_amdgcn_mfma_f32_16x16x32_bf16(af[t], bfr[nf], acc[mg * 4 + t][nf], 0, 0, 0);
        __builtin_amdgcn_s_setprio(0);
      }
      cur ^= 1;
    }
#pragma unroll
    for (int mf = 0; mf < 8; ++mf)
#pragma unroll
      for (int nf = 0; nf < 4; ++nf) {
        const int col = n0 + wn * 64 + nf * 16 + fr;
#pragma unroll
        for (int r = 0; r < 4; ++r) {
          const int row = m0 + wm * 128 + mf * 16 + kg * 4 + r;
          float v = acc[mf][nf][r];
          v = v / (1.f + __expf(-v));
          GOUT[(size_t)row * 2048 + col] = f2bf(v);
        }
      }
    return;
  }
  // ----------------------------- scan (1 wave) ------------------------------
  if (threadIdx.x >= 64) return;
  const int bid = blockIdx.x;          // b*32 + h
  const int h = bid & 31, b = bid >> 5;
  const int lane = threadIdx.x;
  const int fr = lane & 15, kg = lane >> 4;

  char* sp = smem;                 // s-pairs [CHUNK] stride 176B   (11264 B)
  char* xT = smem + 11264;         // xT [CHUNK] stride 304B        (19456 B)
  char* db = smem + 30720;         // Dv staging: 2 bufs x 16KB

  bf16x8 afr[4][2];
  {
    const float* Ah = Aw + (size_t)h * 64 * 64;
#pragma unroll
    for (int mb = 0; mb < 4; ++mb)
#pragma unroll
      for (int kt = 0; kt < 2; ++kt) {
        const float* p = &Ah[(size_t)(mb * 16 + fr) * 64 + kt * 32 + kg * 8];
        float4 v0 = *(const float4*)p;
        float4 v1 = *(const float4*)(p + 4);
        bf16x8 f;
        f[0] = (short)f2bf(v0.x); f[1] = (short)f2bf(v0.y);
        f[2] = (short)f2bf(v0.z); f[3] = (short)f2bf(v0.w);
        f[4] = (short)f2bf(v1.x); f[5] = (short)f2bf(v1.y);
        f[6] = (short)f2bf(v1.z); f[7] = (short)f2bf(v1.w);
        afr[mb][kt] = f;
      }
  }

  const float* dBp = dBt + (size_t)(bid * 64 + lane) * L_SEQ;   // own row
  unsigned short* stp = states + (size_t)bid * L_SEQ * 64 + lane;
  const float* dtp = dt + b * L_SEQ;
  const int spw = (lane >> 1) * 4;

  auto pfDv = [&](int buf, int c) {
#pragma unroll
    for (int q = 0; q < 16; ++q)
      gl_lds16(&dBp[c * CHUNK + q * 4], db + buf * 16384 + q * 1024);
  };
  pfDv(0, 0);

  float scs = 0.f;
  for (int c = 0; c < L_SEQ / CHUNK; ++c) {
    const int l0 = c * CHUNK;
    const int buf = c & 1;
    float Dv[CHUNK];
    asm volatile("s_waitcnt vmcnt(0)" ::: "memory");
#pragma unroll
    for (int q = 0; q < 16; ++q) {
      f32x4 v = *(const f32x4*)(db + buf * 16384 + q * 1024 + lane * 16);
      Dv[q * 4] = v[0]; Dv[q * 4 + 1] = v[1]; Dv[q * 4 + 2] = v[2]; Dv[q * 4 + 3] = v[3];
    }
    if (c + 1 < L_SEQ / CHUNK) pfDv(buf ^ 1, c + 1);
    float dtq[4];
#pragma unroll
    for (int tb = 0; tb < 4; ++tb) dtq[tb] = dtp[l0 + tb * 16 + fr];

    // ---- pass 1 (E=1): write s-pair (state BEFORE step l), then s += Dv ----
    {
      float s = scs;
#pragma unroll
      for (int l = 0; l < CHUNK; ++l) {
        float sn = qperm<0xB1>(s);
        float lo = (lane & 1) ? sn : s;
        float hi = (lane & 1) ? s : sn;
        unsigned pw;
        asm("v_cvt_pk_bf16_f32 %0, %1, %2" : "=v"(pw) : "v"(lo), "v"(hi));
        *(unsigned*)(sp + l * 176 + spw) = pw;
        s = s + Dv[l];
      }
    }
    asm volatile("" ::: "memory");
    // ---- batched matvec: X[m][t] = A_w · S, scaled by dt ----
    {
      bf16x8 bf[4][2];
#pragma unroll
      for (int tb = 0; tb < 4; ++tb)
#pragma unroll
        for (int kt = 0; kt < 2; ++kt)
          bf[tb][kt] = *(const bf16x8*)(sp + (tb * 16 + fr) * 176 + (kt * 16 + kg * 4) * 4);
      f32x4 acc[4][4];
#pragma unroll
      for (int mb = 0; mb < 4; ++mb)
#pragma unroll
        for (int tb = 0; tb < 4; ++tb) {
          f32x4 z = {0.f, 0.f, 0.f, 0.f};
          f32x4 t0 = __builtin_amdgcn_mfma_f32_16x16x32_bf16(afr[mb][0], bf[tb][0], z, 0, 0, 0);
          acc[mb][tb] = __builtin_amdgcn_mfma_f32_16x16x32_bf16(afr[mb][1], bf[tb][1], t0, 0, 0, 0);
        }
#pragma unroll
      for (int mb = 0; mb < 4; ++mb)
#pragma unroll
        for (int tb = 0; tb < 4; ++tb) {
          f32x4 v = acc[mb][tb];
          v[0] *= dtq[tb]; v[1] *= dtq[tb]; v[2] *= dtq[tb]; v[3] *= dtq[tb];
          *(f32x4*)(xT + (tb * 16 + fr) * 304 + (mb * 16 + kg * 4) * 4) = v;
        }
    }
    asm volatile("" ::: "memory");
    // ---- final pass: x read 8-at-a-time (latency amortized), E inline ----
    {
      float s = scs;
#pragma unroll
      for (int gq = 0; gq < CHUNK / 8; ++gq) {
        float xs[8];
#pragma unroll
        for (int j = 0; j < 8; ++j)
          xs[j] = *(const float*)(xT + (gq * 8 + j) * 304 + lane * 4);
#pragma unroll
        for (int j = 0; j < 8; ++j) {
          const int l = gq * 8 + j;
          float x = xs[j];
          float E = __builtin_fmaf(x * x, 0.5f, 1.0f + x);
          s = __builtin_fmaf(E, s, Dv[l]);
          stp[(size_t)(l0 + l) * 64] = f2bf(s);
        }
      }
      scs = s;
    }
  }
}

// -- C projection + x*D + silu(gate) multiply; writes hsb (b,l,hid) bf16 -------
__global__ __launch_bounds__(256) void proj_k(const unsigned short* __restrict__ st,
                                              const unsigned short* __restrict__ cwb,
                                              const unsigned short* __restrict__ xbp,
                                              const float* __restrict__ Dp,
                                              const unsigned short* __restrict__ gsb,
                                              unsigned short* __restrict__ hsb) {
  const int l0 = blockIdx.x * 64, h = blockIdx.y, b = blockIdx.z;
  const int tid = threadIdx.x, lane = tid & 63, wid = tid >> 6;
  const int fr = lane & 15, kg = lane >> 4, wm = wid;
  f32x4 acc[4] = {};
#pragma unroll
  for (int ks = 0; ks < 2; ++ks) {
    bf16x8 a = *(const bf16x8*)&st[((size_t)(b * NH + h) * L_SEQ + l0 + wm * 16 + fr) * 64 + ks * 32 + kg * 8];
#pragma unroll
    for (int nt = 0; nt < 4; ++nt) {
      bf16x8 bq = *(const bf16x8*)&cwb[(size_t)(h * 64 + nt * 16 + fr) * 64 + ks * 32 + kg * 8];
      acc[nt] = __builtin_amdgcn_mfma_f32_16x16x32_bf16(a, bq, acc[nt], 0, 0, 0);
    }
  }
  const float Dh = Dp[h];
#pragma unroll
  for (int nt = 0; nt < 4; ++nt) {
    const int ccol = h * 64 + nt * 16 + fr;
#pragma unroll
    for (int r = 0; r < 4; ++r) {
      const int lg = l0 + wm * 16 + kg * 4 + r;
      const size_t idx = (size_t)(b * L_SEQ + lg) * HIDN + ccol;
      float v = acc[nt][r] + bf2f(xbp[idx]) * Dh;
      hsb[idx] = f2bf(v * bf2f(gsb[idx]));
    }
  }
}

// ---------- per-row rsqrt(mean(hs^2)+eps) from bf16 hs (norm fold) ------------
__global__ __launch_bounds__(256) void rs_k(const unsigned short* __restrict__ hsb,
                                            float* __restrict__ rs) {
  const int row = blockIdx.x;
  const unsigned short* p = hsb + (size_t)row * HIDN;
  const int c0 = threadIdx.x * 8;
  bf16x8 u = *(const bf16x8*)&p[c0];
  float ss = 0.f;
#pragma unroll
  for (int i = 0; i < 8; ++i) { float f = bf2f((unsigned short)u[i]); ss += f * f; }
#pragma unroll
  for (int off = 32; off; off >>= 1) ss += __shfl_xor(ss, off);
  __shared__ float pr[4];
  if ((threadIdx.x & 63) == 0) pr[threadIdx.x >> 6] = ss;
  __syncthreads();
  if (threadIdx.x == 0) {
    float tot = pr[0] + pr[1] + pr[2] + pr[3];
    rs[row] = rsqrtf(tot * (1.f / HIDN) + 1e-6f);
  }
}

extern "C" void kernel_launch(void* const* d_in, const int* in_sizes, int n_in,
                              void* d_out, int out_size, void* d_ws, size_t ws_size,
                              hipStream_t stream) {
  const float* x  = (const float*)d_in[0];
  const float* dt = (const float*)d_in[1];
  const float* gw = (const float*)d_in[2];
  const float* Aw = (const float*)d_in[3];
  const float* cw = (const float*)d_in[4];
  const float* cb = (const float*)d_in[5];
  const float* Cw = (const float*)d_in[6];
  const float* Dp = (const float*)d_in[7];
  const float* nw = (const float*)d_in[8];
  const float* ow = (const float*)d_in[9];
  float* out = (float*)d_out;

  // workspace (bytes): hsb overlays dBt (dead after scan); stb has own slot.
  // gate bf16 lives in d_out's first 32MB (dead before out-GEMM writes).
  char* w = (char*)d_ws;
  unsigned short* xb   = (unsigned short*)(w);                // 32MB
  unsigned short* gwb  = (unsigned short*)(w + 33554432);     // 8MB
  unsigned short* owb  = (unsigned short*)(w + 41943040);     // 8MB (ow*nw)
  unsigned short* wret = (unsigned short*)(w + 50331648);     // 1MB
  unsigned short* cwb  = (unsigned short*)(w + 51380224);     // 256KB
  float*          rsb  = (float*)(w + 51642368);              // 32KB
  float*          dBt  = (float*)(w + 52428800);              // 64MB
  unsigned short* hsb  = (unsigned short*)(w + 52428800);     // overlay (after scan)
  unsigned short* stb  = (unsigned short*)(w + 119537664);    // 32MB
  unsigned short* gsb  = (unsigned short*)d_out;              // gate bf16, 32MB
  if (ws_size < 153092096) return;

  cvt_bf16_k<<<2048, 256, 0, stream>>>(x, xb, 16777216 / 4);
  cvt_bf16_k<<<1024, 256, 0, stream>>>(gw, gwb, 4194304 / 4);
  ownw_k<<<4096, 256, 0, stream>>>(ow, nw, owb);
  cvt_bf16_k<<<128, 256, 0, stream>>>(Cw, cwb, 131072 / 4);
  wret_k<<<2048, 256, 0, stream>>>(cw, wret);

  conv_k<<<dim3(32, 32, 4), 256, 0, stream>>>(xb, wret, cb, dt, dBt);
  // FUSED: scan (blocks 0..127, CU-exclusive via 128KB LDS) || gate GEMM
  scan_gate_k<<<384, 512, 0, stream>>>(dBt, Aw, dt, stb, xb, gwb, gsb);
  proj_k<<<dim3(32, 32, 4), 256, 0, stream>>>(stb, cwb, xb, Dp, gsb, hsb);
  rs_k<<<8192, 256, 0, stream>>>(hsb, rsb);
  gemm256_out_k<<<256, 512, 0, stream>>>(hsb, owb, rsb, out, 8192, 2048, 2048);
}

// Round 19
// 325.505 us; speedup vs baseline: 2.9559x; 1.0822x over previous
//
#include <hip/hip_runtime.h>
#include <hip/hip_bf16.h>

#define L_SEQ 2048
#define HIDN  2048
#define NH    32
#define BATCHN 4
#define CHUNK 64

using bf16x8 = __attribute__((ext_vector_type(8))) short;
using f32x4  = __attribute__((ext_vector_type(4))) float;

__device__ __forceinline__ unsigned short f2bf(float f) {
  union { float f; unsigned u; } v; v.f = f;
  unsigned r = v.u + 0x7fffu + ((v.u >> 16) & 1u);
  return (unsigned short)(r >> 16);
}

__device__ __forceinline__ float bf2f(unsigned short u) {
  unsigned v = ((unsigned)u) << 16;
  return __builtin_bit_cast(float, v);
}

__device__ __forceinline__ void gl_lds16(const void* g, void* l) {
  __builtin_amdgcn_global_load_lds(
      (const __attribute__((address_space(1))) unsigned int*)g,
      (__attribute__((address_space(3))) unsigned int*)l, 16, 0, 0);
}

template <int CTRL>
__device__ __forceinline__ float qperm(float x) {
  int xi = __builtin_bit_cast(int, x);
  int yi = __builtin_amdgcn_update_dpp(0, xi, CTRL, 0xF, 0xF, true);
  return __builtin_bit_cast(float, yi);
}

#define BARRIER() do { asm volatile("" ::: "memory"); \
  __builtin_amdgcn_s_barrier(); asm volatile("" ::: "memory"); } while (0)

// ---- merged prep: x->bf16, gw->bf16, ow*nw->bf16, Cw->bf16, conv-w transform -
__global__ __launch_bounds__(256) void prep_k(const float* __restrict__ x,
                                              const float* __restrict__ gw,
                                              const float* __restrict__ ow,
                                              const float* __restrict__ nw,
                                              const float* __restrict__ Cw,
                                              const float* __restrict__ cw,
                                              unsigned short* __restrict__ xb,
                                              unsigned short* __restrict__ gwb,
                                              unsigned short* __restrict__ owb,
                                              unsigned short* __restrict__ cwb,
                                              unsigned short* __restrict__ wret) {
  const int U0 = 4194304, U1 = U0 + 1048576, U2 = U1 + 1048576;
  const int U3 = U2 + 32768, U4 = U3 + 524288;
  for (int i = blockIdx.x * 256 + threadIdx.x; i < U4; i += gridDim.x * 256) {
    if (i < U0) {
      float4 v = *(const float4*)&x[(size_t)i * 4];
      ushort4 o = { f2bf(v.x), f2bf(v.y), f2bf(v.z), f2bf(v.w) };
      *(ushort4*)&xb[(size_t)i * 4] = o;
    } else if (i < U1) {
      int j = i - U0;
      float4 v = *(const float4*)&gw[(size_t)j * 4];
      ushort4 o = { f2bf(v.x), f2bf(v.y), f2bf(v.z), f2bf(v.w) };
      *(ushort4*)&gwb[(size_t)j * 4] = o;
    } else if (i < U2) {
      int j = i - U1;
      float4 v = *(const float4*)&ow[(size_t)j * 4];
      int k0 = (j * 4) & 2047;
      ushort4 o = { f2bf(v.x * nw[k0]), f2bf(v.y * nw[k0 + 1]),
                    f2bf(v.z * nw[k0 + 2]), f2bf(v.w * nw[k0 + 3]) };
      *(ushort4*)&owb[(size_t)j * 4] = o;
    } else if (i < U3) {
      int j = i - U2;
      float4 v = *(const float4*)&Cw[(size_t)j * 4];
      ushort4 o = { f2bf(v.x), f2bf(v.y), f2bf(v.z), f2bf(v.w) };
      *(ushort4*)&cwb[(size_t)j * 4] = o;
    } else {
      int idx = i - U3;
      int o = idx >> 8, q = idx & 255;
      int k = q >> 6, ii = q & 63;
      wret[idx] = f2bf(cw[o * 256 + ii * 4 + k]);
    }
  }
}

// ===== 256x256 tile, BK=64, 8-wave, double-buffered 4-phase pipelined GEMM ====
// out-projection; epilogue: v * rsqrt(mean(hs^2)+eps) from row sums buffer.
__global__ __launch_bounds__(512, 2) void gemm256_out_k(const unsigned short* __restrict__ X,
                                                        const unsigned short* __restrict__ W,
                                                        const float* __restrict__ sums,
                                                        float* __restrict__ OUT,
                                                        int M, int N, int K) {
  __shared__ __align__(16) char smem[131072];
  const int tid = threadIdx.x, lane = tid & 63, w = tid >> 6;
  const int wm = w >> 2, wn = w & 3, fr = lane & 15, kg = lane >> 4;
  const int nbx = M >> 8, nby = N >> 8;
  const int nwg = nbx * nby, cpx = nwg >> 3;
  const int lin = blockIdx.x;
  const int swz = (lin & 7) * cpx + (lin >> 3);
  const int m0 = (swz % nbx) * 256, n0 = (swz / nbx) * 256;
  const int twistL = (fr & 7) << 4;

  auto stageA = [&](int buf, int half, int kq) {
#pragma unroll
    for (int q = 0; q < 2; ++q) {
      int s = q * 8192 + tid * 16;
      int r = s >> 7, cb = s & 127;
      const void* src = &X[(size_t)(m0 + half * 128 + r) * K + kq + ((cb ^ ((r & 7) << 4)) >> 1)];
      void* dst = smem + buf * 65536 + half * 16384 + q * 8192 + w * 1024;
      gl_lds16(src, dst);
    }
  };
  auto stageB = [&](int buf, int half, int kq) {
#pragma unroll
    for (int q = 0; q < 2; ++q) {
      int s = q * 8192 + tid * 16;
      int r = s >> 7, cb = s & 127;
      const void* src = &W[(size_t)(n0 + half * 128 + r) * K + kq + ((cb ^ ((r & 7) << 4)) >> 1)];
      void* dst = smem + buf * 65536 + 32768 + half * 16384 + q * 8192 + w * 1024;
      gl_lds16(src, dst);
    }
  };

  stageA(0, 0, 0); stageA(0, 1, 0); stageB(0, 0, 0); stageB(0, 1, 0);

  f32x4 acc[8][4] = {};
  int cur = 0;
  const int NT = K >> 6;
  for (int kt = 0; kt < NT; ++kt) {
    const char* Ab = smem + cur * 65536;
    const char* Bb = smem + cur * 65536 + 32768;
#pragma unroll
    for (int p = 0; p < 4; ++p) {
      const int mg = p & 1, ks = p >> 1;
      if (p == 0) { asm volatile("s_waitcnt vmcnt(0)" ::: "memory"); }
      BARRIER();
      if (kt + 1 < NT) {
        if (p == 0)      { stageA(cur ^ 1, 0, (kt + 1) << 6); stageA(cur ^ 1, 1, (kt + 1) << 6); }
        else if (p == 1) { stageB(cur ^ 1, 0, (kt + 1) << 6); }
        else if (p == 2) { stageB(cur ^ 1, 1, (kt + 1) << 6); }
      }
      bf16x8 af[4], bfr[4];
#pragma unroll
      for (int t = 0; t < 4; ++t) {
        const int Ra = wm * 128 + mg * 64 + t * 16 + fr;
        af[t] = *(const bf16x8*)(Ab + Ra * 128 + ((ks * 64 + kg * 16) ^ twistL));
        const int Rb = wn * 64 + t * 16 + fr;
        bfr[t] = *(const bf16x8*)(Bb + Rb * 128 + ((ks * 64 + kg * 16) ^ twistL));
      }
      asm volatile("s_waitcnt lgkmcnt(0)" ::: "memory");
      __builtin_amdgcn_sched_barrier(0);
      __builtin_amdgcn_s_setprio(1);
#pragma unroll
      for (int t = 0; t < 4; ++t)
#pragma unroll
        for (int nf = 0; nf < 4; ++nf)
          acc[mg * 4 + t][nf] = __builtin_amdgcn_mfma_f32_16x16x32_bf16(af[t], bfr[nf], acc[mg * 4 + t][nf], 0, 0, 0);
      __builtin_amdgcn_s_setprio(0);
    }
    cur ^= 1;
  }

#pragma unroll
  for (int mf = 0; mf < 8; ++mf)
#pragma unroll
    for (int nf = 0; nf < 4; ++nf) {
      const int col = n0 + wn * 64 + nf * 16 + fr;
#pragma unroll
      for (int r = 0; r < 4; ++r) {
        const int row = m0 + wm * 128 + mf * 16 + kg * 4 + r;
        float rsv = rsqrtf(sums[row] * (1.0f / HIDN) + 1e-6f);
        OUT[(size_t)row * N + col] = acc[mf][nf][r] * rsv;
      }
    }
}

// --- grouped causal conv as MFMA GEMM; epilogue: (Bc+bias)*dt -> dBt[row][l] --
__global__ __launch_bounds__(256) void conv_k(const unsigned short* __restrict__ xb,
                                              const unsigned short* __restrict__ wreT,
                                              const float* __restrict__ conv_b,
                                              const float* __restrict__ dt,
                                              float* __restrict__ dBt) {
  __shared__ __align__(16) unsigned short x_lds[67 * 64];
  const int l0 = blockIdx.x * 64, g = blockIdx.y, b = blockIdx.z;
  const int tid = threadIdx.x, lane = tid & 63, wid = tid >> 6;
  {
    const int r = tid >> 3, ch = (tid & 7) * 8;
#pragma unroll
    for (int pass = 0; pass < 3; ++pass) {
      int rr = r + pass * 32;
      if (rr < 67) {
        int lg = l0 - 3 + rr;
        bf16x8 v = {};
        if (lg >= 0) v = *(const bf16x8*)&xb[(size_t)(b * L_SEQ + lg) * HIDN + g * 64 + ch];
        *(bf16x8*)&x_lds[rr * 64 + ch] = v;
      }
    }
  }
  __syncthreads();
  const int fr = lane & 15, kg = lane >> 4, wm = wid;
  f32x4 acc[4] = {};
#pragma unroll
  for (int ks = 0; ks < 8; ++ks) {
    bf16x8 a = *(const bf16x8*)&x_lds[(wm * 16 + fr + (ks >> 1)) * 64 + (ks & 1) * 32 + kg * 8];
#pragma unroll
    for (int nt = 0; nt < 4; ++nt) {
      bf16x8 bq = *(const bf16x8*)&wreT[(size_t)(g * 64 + nt * 16 + fr) * 256 + ks * 32 + kg * 8];
      acc[nt] = __builtin_amdgcn_mfma_f32_16x16x32_bf16(a, bq, acc[nt], 0, 0, 0);
    }
  }
  const int lgb = l0 + wm * 16 + kg * 4;
  const float4 dt4 = *(const float4*)&dt[b * L_SEQ + lgb];
#pragma unroll
  for (int nt = 0; nt < 4; ++nt) {
    const int o = nt * 16 + fr;
    const float bias = conv_b[g * 64 + o];
    float4 vv;
    vv.x = (acc[nt][0] + bias) * dt4.x;
    vv.y = (acc[nt][1] + bias) * dt4.y;
    vv.z = (acc[nt][2] + bias) * dt4.z;
    vv.w = (acc[nt][3] + bias) * dt4.w;
    *(float4*)&dBt[((size_t)(b * NH + g) * 64 + o) * L_SEQ + lgb] = vv;
  }
}

// ==== FUSED: blocks 0..127 = chunked scan (1 wave; 128KB LDS -> CU-exclusive);
// ==== blocks 128..383 = gate GEMM 256^2 (silu -> bf16).
__global__ __launch_bounds__(512, 1) void scan_gate_k(const float* __restrict__ dBt,
                                                      const float* __restrict__ Aw,
                                                      const float* __restrict__ dt,
                                                      unsigned short* __restrict__ states,
                                                      const unsigned short* __restrict__ X,
                                                      const unsigned short* __restrict__ W,
                                                      unsigned short* __restrict__ GOUT) {
  __shared__ __align__(16) char smem[131072];
  if (blockIdx.x >= 128) {
    // ------------------ gate GEMM (M=8192,N=2048,K=2048) ---------------------
    const int tid = threadIdx.x, lane = tid & 63, w = tid >> 6;
    const int wm = w >> 2, wn = w & 3, fr = lane & 15, kg = lane >> 4;
    const int gb = blockIdx.x - 128;            // 0..255
    const int swz = (gb & 7) * 32 + (gb >> 3);  // XCD-bijective (256 blocks)
    const int m0 = (swz & 31) * 256, n0 = (swz >> 5) * 256;
    const int twistL = (fr & 7) << 4;
    auto stageA = [&](int buf, int half, int kq) {
#pragma unroll
      for (int q = 0; q < 2; ++q) {
        int s = q * 8192 + tid * 16;
        int r = s >> 7, cb = s & 127;
        const void* src = &X[(size_t)(m0 + half * 128 + r) * 2048 + kq + ((cb ^ ((r & 7) << 4)) >> 1)];
        void* dst = smem + buf * 65536 + half * 16384 + q * 8192 + w * 1024;
        gl_lds16(src, dst);
      }
    };
    auto stageB = [&](int buf, int half, int kq) {
#pragma unroll
      for (int q = 0; q < 2; ++q) {
        int s = q * 8192 + tid * 16;
        int r = s >> 7, cb = s & 127;
        const void* src = &W[(size_t)(n0 + half * 128 + r) * 2048 + kq + ((cb ^ ((r & 7) << 4)) >> 1)];
        void* dst = smem + buf * 65536 + 32768 + half * 16384 + q * 8192 + w * 1024;
        gl_lds16(src, dst);
      }
    };
    stageA(0, 0, 0); stageA(0, 1, 0); stageB(0, 0, 0); stageB(0, 1, 0);
    f32x4 acc[8][4] = {};
    int cur = 0;
    for (int kt = 0; kt < 32; ++kt) {
      const char* Ab = smem + cur * 65536;
      const char* Bb = smem + cur * 65536 + 32768;
#pragma unroll
      for (int p = 0; p < 4; ++p) {
        const int mg = p & 1, ks = p >> 1;
        if (p == 0) { asm volatile("s_waitcnt vmcnt(0)" ::: "memory"); }
        BARRIER();
        if (kt + 1 < 32) {
          if (p == 0)      { stageA(cur ^ 1, 0, (kt + 1) << 6); stageA(cur ^ 1, 1, (kt + 1) << 6); }
          else if (p == 1) { stageB(cur ^ 1, 0, (kt + 1) << 6); }
          else if (p == 2) { stageB(cur ^ 1, 1, (kt + 1) << 6); }
        }
        bf16x8 af[4], bfr[4];
#pragma unroll
        for (int t = 0; t < 4; ++t) {
          const int Ra = wm * 128 + mg * 64 + t * 16 + fr;
          af[t] = *(const bf16x8*)(Ab + Ra * 128 + ((ks * 64 + kg * 16) ^ twistL));
          const int Rb = wn * 64 + t * 16 + fr;
          bfr[t] = *(const bf16x8*)(Bb + Rb * 128 + ((ks * 64 + kg * 16) ^ twistL));
        }
        asm volatile("s_waitcnt lgkmcnt(0)" ::: "memory");
        __builtin_amdgcn_sched_barrier(0);
        __builtin_amdgcn_s_setprio(1);
#pragma unroll
        for (int t = 0; t < 4; ++t)
#pragma unroll
          for (int nf = 0; nf < 4; ++nf)
            acc[mg * 4 + t][nf] = __builtin_amdgcn_mfma_f32_16x16x32_bf16(af[t], bfr[nf], acc[mg * 4 + t][nf], 0, 0, 0);
        __builtin_amdgcn_s_setprio(0);
      }
      cur ^= 1;
    }
#pragma unroll
    for (int mf = 0; mf < 8; ++mf)
#pragma unroll
      for (int nf = 0; nf < 4; ++nf) {
        const int col = n0 + wn * 64 + nf * 16 + fr;
#pragma unroll
        for (int r = 0; r < 4; ++r) {
          const int row = m0 + wm * 128 + mf * 16 + kg * 4 + r;
          float v = acc[mf][nf][r];
          v = v / (1.f + __expf(-v));
          GOUT[(size_t)row * 2048 + col] = f2bf(v);
        }
      }
    return;
  }
  // ----------------------------- scan (1 wave) ------------------------------
  if (threadIdx.x >= 64) return;
  const int bid = blockIdx.x;          // b*32 + h
  const int h = bid & 31, b = bid >> 5;
  const int lane = threadIdx.x;
  const int fr = lane & 15, kg = lane >> 4;

  char* sp = smem;                 // s-pairs [CHUNK] stride 176B   (11264 B)
  char* xT = smem + 11264;         // xT [CHUNK] stride 304B        (19456 B)
  char* db = smem + 30720;         // Dv staging: 2 bufs x 16KB

  bf16x8 afr[4][2];
  {
    const float* Ah = Aw + (size_t)h * 64 * 64;
#pragma unroll
    for (int mb = 0; mb < 4; ++mb)
#pragma unroll
      for (int kt = 0; kt < 2; ++kt) {
        const float* p = &Ah[(size_t)(mb * 16 + fr) * 64 + kt * 32 + kg * 8];
        float4 v0 = *(const float4*)p;
        float4 v1 = *(const float4*)(p + 4);
        bf16x8 f;
        f[0] = (short)f2bf(v0.x); f[1] = (short)f2bf(v0.y);
        f[2] = (short)f2bf(v0.z); f[3] = (short)f2bf(v0.w);
        f[4] = (short)f2bf(v1.x); f[5] = (short)f2bf(v1.y);
        f[6] = (short)f2bf(v1.z); f[7] = (short)f2bf(v1.w);
        afr[mb][kt] = f;
      }
  }

  const float* dBp = dBt + (size_t)(bid * 64 + lane) * L_SEQ;   // own row
  unsigned short* stbase = states + (size_t)bid * L_SEQ * 64;
  const float* dtp = dt + b * L_SEQ;
  const int spw = (lane >> 1) * 4;

  auto pfDv = [&](int buf, int c) {
#pragma unroll
    for (int q = 0; q < 16; ++q)
      gl_lds16(&dBp[c * CHUNK + q * 4], db + buf * 16384 + q * 1024);
  };
  pfDv(0, 0);

  float scs = 0.f;
  for (int c = 0; c < L_SEQ / CHUNK; ++c) {
    const int l0 = c * CHUNK;
    const int buf = c & 1;
    // chunk 0: only the 16 prefetch loads outstanding -> full drain.
    // later chunks: [16 gl_lds older, 8 bulk stores newer] -> vmcnt(8)
    // guarantees prefetch complete while stores stay in flight.
    if (c == 0) { asm volatile("s_waitcnt vmcnt(0)" ::: "memory"); }
    else        { asm volatile("s_waitcnt vmcnt(8)" ::: "memory"); }
    float Dv[CHUNK];
#pragma unroll
    for (int q = 0; q < 16; ++q) {
      f32x4 v = *(const f32x4*)(db + buf * 16384 + q * 1024 + lane * 16);
      Dv[q * 4] = v[0]; Dv[q * 4 + 1] = v[1]; Dv[q * 4 + 2] = v[2]; Dv[q * 4 + 3] = v[3];
    }
    // dtq BEFORE pfDv: compiler's dtq-use wait then leaves the 16 newer
    // prefetch loads in flight (counted wait), instead of draining them.
    float dtq[4];
#pragma unroll
    for (int tb = 0; tb < 4; ++tb) dtq[tb] = dtp[l0 + tb * 16 + fr];
    if (c + 1 < L_SEQ / CHUNK) pfDv(buf ^ 1, c + 1);

    // ---- pass 1 (E=1): write s-pair (state BEFORE step l), then s += Dv ----
    {
      float s = scs;
#pragma unroll
      for (int l = 0; l < CHUNK; ++l) {
        float sn = qperm<0xB1>(s);
        float lo = (lane & 1) ? sn : s;
        float hi = (lane & 1) ? s : sn;
        unsigned pw;
        asm("v_cvt_pk_bf16_f32 %0, %1, %2" : "=v"(pw) : "v"(lo), "v"(hi));
        *(unsigned*)(sp + l * 176 + spw) = pw;
        s = s + Dv[l];
      }
    }
    asm volatile("" ::: "memory");
    // ---- batched matvec: X[m][t] = A_w · S, scaled by dt ----
    {
      bf16x8 bf[4][2];
#pragma unroll
      for (int tb = 0; tb < 4; ++tb)
#pragma unroll
        for (int kt = 0; kt < 2; ++kt)
          bf[tb][kt] = *(const bf16x8*)(sp + (tb * 16 + fr) * 176 + (kt * 16 + kg * 4) * 4);
      f32x4 acc[4][4];
#pragma unroll
      for (int mb = 0; mb < 4; ++mb)
#pragma unroll
        for (int tb = 0; tb < 4; ++tb) {
          f32x4 z = {0.f, 0.f, 0.f, 0.f};
          f32x4 t0 = __builtin_amdgcn_mfma_f32_16x16x32_bf16(afr[mb][0], bf[tb][0], z, 0, 0, 0);
          acc[mb][tb] = __builtin_amdgcn_mfma_f32_16x16x32_bf16(afr[mb][1], bf[tb][1], t0, 0, 0, 0);
        }
#pragma unroll
      for (int mb = 0; mb < 4; ++mb)
#pragma unroll
        for (int tb = 0; tb < 4; ++tb) {
          f32x4 v = acc[mb][tb];
          v[0] *= dtq[tb]; v[1] *= dtq[tb]; v[2] *= dtq[tb]; v[3] *= dtq[tb];
          *(f32x4*)(xT + (tb * 16 + fr) * 304 + (mb * 16 + kg * 4) * 4) = v;
        }
    }
    asm volatile("" ::: "memory");
    // ---- final pass: E inline; pack exact states to sp; bulk-store chunk ----
    {
      float s = scs;
#pragma unroll
      for (int gq = 0; gq < CHUNK / 8; ++gq) {
        float xs[8];
#pragma unroll
        for (int j = 0; j < 8; ++j)
          xs[j] = *(const float*)(xT + (gq * 8 + j) * 304 + lane * 4);
#pragma unroll
        for (int j = 0; j < 8; ++j) {
          const int l = gq * 8 + j;
          float xv = xs[j];
          float E = __builtin_fmaf(xv * xv, 0.5f, 1.0f + xv);
          s = __builtin_fmaf(E, s, Dv[l]);
          float sn = qperm<0xB1>(s);
          float lo = (lane & 1) ? sn : s;
          float hi = (lane & 1) ? s : sn;
          unsigned pw;
          asm("v_cvt_pk_bf16_f32 %0, %1, %2" : "=v"(pw) : "v"(lo), "v"(hi));
          *(unsigned*)(sp + l * 176 + spw) = pw;
        }
      }
      scs = s;
    }
    asm volatile("" ::: "memory");
    // 8 coalesced 16B stores replace 64 scattered 2B stores
#pragma unroll
    for (int j2 = 0; j2 < 8; ++j2) {
      const int g0 = j2 * 1024 + lane * 16;          // byte within chunk block
      const int lrow = g0 >> 7, cbyte = g0 & 127;
      bf16x8 vv = *(const bf16x8*)(sp + lrow * 176 + cbyte);
      *(bf16x8*)&stbase[(size_t)l0 * 64 + (g0 >> 1)] = vv;
    }
  }
}

// -- C proj + x*D + silu(gate); LDS-staged coalesced bf16 stores + row sums ----
__global__ __launch_bounds__(256) void proj_k(const unsigned short* __restrict__ st,
                                              const unsigned short* __restrict__ cwb,
                                              const unsigned short* __restrict__ xbp,
                                              const float* __restrict__ Dp,
                                              const unsigned short* __restrict__ gsb,
                                              unsigned short* __restrict__ hsb,
                                              float* __restrict__ sums) {
  __shared__ __align__(16) unsigned short hls[64 * 72];   // padded stride 72
  const int l0 = blockIdx.x * 64, h = blockIdx.y, b = blockIdx.z;
  const int tid = threadIdx.x, lane = tid & 63, wid = tid >> 6;
  const int fr = lane & 15, kg = lane >> 4, wm = wid;
  f32x4 acc[4] = {};
#pragma unroll
  for (int ks = 0; ks < 2; ++ks) {
    bf16x8 a = *(const bf16x8*)&st[((size_t)(b * NH + h) * L_SEQ + l0 + wm * 16 + fr) * 64 + ks * 32 + kg * 8];
#pragma unroll
    for (int nt = 0; nt < 4; ++nt) {
      bf16x8 bq = *(const bf16x8*)&cwb[(size_t)(h * 64 + nt * 16 + fr) * 64 + ks * 32 + kg * 8];
      acc[nt] = __builtin_amdgcn_mfma_f32_16x16x32_bf16(a, bq, acc[nt], 0, 0, 0);
    }
  }
  const float Dh = Dp[h];
#pragma unroll
  for (int r = 0; r < 4; ++r) {
    const int lg = l0 + wm * 16 + kg * 4 + r;
    float sq = 0.f;
#pragma unroll
    for (int nt = 0; nt < 4; ++nt) {
      const int ccol = h * 64 + nt * 16 + fr;
      const size_t idx = (size_t)(b * L_SEQ + lg) * HIDN + ccol;
      float v = acc[nt][r] + bf2f(xbp[idx]) * Dh;
      float hv = v * bf2f(gsb[idx]);
      hls[(wm * 16 + kg * 4 + r) * 72 + nt * 16 + fr] = f2bf(hv);
      sq += hv * hv;
    }
    sq += __shfl_xor(sq, 1);
    sq += __shfl_xor(sq, 2);
    sq += __shfl_xor(sq, 4);
    sq += __shfl_xor(sq, 8);
    if (fr == 0) atomicAdd(&sums[b * L_SEQ + lg], sq);
  }
  __syncthreads();
#pragma unroll
  for (int it = 0; it < 2; ++it) {
    int unit = tid + it * 256;               // 512 units of 16B
    int row = unit >> 3, seg = unit & 7;
    bf16x8 vv = *(const bf16x8*)&hls[row * 72 + seg * 8];
    *(bf16x8*)&hsb[(size_t)(b * L_SEQ + l0 + row) * HIDN + h * 64 + seg * 8] = vv;
  }
}

extern "C" void kernel_launch(void* const* d_in, const int* in_sizes, int n_in,
                              void* d_out, int out_size, void* d_ws, size_t ws_size,
                              hipStream_t stream) {
  const float* x  = (const float*)d_in[0];
  const float* dt = (const float*)d_in[1];
  const float* gw = (const float*)d_in[2];
  const float* Aw = (const float*)d_in[3];
  const float* cw = (const float*)d_in[4];
  const float* cb = (const float*)d_in[5];
  const float* Cw = (const float*)d_in[6];
  const float* Dp = (const float*)d_in[7];
  const float* nw = (const float*)d_in[8];
  const float* ow = (const float*)d_in[9];
  float* out = (float*)d_out;

  // workspace (bytes): hsb overlays dBt (dead after scan); stb has own slot.
  // gate bf16 lives in d_out's first 32MB (dead before out-GEMM writes).
  char* w = (char*)d_ws;
  unsigned short* xb   = (unsigned short*)(w);                // 32MB
  unsigned short* gwb  = (unsigned short*)(w + 33554432);     // 8MB
  unsigned short* owb  = (unsigned short*)(w + 41943040);     // 8MB (ow*nw)
  unsigned short* wret = (unsigned short*)(w + 50331648);     // 1MB
  unsigned short* cwb  = (unsigned short*)(w + 51380224);     // 256KB
  float*          sums = (float*)(w + 51642368);              // 32KB (row sums)
  float*          dBt  = (float*)(w + 52428800);              // 64MB
  unsigned short* hsb  = (unsigned short*)(w + 52428800);     // overlay (after scan)
  unsigned short* stb  = (unsigned short*)(w + 119537664);    // 32MB
  unsigned short* gsb  = (unsigned short*)d_out;              // gate bf16, 32MB
  if (ws_size < 153092096) return;

  hipMemsetAsync(sums, 0, 8192 * sizeof(float), stream);
  prep_k<<<2048, 256, 0, stream>>>(x, gw, ow, nw, Cw, cw, xb, gwb, owb, cwb, wret);
  conv_k<<<dim3(32, 32, 4), 256, 0, stream>>>(xb, wret, cb, dt, dBt);
  // FUSED: scan (blocks 0..127, CU-exclusive via 128KB LDS) || gate GEMM
  scan_gate_k<<<384, 512, 0, stream>>>(dBt, Aw, dt, stb, xb, gwb, gsb);
  proj_k<<<dim3(32, 32, 4), 256, 0, stream>>>(stb, cwb, xb, Dp, gsb, hsb, sums);
  gemm256_out_k<<<256, 512, 0, stream>>>(hsb, owb, sums, out, 8192, 2048, 2048);
}